// Round 7
// baseline (394.310 us; speedup 1.0000x reference)
//
#include <hip/hip_runtime.h>
#include <math.h>

#define LEAK 0.01f

typedef __bf16 bf16x8 __attribute__((ext_vector_type(8)));
typedef float f32x4 __attribute__((ext_vector_type(4)));
typedef unsigned short ushort;
typedef unsigned int uint32;

struct HL { ushort h, l; };

// split fp32 into bf16 hi + bf16 lo (both RNE): x ~= hi + lo, err ~2^-17 rel
__device__ inline HL split_bf16(float x) {
    unsigned u = __float_as_uint(x);
    unsigned hr = (u + 0x7FFFu + ((u >> 16) & 1u)) >> 16;
    float fh = __uint_as_float(hr << 16);
    float r = x - fh;
    unsigned v = __float_as_uint(r);
    unsigned lr = (v + 0x7FFFu + ((v >> 16) & 1u)) >> 16;
    HL out; out.h = (ushort)hr; out.l = (ushort)lr;
    return out;
}

// ============ staged-B raw load: 32n x 64k fp32 tile, 8 floats/thread (2 k-halves) ============
template<int MODE>
__device__ inline void stage_load(float (&pv)[2][4], const float* __restrict__ Bf,
                                  int kbase, int n0, int tid,
                                  int Ci, int Hin, int Ho, int lgHo, int lgHW) {
    int nl = tid >> 3, kg = tid & 7;
    int n = n0 + nl;
#pragma unroll
    for (int r = 0; r < 2; ++r) {
        if (MODE == 0) {
            int k4 = kbase + (r << 5) + (kg << 2);
            int ic = k4 >> 4, kh = (k4 >> 2) & 3;
            int ow = n & (Ho - 1), oh = (n >> lgHo) & (Ho - 1), b = n >> (lgHo + lgHo);
            int ih = oh * 2 - 1 + kh;
            int ihc = ih < 0 ? 0 : (ih >= Hin ? Hin - 1 : ih);
            int iwb = ow * 2 - 1;
            size_t base = ((size_t)(b * Ci + ic) * Hin + ihc) * Hin;
#pragma unroll
            for (int e = 0; e < 4; ++e) {
                int iw = iwb + e;
                int iwc = iw < 0 ? 0 : (iw >= Hin ? Hin - 1 : iw);
                pv[r][e] = Bf[base + iwc];
            }
        } else {
            int c = kbase + (r << 5) + (kg << 2);
            int b = n >> lgHW, hw = n & ((1 << lgHW) - 1);
            size_t base = (((size_t)(b * Ci + c)) << lgHW) + hw;
            size_t str = (size_t)1 << lgHW;
#pragma unroll
            for (int e = 0; e < 4; ++e) pv[r][e] = Bf[base + e * str];
        }
    }
}

// ================= bf16-split MFMA GEMM with fused BN+LeakyReLU on B-load =================
// Block tile 128M x 32N, 4 waves of 32M x 32N. K-step 64 (r7): one barrier pair per
// 64-K instead of per 32-K — doubles in-flight staged bytes/thread and the MFMA work
// between prefetch-issue and use (the r6 counters showed each 32-K step paid a nearly
// full ~500-900cy gather latency; only ~150cy was hidden).
// MODE 0: conv-im2col B; MODE 1: channel-major B; MODE 2: PRE-SPLIT B from global
//   (QH/QL bf16 [n][k] row-major; Ci = K stride, Ho = QL ushort offset) — no
//   staging/transform/LDS/barriers in the K-loop (keeps 32-K steps).
// statsBnt != nullptr (KS==1): fused per-channel sum/sumsq atomics, 8-way banked.
// bntBankStride > 0: input bnt is 8-banked; sum banks in prologue.
// NOTE (r2): never replicate B transform across Mtiles. NOTE (r4): split-K multiplies
// per-block fixed cost. NOTE (r6): occupancy was NOT the limiter (34% occ, same time).
template<int MODE>
__global__ __launch_bounds__(256, 3) void gemm_mfma(
    const ushort* __restrict__ Ah, const ushort* __restrict__ Al,
    const float* __restrict__ Bf,
    const float* __restrict__ bnt, const float* __restrict__ gamma,
    const float* __restrict__ beta, float invN, int chanShift,
    const float* __restrict__ bias, float* __restrict__ P,
    int Mtiles, int Ntiles, int K, int Kslice, int KS, int outSize,
    int Ci, int Hin, int Co, int Ho, int lgHo,
    int lgHW, int lgHin, int lgCo, int lgk,
    float* __restrict__ statsBnt, const float* __restrict__ bnPart,
    int statsBank, int bntBankStride)
{
    __shared__ __align__(16) uint32 Bsp[32 * 68];   // [n][64k] packed, stride 68
    __shared__ float scs[256], shs[256];

    int bid = blockIdx.x;
    int ntile = bid % Ntiles; bid /= Ntiles;
    int mtile = bid % Mtiles;
    int ks = bid / Mtiles;
    int tid = threadIdx.x;
    int lane = tid & 63, w = tid >> 6;
    int quad = lane >> 4, tl = lane & 15;
    int n0 = ntile << 5, m0 = mtile << 7, k0 = ks * Kslice;
    int Kt = K >> 5;

    bool useBN = (bnt != nullptr) || (bnPart != nullptr);
    int c0 = k0 >> chanShift;
    if (bnPart != nullptr) {
        // BN0 from conv tile-partials: 64 channels x 256 (sum,sq) pairs
        int c = tid >> 2, qq = tid & 3;
        const float2* pp2 = (const float2*)(bnPart + c * 512) + qq * 64;
        float s = 0.f, s2 = 0.f;
#pragma unroll 8
        for (int p = 0; p < 64; ++p) { float2 v = pp2[p]; s += v.x; s2 += v.y; }
        scs[tid] = s; shs[tid] = s2;
        __syncthreads();
        float scale = 0.f, shift = 0.f;
        if (tid < 64) {
            float st = scs[tid * 4] + scs[tid * 4 + 1] + scs[tid * 4 + 2] + scs[tid * 4 + 3];
            float qt = shs[tid * 4] + shs[tid * 4 + 1] + shs[tid * 4 + 2] + shs[tid * 4 + 3];
            float m = st * invN;
            float var = qt * invN - m * m;
            scale = gamma[tid] * rsqrtf(var + 1e-5f);
            shift = beta[tid] - m * scale;
        }
        __syncthreads();
        // store shifted so the transform's scs[ic - c0] indexing works for any K-slice
        if (tid < 64 && tid >= c0) { scs[tid - c0] = scale; shs[tid - c0] = shift; }
    } else if (bnt != nullptr) {
        int nch = Kslice >> chanShift;
        for (int c = tid; c < nch; c += 256) {
            float sm, sq;
            if (bntBankStride > 0) {
                sm = 0.f; sq = 0.f;
#pragma unroll
                for (int bk = 0; bk < 8; ++bk) {
                    sm += bnt[bk * bntBankStride + (c0 + c) * 2];
                    sq += bnt[bk * bntBankStride + (c0 + c) * 2 + 1];
                }
            } else {
                sm = bnt[(c0 + c) * 2];
                sq = bnt[(c0 + c) * 2 + 1];
            }
            float m = sm * invN;
            float var = sq * invN - m * m;
            float scale = gamma[c0 + c] * rsqrtf(var + 1e-5f);
            scs[c] = scale;
            shs[c] = beta[c0 + c] - m * scale;
        }
    }
    __syncthreads();

    f32x4 zero4 = {0.f, 0.f, 0.f, 0.f};
    f32x4 acc[2][2];
#pragma unroll
    for (int mt = 0; mt < 2; ++mt)
#pragma unroll
        for (int nt = 0; nt < 2; ++nt) acc[mt][nt] = zero4;

    if (MODE == 2) {
        // ---- barrier-free K-loop: B pre-split in global (L2-resident) ----
        const ushort* Bu = (const ushort*)Bf;
        for (int kc = 0; kc < Kslice; kc += 32) {
            int kbase = k0 + kc;
            int kt = kbase >> 5;
            bf16x8 afh[2], afl[2];
#pragma unroll
            for (int mt = 0; mt < 2; ++mt) {
                int mtAbs = (m0 >> 4) + (w << 1) + mt;
                size_t abase = (((size_t)mtAbs * Kt + kt) << 6) + lane;
                afh[mt] = *(const bf16x8*)(Ah + abase * 8);
                afl[mt] = *(const bf16x8*)(Al + abase * 8);
            }
            bf16x8 bfh[2], bfl[2];
#pragma unroll
            for (int nt = 0; nt < 2; ++nt) {
                int n = n0 + (nt << 4) + tl;
                size_t ba = (size_t)n * Ci + kbase + (quad << 3);
                bfh[nt] = *(const bf16x8*)(Bu + ba);
                bfl[nt] = *(const bf16x8*)(Bu + Ho + ba);
            }
#pragma unroll
            for (int mt = 0; mt < 2; ++mt)
#pragma unroll
                for (int nt = 0; nt < 2; ++nt) {
                    acc[mt][nt] = __builtin_amdgcn_mfma_f32_16x16x32_bf16(afh[mt], bfh[nt], acc[mt][nt], 0, 0, 0);
                    acc[mt][nt] = __builtin_amdgcn_mfma_f32_16x16x32_bf16(afh[mt], bfl[nt], acc[mt][nt], 0, 0, 0);
                    acc[mt][nt] = __builtin_amdgcn_mfma_f32_16x16x32_bf16(afl[mt], bfh[nt], acc[mt][nt], 0, 0, 0);
                }
        }
    } else {
        // ---- staged K-loop, BK=64: stage/transform 32n x 64k per barrier pair ----
        float pv[2][4];
        stage_load<MODE>(pv, Bf, k0, n0, tid, Ci, Hin, Ho, lgHo, lgHW);

        for (int kc = 0; kc < Kslice; kc += 64) {
            int kbase = k0 + kc;
            // ---- transform both k-halves + regs -> LDS ----
            int nl = tid >> 3, kg = tid & 7;
#pragma unroll
            for (int r = 0; r < 2; ++r) {
                int k4 = kbase + (r << 5) + (kg << 2);
                uint32 pk[4];
                if (MODE == 0) {
                    int ic = k4 >> 4, kh = (k4 >> 2) & 3;
                    int n = n0 + nl;
                    int ow = n & (Ho - 1), oh = (n >> lgHo) & (Ho - 1);
                    int ih = oh * 2 - 1 + kh;
                    bool rowok = (unsigned)ih < (unsigned)Hin;
                    int iwb = ow * 2 - 1;
                    float sc_ = useBN ? scs[ic - c0] : 0.f;
                    float sh_ = useBN ? shs[ic - c0] : 0.f;
#pragma unroll
                    for (int e = 0; e < 4; ++e) {
                        int iw = iwb + e;
                        bool ok = rowok && ((unsigned)iw < (unsigned)Hin);
                        float f = pv[r][e];
                        if (useBN) { f = f * sc_ + sh_; f = f >= 0.f ? f : LEAK * f; }
                        if (!ok) f = 0.f;
                        HL s = split_bf16(f);
                        pk[e] = ((uint32)s.h << 16) | s.l;
                    }
                } else {
#pragma unroll
                    for (int e = 0; e < 4; ++e) {
                        float f = pv[r][e];
                        if (useBN) {
                            int lc = k4 + e - k0;
                            f = f * scs[lc] + shs[lc];
                            f = f >= 0.f ? f : LEAK * f;
                        }
                        HL s = split_bf16(f);
                        pk[e] = ((uint32)s.h << 16) | s.l;
                    }
                }
                *(uint4*)&Bsp[nl * 68 + (r << 5) + (kg << 2)] = make_uint4(pk[0], pk[1], pk[2], pk[3]);
            }
            __syncthreads();

            // ---- prefetch next 64-K tile (raw; latency hidden under 24 MFMAs) ----
            bool more = (kc + 64) < Kslice;
            float pvn[2][4];
            if (more) stage_load<MODE>(pvn, Bf, kbase + 64, n0, tid, Ci, Hin, Ho, lgHo, lgHW);

            // ---- two 32-K substeps from LDS ----
#pragma unroll
            for (int sub = 0; sub < 2; ++sub) {
                int kt = (kbase >> 5) + sub;
                bf16x8 afh[2], afl[2];
#pragma unroll
                for (int mt = 0; mt < 2; ++mt) {
                    int mtAbs = (m0 >> 4) + (w << 1) + mt;
                    size_t abase = (((size_t)mtAbs * Kt + kt) << 6) + lane;
                    afh[mt] = *(const bf16x8*)(Ah + abase * 8);
                    afl[mt] = *(const bf16x8*)(Al + abase * 8);
                }
                bf16x8 bfh[2], bfl[2];
#pragma unroll
                for (int nt = 0; nt < 2; ++nt) {
                    int base = ((nt << 4) + tl) * 68 + (sub << 5) + (quad << 3);
                    uint4 ua = *(const uint4*)&Bsp[base];
                    uint4 ub = *(const uint4*)&Bsp[base + 4];
                    union { uint32 u[4]; bf16x8 v; } H, L;
                    H.u[0] = __builtin_amdgcn_perm(ua.y, ua.x, 0x07060302u);
                    H.u[1] = __builtin_amdgcn_perm(ua.w, ua.z, 0x07060302u);
                    H.u[2] = __builtin_amdgcn_perm(ub.y, ub.x, 0x07060302u);
                    H.u[3] = __builtin_amdgcn_perm(ub.w, ub.z, 0x07060302u);
                    L.u[0] = __builtin_amdgcn_perm(ua.y, ua.x, 0x05040100u);
                    L.u[1] = __builtin_amdgcn_perm(ua.w, ua.z, 0x05040100u);
                    L.u[2] = __builtin_amdgcn_perm(ub.y, ub.x, 0x05040100u);
                    L.u[3] = __builtin_amdgcn_perm(ub.w, ub.z, 0x05040100u);
                    bfh[nt] = H.v; bfl[nt] = L.v;
                }
#pragma unroll
                for (int mt = 0; mt < 2; ++mt)
#pragma unroll
                    for (int nt = 0; nt < 2; ++nt) {
                        acc[mt][nt] = __builtin_amdgcn_mfma_f32_16x16x32_bf16(afh[mt], bfh[nt], acc[mt][nt], 0, 0, 0);
                        acc[mt][nt] = __builtin_amdgcn_mfma_f32_16x16x32_bf16(afh[mt], bfl[nt], acc[mt][nt], 0, 0, 0);
                        acc[mt][nt] = __builtin_amdgcn_mfma_f32_16x16x32_bf16(afl[mt], bfh[nt], acc[mt][nt], 0, 0, 0);
                    }
            }
            __syncthreads();
            if (more) {
#pragma unroll
                for (int r = 0; r < 2; ++r)
#pragma unroll
                    for (int e = 0; e < 4; ++e) pv[r][e] = pvn[r][e];
            }
        }
    }

    // ---- epilogue: D[m = quad*4+reg][n = tl] + optional fused stats (KS==1 paths) ----
    bool doStats = (statsBnt != nullptr);
    if (doStats) {
        if (tid < 2 * Co) scs[tid] = 0.f;
        __syncthreads();
    }
    float ssum[2][4] = {{0.f,0.f,0.f,0.f},{0.f,0.f,0.f,0.f}};
    float ssq [2][4] = {{0.f,0.f,0.f,0.f},{0.f,0.f,0.f,0.f}};
    float* dst = P + (size_t)ks * outSize;
    if (MODE == 0) {
#pragma unroll
        for (int nt = 0; nt < 2; ++nt) {
            int n = n0 + (nt << 4) + tl;
            int ow = n & (Ho - 1), oh = (n >> lgHo) & (Ho - 1), b = n >> (lgHo + lgHo);
#pragma unroll
            for (int mt = 0; mt < 2; ++mt) {
                int mb = m0 + (w << 5) + (mt << 4) + (quad << 2);
#pragma unroll
                for (int r = 0; r < 4; ++r) {
                    int oc = mb + r;
                    float v = acc[mt][nt][r];
                    if (KS == 1) v += bias[oc];
                    if (doStats) { ssum[mt][r] += v; ssq[mt][r] += v * v; }
                    dst[((size_t)(b * Co + oc) * Ho + oh) * Ho + ow] = v;
                }
            }
        }
    } else {
        int kf = 1 << lgk;
        int Ho2 = Hin << lgk;
#pragma unroll
        for (int nt = 0; nt < 2; ++nt) {
            int n = n0 + (nt << 4) + tl;
            int b = n >> lgHW, hw = n & ((1 << lgHW) - 1);
            int h = hw >> lgHin, wp = hw & (Hin - 1);
#pragma unroll
            for (int mt = 0; mt < 2; ++mt) {
                int mb = m0 + (w << 5) + (mt << 4) + (quad << 2);
#pragma unroll
                for (int r = 0; r < 4; ++r) {
                    int m = mb + r;
                    int o = m & (Co - 1), ij = m >> lgCo;
                    int ii = ij >> lgk, jj = ij & (kf - 1);
                    float v = acc[mt][nt][r];
                    if (KS == 1) v += bias[o];
                    if (doStats) { ssum[mt][r] += v; ssq[mt][r] += v * v; }
                    dst[((size_t)(b * Co + o) * Ho2 + (h << lgk) + ii) * Ho2 + (wp << lgk) + jj] = v;
                }
            }
        }
    }
    if (doStats) {
        // reduce over the 16 lanes (tl) sharing identical channels
#pragma unroll
        for (int mt = 0; mt < 2; ++mt)
#pragma unroll
            for (int r = 0; r < 4; ++r) {
                float s = ssum[mt][r], q2 = ssq[mt][r];
#pragma unroll
                for (int m2 = 1; m2 < 16; m2 <<= 1) {
                    s  += __shfl_xor(s,  m2);
                    q2 += __shfl_xor(q2, m2);
                }
                if (tl == 0) {
                    int m = m0 + (w << 5) + (mt << 4) + (quad << 2) + r;
                    int o = (MODE == 0) ? m : (m & (Co - 1));
                    atomicAdd(&scs[o * 2],     s);
                    atomicAdd(&scs[o * 2 + 1], q2);
                }
            }
        __syncthreads();
        float* sb = statsBnt + (blockIdx.x & 7) * statsBank;
        if (tid < 2 * Co) atomicAdd(&sb[tid], scs[tid]);
    }
}

// ================= weight prep address =================
__device__ inline int fragaddr(int m, int k, int K) {
    return ((((m >> 4) * (K >> 5) + (k >> 5)) << 9) | (((k >> 3) & 3) << 7) | ((m & 15) << 3) | (k & 7));
}

#define OUT_CL   786432
#define OUT_CB   786433
#define OUT_IDX  786434
#define OUT_MIND 787458

// ================= enc0 direct conv (Ci=3) with non-atomic per-tile BN stat partials =================
__device__ void conv_body(int bid, int tid,
                          const float* __restrict__ x, const float* __restrict__ w,
                          const float* __restrict__ bias, float* __restrict__ P,
                          float* __restrict__ pst, float (&cst)[4][16])
{
    const int Ci = 3, Hin = 128, Co = 64, Ho = 64, OCT = 8;
    int ntile = (16 * Ho * Ho) >> 8;          // 256
    int tile = bid % ntile;
    int og = bid / ntile;
    int oc0 = og * OCT;

    int px = (tile << 8) + tid;
    int ow = px % Ho; int t = px / Ho;
    int oh = t % Ho;  int b = t / Ho;

    int off[16]; float fm[16];
    int ih0 = oh * 2 - 1, iw0 = ow * 2 - 1;
#pragma unroll
    for (int kh = 0; kh < 4; ++kh)
#pragma unroll
        for (int kw = 0; kw < 4; ++kw) {
            int ih = ih0 + kh, iw = iw0 + kw;
            bool ok = (ih >= 0) && (ih < Hin) && (iw >= 0) && (iw < Hin);
            int ihc = ih < 0 ? 0 : (ih >= Hin ? Hin - 1 : ih);
            int iwc = iw < 0 ? 0 : (iw >= Hin ? Hin - 1 : iw);
            off[kh * 4 + kw] = ihc * Hin + iwc;
            fm[kh * 4 + kw] = ok ? 1.f : 0.f;
        }

    float acc[OCT];
#pragma unroll
    for (int u = 0; u < OCT; ++u) acc[u] = bias[oc0 + u];

    const float* xc = x + (size_t)b * Ci * Hin * Hin;
    const float* wi = w + (size_t)oc0 * Ci * 16;
    int HinHin = Hin * Hin;
    for (int ic = 0; ic < Ci; ++ic) {
        float xv[16];
#pragma unroll
        for (int q = 0; q < 16; ++q) xv[q] = xc[off[q]] * fm[q];
#pragma unroll
        for (int u = 0; u < OCT; ++u) {
            const float* wo = wi + (size_t)u * Ci * 16;
            float a = acc[u];
#pragma unroll
            for (int q = 0; q < 16; ++q) a += xv[q] * wo[q];
            acc[u] = a;
        }
        xc += HinHin;
        wi += 16;
    }
    size_t obase = (((size_t)b * Co + oc0) * Ho + oh) * Ho + ow;
    size_t opl = (size_t)Ho * Ho;
#pragma unroll
    for (int u = 0; u < OCT; ++u) P[obase + u * opl] = acc[u];

    // ---- BN stat partials: butterfly over 64 lanes, combine 4 waves, plain store ----
    float sv[OCT], qv[OCT];
#pragma unroll
    for (int u = 0; u < OCT; ++u) { sv[u] = acc[u]; qv[u] = acc[u] * acc[u]; }
#pragma unroll
    for (int m2 = 1; m2 < 64; m2 <<= 1)
#pragma unroll
        for (int u = 0; u < OCT; ++u) {
            sv[u] += __shfl_xor(sv[u], m2);
            qv[u] += __shfl_xor(qv[u], m2);
        }
    int lane = tid & 63, wv = tid >> 6;
    if (lane == 0) {
#pragma unroll
        for (int u = 0; u < OCT; ++u) { cst[wv][u * 2] = sv[u]; cst[wv][u * 2 + 1] = qv[u]; }
    }
    __syncthreads();
    if (tid < 2 * OCT) {
        float v = cst[0][tid] + cst[1][tid] + cst[2][tid] + cst[3][tid];
        pst[(oc0 + (tid >> 1)) * 512 + tile * 2 + (tid & 1)] = v;
    }
}

// ================= fused prologue: zero BNT/losses + cbT + weight prep + enc0 conv =================
__global__ void prologue(const float* __restrict__ w1, const float* __restrict__ w2,
                         const float* __restrict__ w3, const float* __restrict__ d0,
                         const float* __restrict__ d1, const float* __restrict__ d2,
                         ushort* __restrict__ WH, ushort* __restrict__ WL,
                         const float* __restrict__ cb, float* __restrict__ cbT,
                         float* __restrict__ bnt, float* __restrict__ dout,
                         const float* __restrict__ x, const float* __restrict__ w0,
                         const float* __restrict__ b0, float* __restrict__ Y0,
                         float* __restrict__ pst) {
    __shared__ float cst[4][16];
    int blk = blockIdx.x;
    int tid = threadIdx.x;
    if (blk < 24) {                          // zero BN totals + loss accumulators
        bnt[blk * 256 + tid] = 0.f;
        if (blk == 0 && tid < 2) dout[OUT_CL + tid] = 0.f;
        return;
    }
    if (blk < 536) {                         // codebook transpose
        int idx = (blk - 24) * 256 + tid;
        int k = idx & 511, c = idx >> 9;
        cbT[idx] = cb[k * 256 + c];
        return;
    }
    if (blk >= 9400) {                       // enc0 direct conv (2048 blocks)
        conv_body(blk - 9400, tid, x, w0, b0, Y0, pst, cst);
        return;
    }
    int idx = (blk - 536) * 256 + tid;       // weight split+reorder
    if (idx >= 2269184) return;
    float v; int dst;
    if (idx < 131072) {                      // enc1: M=128 K=1024
        int m = idx >> 10, k = idx & 1023;
        v = w1[idx];
        dst = fragaddr(m, k, 1024);
    } else if (idx < 655360) {               // enc2: M=256 K=2048
        int i = idx - 131072;
        int m = i >> 11, k = i & 2047;
        v = w2[i];
        dst = 131072 + fragaddr(m, k, 2048);
    } else if (idx < 1703936) {              // enc3: M=256 K=4096
        int i = idx - 655360;
        int m = i >> 12, k = i & 4095;
        v = w3[i];
        dst = 655360 + fragaddr(m, k, 4096);
    } else if (idx < 2228224) {              // dec0: M=2048 K=256
        int i = idx - 1703936;
        int m = i >> 8, c = i & 255;
        int o = m & 127, ij = m >> 7;
        v = d0[((size_t)c * 128 + o) * 16 + ij];
        dst = 1703936 + fragaddr(m, c, 256);
    } else if (idx < 2260992) {              // dec1: M=256 K=128
        int i = idx - 2228224;
        int m = i >> 7, c = i & 127;
        int o = m & 63, ij = m >> 6;
        v = d1[((size_t)c * 64 + o) * 4 + ij];
        dst = 2228224 + fragaddr(m, c, 128);
    } else {                                 // dec2: M=128 K=64
        int i = idx - 2260992;
        int m = i >> 6, c = i & 63;
        int o = m & 31, ij = m >> 5;
        v = d2[((size_t)c * 32 + o) * 4 + ij];
        dst = 2260992 + fragaddr(m, c, 64);
    }
    HL s = split_bf16(v);
    WH[dst] = s.h; WL[dst] = s.l;
}

// ================= reduce partials + BN stats =================
__global__ void reduce_bias_stats4(const float4* __restrict__ P, const float* __restrict__ bias,
                                   float4* __restrict__ y, float* __restrict__ bnt,
                                   int outSize4, int KS, int Co, int HW4, int nch) {
    int tid = threadIdx.x;
    int i = blockIdx.x * 256 + tid;
    int c = (i / HW4) % Co;
    float bv = bias[c];
    float4 s = make_float4(bv, bv, bv, bv);
    for (int ks = 0; ks < KS; ++ks) {
        float4 p = P[(size_t)ks * outSize4 + i];
        s.x += p.x; s.y += p.y; s.z += p.z; s.w += p.w;
    }
    y[i] = s;
    float ls  = s.x + s.y + s.z + s.w;
    float ls2 = s.x * s.x + s.y * s.y + s.z * s.z + s.w * s.w;
    __shared__ float as[16], aq[16];
    if (tid < 16) { as[tid] = 0.f; aq[tid] = 0.f; }
    __syncthreads();
    int c0 = ((blockIdx.x * 256) / HW4) % Co;
    atomicAdd(&as[c - c0], ls);
    atomicAdd(&aq[c - c0], ls2);
    __syncthreads();
    if (tid < nch) {
        atomicAdd(&bnt[(c0 + tid) * 2],     as[tid]);
        atomicAdd(&bnt[(c0 + tid) * 2 + 1], aq[tid]);
    }
}

// ================= Vector quantizer: sums 16 enc3 partial slices on load; writes
// pre-split QH/QL bf16 [n][k] row-major for dec0 MODE2; fused loss =================
__global__ void vq_main(const float* __restrict__ Pz, const float* __restrict__ b3,
                        const float* __restrict__ cbT, const float* __restrict__ cb,
                        ushort* __restrict__ qhl, float* __restrict__ dout) {
    int r0 = blockIdx.x * 4;
    int tid = threadIdx.x;
    int lane = tid & 63, w = tid >> 6;

    __shared__ __align__(16) float zT[256][4];
    __shared__ float wred[4][4];
    __shared__ float zn2s[4];
    __shared__ float wbd[4][4];
    __shared__ int   wbi[4][4];
    __shared__ int   bestsh[4];
    __shared__ float bestd[4];

    int b = r0 >> 6, s0 = r0 & 63;
    size_t zi = ((size_t)(b * 256 + tid)) * 64 + s0;
    float bv = b3[tid];
    float4 zv = make_float4(bv, bv, bv, bv);
    const float4* pp = (const float4*)Pz + (zi >> 2);
#pragma unroll
    for (int ks = 0; ks < 16; ++ks) {
        float4 p = pp[(size_t)ks * 65536];
        zv.x += p.x; zv.y += p.y; zv.z += p.z; zv.w += p.w;
    }
    *(float4*)&zT[tid][0] = zv;

    // ---- per-row |z|^2 via butterfly sum over channels ----
    float p0 = zv.x * zv.x, p1 = zv.y * zv.y, p2 = zv.z * zv.z, p3 = zv.w * zv.w;
#pragma unroll
    for (int m2 = 1; m2 < 64; m2 <<= 1) {
        p0 += __shfl_xor(p0, m2); p1 += __shfl_xor(p1, m2);
        p2 += __shfl_xor(p2, m2); p3 += __shfl_xor(p3, m2);
    }
    if (lane == 0) { wred[w][0] = p0; wred[w][1] = p1; wred[w][2] = p2; wred[w][3] = p3; }
    __syncthreads();
    if (tid < 4) zn2s[tid] = wred[0][tid] + wred[1][tid] + wred[2][tid] + wred[3][tid];
    __syncthreads();

    // ---- dot products: thread owns codebook entries k=tid and k=tid+256 ----
    float d0[4], d1[4];
#pragma unroll
    for (int rr = 0; rr < 4; ++rr) { d0[rr] = 0.f; d1[rr] = 0.f; }
    float cn0 = 0.f, cn1 = 0.f;
#pragma unroll 4
    for (int c = 0; c < 256; ++c) {
        float cv0 = cbT[c * 512 + tid];
        float cv1 = cbT[c * 512 + 256 + tid];
        cn0 += cv0 * cv0;
        cn1 += cv1 * cv1;
        float4 za = *(const float4*)&zT[c][0];
        d0[0] += za.x * cv0; d1[0] += za.x * cv1;
        d0[1] += za.y * cv0; d1[1] += za.y * cv1;
        d0[2] += za.z * cv0; d1[2] += za.z * cv1;
        d0[3] += za.w * cv0; d1[3] += za.w * cv1;
    }

    // ---- argmin via butterfly (tie-break: smaller index) ----
#pragma unroll
    for (int rr = 0; rr < 4; ++rr) {
        float dist0 = zn2s[rr] - 2.f * d0[rr] + cn0;
        float dist1 = zn2s[rr] - 2.f * d1[rr] + cn1;
        float bd = dist0; int bi = tid;
        if (dist1 < bd) { bd = dist1; bi = tid + 256; }
#pragma unroll
        for (int m2 = 1; m2 < 64; m2 <<= 1) {
            float od = __shfl_xor(bd, m2); int oi = __shfl_xor(bi, m2);
            if (od < bd || (od == bd && oi < bi)) { bd = od; bi = oi; }
        }
        if (lane == 0) { wbd[w][rr] = bd; wbi[w][rr] = bi; }
    }
    __syncthreads();
    if (tid < 4) {
        float bd = wbd[0][tid]; int bi = wbi[0][tid];
#pragma unroll
        for (int ww = 1; ww < 4; ++ww) {
            float od = wbd[ww][tid]; int oi = wbi[ww][tid];
            if (od < bd || (od == bd && oi < bi)) { bd = od; bi = oi; }
        }
        bestsh[tid] = bi; bestd[tid] = bd;
        dout[OUT_IDX + r0 + tid]  = (float)bi;
        dout[OUT_MIND + r0 + tid] = bd;
    }
    __syncthreads();

    // ---- gather quantized rows, split to bf16 hi/lo, store [n][k] (n = r0+rr) ----
#pragma unroll
    for (int rr = 0; rr < 4; ++rr) {
        float v = cb[(size_t)bestsh[rr] * 256 + tid];
        HL s = split_bf16(v);
        size_t o = (size_t)(r0 + rr) * 256 + tid;
        qhl[o]          = s.h;
        qhl[262144 + o] = s.l;
    }
    if (tid == 0) {
        float ls = (bestd[0] + bestd[1] + bestd[2] + bestd[3]) * (1.f / 262144.f);
        atomicAdd(&dout[OUT_CL], ls);
        atomicAdd(&dout[OUT_CB], ls);
    }
}

// ================= Final: BN(D2, 8-banked stats) + LeakyReLU + 1x1 conv + tanh =================
__global__ void final_conv_tanh(const float* __restrict__ hbuf, const float* __restrict__ bnt,
                                const float* __restrict__ g, const float* __restrict__ bt,
                                const float* __restrict__ w3, const float* __restrict__ b3,
                                float* __restrict__ out) {
    __shared__ float sc[32], sh[32], sw[96];
    int tid = threadIdx.x;
    if (tid < 32) {
        float sm = 0.f, sq = 0.f;
#pragma unroll
        for (int bk = 0; bk < 8; ++bk) {
            sm += bnt[bk * 64 + tid * 2];
            sq += bnt[bk * 64 + tid * 2 + 1];
        }
        float m = sm * (1.f / 262144.f);
        float var = sq * (1.f / 262144.f) - m * m;
        float scale = g[tid] * rsqrtf(var + 1e-5f);
        sc[tid] = scale;
        sh[tid] = bt[tid] - m * scale;
    }
    if (tid < 96) sw[tid] = w3[tid];
    __syncthreads();
    int idx = blockIdx.x * 256 + tid;          // 65536 = 16 * 4096 float4 pixels
    int hw4 = idx & 4095;
    int b   = idx >> 12;
    const float4* hp = (const float4*)hbuf + ((size_t)b * 32) * 4096 + hw4;
    float b0 = b3[0], b1 = b3[1], b2 = b3[2];
    float4 a0 = make_float4(b0, b0, b0, b0);
    float4 a1 = make_float4(b1, b1, b1, b1);
    float4 a2 = make_float4(b2, b2, b2, b2);
#pragma unroll 8
    for (int c = 0; c < 32; ++c) {
        float4 v = hp[(size_t)c * 4096];
        float scv = sc[c], shv = sh[c];
        float vx = v.x * scv + shv; vx = vx >= 0.f ? vx : LEAK * vx;
        float vy = v.y * scv + shv; vy = vy >= 0.f ? vy : LEAK * vy;
        float vz = v.z * scv + shv; vz = vz >= 0.f ? vz : LEAK * vz;
        float vw = v.w * scv + shv; vw = vw >= 0.f ? vw : LEAK * vw;
        float w0 = sw[c], w1 = sw[32 + c], w2 = sw[64 + c];
        a0.x += vx * w0; a0.y += vy * w0; a0.z += vz * w0; a0.w += vw * w0;
        a1.x += vx * w1; a1.y += vy * w1; a1.z += vz * w1; a1.w += vw * w1;
        a2.x += vx * w2; a2.y += vy * w2; a2.z += vz * w2; a2.w += vw * w2;
    }
    float4* op = (float4*)out;
    size_t ob = ((size_t)b * 3) * 4096 + hw4;
    op[ob]            = make_float4(tanhf(a0.x), tanhf(a0.y), tanhf(a0.z), tanhf(a0.w));
    op[ob + 4096]     = make_float4(tanhf(a1.x), tanhf(a1.y), tanhf(a1.z), tanhf(a1.w));
    op[ob + 2 * 4096] = make_float4(tanhf(a2.x), tanhf(a2.y), tanhf(a2.z), tanhf(a2.w));
}

extern "C" void kernel_launch(void* const* d_in, const int* in_sizes, int n_in,
                              void* d_out, int out_size, void* d_ws, size_t ws_size,
                              hipStream_t stream) {
    const float* x      = (const float*)d_in[0];
    const float* enc_w0 = (const float*)d_in[1];
    const float* enc_b0 = (const float*)d_in[2];
    const float* enc_w1 = (const float*)d_in[3];
    const float* enc_b1 = (const float*)d_in[4];
    const float* enc_w2 = (const float*)d_in[5];
    const float* enc_b2 = (const float*)d_in[6];
    const float* enc_w3 = (const float*)d_in[7];
    const float* enc_b3 = (const float*)d_in[8];
    const float* ebn_g0 = (const float*)d_in[9];
    const float* ebn_b0 = (const float*)d_in[10];
    const float* ebn_g1 = (const float*)d_in[11];
    const float* ebn_b1 = (const float*)d_in[12];
    const float* ebn_g2 = (const float*)d_in[13];
    const float* ebn_b2 = (const float*)d_in[14];
    const float* cb     = (const float*)d_in[15];
    const float* dec_w0 = (const float*)d_in[16];
    const float* dec_b0 = (const float*)d_in[17];
    const float* dbn_g0 = (const float*)d_in[18];
    const float* dbn_b0 = (const float*)d_in[19];
    const float* dec_w1 = (const float*)d_in[20];
    const float* dec_b1 = (const float*)d_in[21];
    const float* dbn_g1 = (const float*)d_in[22];
    const float* dbn_b1 = (const float*)d_in[23];
    const float* dec_w2 = (const float*)d_in[24];
    const float* dec_b2 = (const float*)d_in[25];
    const float* dbn_g2 = (const float*)d_in[26];
    const float* dbn_b2 = (const float*)d_in[27];
    const float* dec_w3 = (const float*)d_in[28];
    const float* dec_b3 = (const float*)d_in[29];

    float* out = (float*)d_out;
    float* ws  = (float*)d_ws;

    // ---- workspace (float units) ----
    float*  Y0   = ws;                               // 4194304
    float*  Y1   = ws + 4194304;                     // 2097152
    float*  Y2   = ws + 6291456;                     // 1048576
    float*  PST  = ws + 7340032;                     // 32768 (conv BN0 partials)
    float*  QHL  = ws + 7602176;                     // 262144 fl = 524288 us (QH | QL)
    ushort* WH   = (ushort*)(ws + 7864320);          // 2269184 us
    ushort* WL   = (ushort*)(ws + 8998912);          // 2269184 us
    float*  CBT  = ws + 10133504;                    // 131072
    float*  BNT  = ws + 10264576;                    // 6144 (incl. 8-banked dec1/dec2 stats)
    float*  PART = ws + 10270720;                    // 8388608
    float*  D0   = ws + 18659328;                    // 2097152
    float*  D1   = ws + 20756480;                    // 4194304
    float*  D2   = ws + 24950784;                    // 8388608

    dim3 blk(256);

    // ---- prologue: zero BNT/losses + cbT + weight prep + enc0 conv (fused, independent) ----
    prologue<<<11448, blk, 0, stream>>>(enc_w1, enc_w2, enc_w3, dec_w0, dec_w1, dec_w2,
                                        WH, WL, cb, CBT, BNT, out,
                                        x, enc_w0, enc_b0, Y0, PST);

    // enc1: M=128 N=16384 K=1024, KS=2, 32N tiles -> 1024 blocks; BN0 from PST
    gemm_mfma<0><<<1024, blk, 0, stream>>>(WH, WL, Y0,
        nullptr, ebn_g0, ebn_b0, 1.f / 65536.f, 4, enc_b1, PART,
        1, 512, 1024, 512, 2, 2097152, 64, 64, 128, 32, 5, 0, 0, 0, 0, nullptr, PST, 0, 0);
    reduce_bias_stats4<<<2048, blk, 0, stream>>>((const float4*)PART, enc_b1, (float4*)Y1,
                                                 BNT + 1024, 524288, 2, 128, 256, 1);

    // enc2: M=256 N=4096 K=2048, KS=4, 32N tiles -> 1024 blocks; B=Y1 raw + BN1
    gemm_mfma<0><<<1024, blk, 0, stream>>>(WH + 131072, WL + 131072, Y1,
        BNT + 1024, ebn_g1, ebn_b1, 1.f / 16384.f, 4, enc_b2, PART,
        2, 128, 2048, 512, 4, 1048576, 128, 32, 256, 16, 4, 0, 0, 0, 0, nullptr, nullptr, 0, 0);
    reduce_bias_stats4<<<1024, blk, 0, stream>>>((const float4*)PART, enc_b2, (float4*)Y2,
                                                 BNT + 2048, 262144, 4, 256, 64, 4);

    // enc3: M=256 N=1024 K=4096, KS=16, 32N tiles -> 1024 blocks; partials -> VQ
    gemm_mfma<0><<<1024, blk, 0, stream>>>(WH + 655360, WL + 655360, Y2,
        BNT + 2048, ebn_g2, ebn_b2, 1.f / 4096.f, 4, enc_b3, PART,
        2, 32, 4096, 256, 16, 262144, 256, 16, 256, 8, 3, 0, 0, 0, 0, nullptr, nullptr, 0, 0);

    // ---- VQ: sums 16 partial slices + bias; emits pre-split QH/QL; fused loss ----
    vq_main<<<256, blk, 0, stream>>>(PART, enc_b3, CBT, cb, (ushort*)QHL, out);

    // ---- decoder ----
    // dec0: M=2048 N=1024 K=256, KS=2, 32N tiles -> 1024 blocks; MODE2 pre-split B
    gemm_mfma<2><<<1024, blk, 0, stream>>>(WH + 1703936, WL + 1703936, QHL,
        nullptr, nullptr, nullptr, 0.f, 0, dec_b0, PART,
        16, 32, 256, 128, 2, 2097152, 256, 8, 128, 262144, 0, 6, 3, 7, 2, nullptr, nullptr, 0, 0);
    reduce_bias_stats4<<<2048, blk, 0, stream>>>((const float4*)PART, dec_b0, (float4*)D0,
                                                 BNT + 3072, 524288, 2, 128, 256, 1);

    // dec1: M=256 N=16384 K=128, KS=1, 32N tiles -> 1024 blocks; direct D1 + banked stats
    gemm_mfma<1><<<1024, blk, 0, stream>>>(WH + 2228224, WL + 2228224, D0,
        BNT + 3072, dbn_g0, dbn_b0, 1.f / 16384.f, 0, dec_b1, D1,
        2, 512, 128, 128, 1, 0, 128, 32, 64, 0, 0, 10, 5, 6, 1, BNT + 4096, nullptr, 128, 0);

    // dec2: M=128 N=65536 K=64, KS=1, 32N tiles -> 2048 blocks; banked stats in+out
    gemm_mfma<1><<<2048, blk, 0, stream>>>(WH + 2260992, WL + 2260992, D1,
        BNT + 4096, dbn_g1, dbn_b1, 1.f / 65536.f, 0, dec_b2, D2,
        1, 2048, 64, 64, 1, 0, 64, 64, 32, 0, 0, 12, 6, 5, 1, BNT + 5120, nullptr, 64, 128);

    // final: BN5 (8 banks) + leaky + 1x1 conv + tanh (float4)
    final_conv_tanh<<<256, blk, 0, stream>>>(D2, BNT + 5120, dbn_g2, dbn_b2, dec_w3, dec_b3, out);
}

// Round 8
// 380.082 us; speedup vs baseline: 1.0374x; 1.0374x over previous
//
#include <hip/hip_runtime.h>
#include <math.h>

#define LEAK 0.01f

typedef __bf16 bf16x8 __attribute__((ext_vector_type(8)));
typedef float f32x4 __attribute__((ext_vector_type(4)));
typedef unsigned short ushort;
typedef unsigned int uint32;

struct HL { ushort h, l; };

// split fp32 into bf16 hi + bf16 lo (both RNE): x ~= hi + lo, err ~2^-17 rel
__device__ inline HL split_bf16(float x) {
    unsigned u = __float_as_uint(x);
    unsigned hr = (u + 0x7FFFu + ((u >> 16) & 1u)) >> 16;
    float fh = __uint_as_float(hr << 16);
    float r = x - fh;
    unsigned v = __float_as_uint(r);
    unsigned lr = (v + 0x7FFFu + ((v >> 16) & 1u)) >> 16;
    HL out; out.h = (ushort)hr; out.l = (ushort)lr;
    return out;
}

// ============ staged-B raw load: 32n x 64k fp32 tile, 8 floats/thread (2 k-halves) ============
// r8: N-MAJOR lane mapping (nl = tid&31, kg = tid>>5). Consecutive lanes walk
// consecutive n -> MODE0 gather = stride-2 runs (~8 lines/load vs 64), MODE1 =
// contiguous 128B runs (~4 lines/load vs 64). The old k-major mapping made every
// staging load a 64-distinct-line gather, serializing the CU's TA pipe (~64cy per
// load instruction, invisible in VALUBusy) — the r6/r7 null results' explanation.
template<int MODE>
__device__ inline void stage_load(float (&pv)[2][4], const float* __restrict__ Bf,
                                  int kbase, int n0, int tid,
                                  int Ci, int Hin, int Ho, int lgHo, int lgHW) {
    int nl = tid & 31, kg = tid >> 5;
    int n = n0 + nl;
#pragma unroll
    for (int r = 0; r < 2; ++r) {
        if (MODE == 0) {
            int k4 = kbase + (r << 5) + (kg << 2);
            int ic = k4 >> 4, kh = (k4 >> 2) & 3;
            int ow = n & (Ho - 1), oh = (n >> lgHo) & (Ho - 1), b = n >> (lgHo + lgHo);
            int ih = oh * 2 - 1 + kh;
            int ihc = ih < 0 ? 0 : (ih >= Hin ? Hin - 1 : ih);
            int iwb = ow * 2 - 1;
            size_t base = ((size_t)(b * Ci + ic) * Hin + ihc) * Hin;
#pragma unroll
            for (int e = 0; e < 4; ++e) {
                int iw = iwb + e;
                int iwc = iw < 0 ? 0 : (iw >= Hin ? Hin - 1 : iw);
                pv[r][e] = Bf[base + iwc];
            }
        } else {
            int c = kbase + (r << 5) + (kg << 2);
            int b = n >> lgHW, hw = n & ((1 << lgHW) - 1);
            size_t base = (((size_t)(b * Ci + c)) << lgHW) + hw;
            size_t str = (size_t)1 << lgHW;
#pragma unroll
            for (int e = 0; e < 4; ++e) pv[r][e] = Bf[base + e * str];
        }
    }
}

// ================= bf16-split MFMA GEMM with fused BN+LeakyReLU on B-load =================
// Block tile 128M x 32N, 4 waves of 32M x 32N. K-step 64.
// MODE 0: conv-im2col B; MODE 1: channel-major B; MODE 2: PRE-SPLIT B from global
//   (QH/QL bf16 [n][k] row-major; Ci = K stride, Ho = QL ushort offset) — no
//   staging/transform/LDS/barriers in the K-loop (keeps 32-K steps).
// statsBnt != nullptr (KS==1): fused per-channel sum/sumsq atomics, 8-way banked.
// bntBankStride > 0: input bnt is 8-banked; sum banks in prologue.
// NOTE (r2): never replicate B transform across Mtiles. NOTE (r4): split-K multiplies
// per-block fixed cost. NOTE (r6): occupancy not the limiter. NOTE (r8): staging
// lane-coalescing (lines per load instruction) WAS the limiter candidate — n-major map.
template<int MODE>
__global__ __launch_bounds__(256, 3) void gemm_mfma(
    const ushort* __restrict__ Ah, const ushort* __restrict__ Al,
    const float* __restrict__ Bf,
    const float* __restrict__ bnt, const float* __restrict__ gamma,
    const float* __restrict__ beta, float invN, int chanShift,
    const float* __restrict__ bias, float* __restrict__ P,
    int Mtiles, int Ntiles, int K, int Kslice, int KS, int outSize,
    int Ci, int Hin, int Co, int Ho, int lgHo,
    int lgHW, int lgHin, int lgCo, int lgk,
    float* __restrict__ statsBnt, const float* __restrict__ bnPart,
    int statsBank, int bntBankStride)
{
    __shared__ __align__(16) uint32 Bsp[32 * 68];   // [n][64k] packed, stride 68
    __shared__ float scs[256], shs[256];

    int bid = blockIdx.x;
    int ntile = bid % Ntiles; bid /= Ntiles;
    int mtile = bid % Mtiles;
    int ks = bid / Mtiles;
    int tid = threadIdx.x;
    int lane = tid & 63, w = tid >> 6;
    int quad = lane >> 4, tl = lane & 15;
    int n0 = ntile << 5, m0 = mtile << 7, k0 = ks * Kslice;
    int Kt = K >> 5;

    bool useBN = (bnt != nullptr) || (bnPart != nullptr);
    int c0 = k0 >> chanShift;
    if (bnPart != nullptr) {
        // BN0 from conv tile-partials: 64 channels x 256 (sum,sq) pairs
        int c = tid >> 2, qq = tid & 3;
        const float2* pp2 = (const float2*)(bnPart + c * 512) + qq * 64;
        float s = 0.f, s2 = 0.f;
#pragma unroll 8
        for (int p = 0; p < 64; ++p) { float2 v = pp2[p]; s += v.x; s2 += v.y; }
        scs[tid] = s; shs[tid] = s2;
        __syncthreads();
        float scale = 0.f, shift = 0.f;
        if (tid < 64) {
            float st = scs[tid * 4] + scs[tid * 4 + 1] + scs[tid * 4 + 2] + scs[tid * 4 + 3];
            float qt = shs[tid * 4] + shs[tid * 4 + 1] + shs[tid * 4 + 2] + shs[tid * 4 + 3];
            float m = st * invN;
            float var = qt * invN - m * m;
            scale = gamma[tid] * rsqrtf(var + 1e-5f);
            shift = beta[tid] - m * scale;
        }
        __syncthreads();
        // store shifted so the transform's scs[ic - c0] indexing works for any K-slice
        if (tid < 64 && tid >= c0) { scs[tid - c0] = scale; shs[tid - c0] = shift; }
    } else if (bnt != nullptr) {
        int nch = Kslice >> chanShift;
        for (int c = tid; c < nch; c += 256) {
            float sm, sq;
            if (bntBankStride > 0) {
                sm = 0.f; sq = 0.f;
#pragma unroll
                for (int bk = 0; bk < 8; ++bk) {
                    sm += bnt[bk * bntBankStride + (c0 + c) * 2];
                    sq += bnt[bk * bntBankStride + (c0 + c) * 2 + 1];
                }
            } else {
                sm = bnt[(c0 + c) * 2];
                sq = bnt[(c0 + c) * 2 + 1];
            }
            float m = sm * invN;
            float var = sq * invN - m * m;
            float scale = gamma[c0 + c] * rsqrtf(var + 1e-5f);
            scs[c] = scale;
            shs[c] = beta[c0 + c] - m * scale;
        }
    }
    __syncthreads();

    f32x4 zero4 = {0.f, 0.f, 0.f, 0.f};
    f32x4 acc[2][2];
#pragma unroll
    for (int mt = 0; mt < 2; ++mt)
#pragma unroll
        for (int nt = 0; nt < 2; ++nt) acc[mt][nt] = zero4;

    if (MODE == 2) {
        // ---- barrier-free K-loop: B pre-split in global (L2-resident) ----
        const ushort* Bu = (const ushort*)Bf;
        for (int kc = 0; kc < Kslice; kc += 32) {
            int kbase = k0 + kc;
            int kt = kbase >> 5;
            bf16x8 afh[2], afl[2];
#pragma unroll
            for (int mt = 0; mt < 2; ++mt) {
                int mtAbs = (m0 >> 4) + (w << 1) + mt;
                size_t abase = (((size_t)mtAbs * Kt + kt) << 6) + lane;
                afh[mt] = *(const bf16x8*)(Ah + abase * 8);
                afl[mt] = *(const bf16x8*)(Al + abase * 8);
            }
            bf16x8 bfh[2], bfl[2];
#pragma unroll
            for (int nt = 0; nt < 2; ++nt) {
                int n = n0 + (nt << 4) + tl;
                size_t ba = (size_t)n * Ci + kbase + (quad << 3);
                bfh[nt] = *(const bf16x8*)(Bu + ba);
                bfl[nt] = *(const bf16x8*)(Bu + Ho + ba);
            }
#pragma unroll
            for (int mt = 0; mt < 2; ++mt)
#pragma unroll
                for (int nt = 0; nt < 2; ++nt) {
                    acc[mt][nt] = __builtin_amdgcn_mfma_f32_16x16x32_bf16(afh[mt], bfh[nt], acc[mt][nt], 0, 0, 0);
                    acc[mt][nt] = __builtin_amdgcn_mfma_f32_16x16x32_bf16(afh[mt], bfl[nt], acc[mt][nt], 0, 0, 0);
                    acc[mt][nt] = __builtin_amdgcn_mfma_f32_16x16x32_bf16(afl[mt], bfh[nt], acc[mt][nt], 0, 0, 0);
                }
        }
    } else {
        // ---- staged K-loop, BK=64: stage/transform 32n x 64k per barrier pair ----
        float pv[2][4];
        stage_load<MODE>(pv, Bf, k0, n0, tid, Ci, Hin, Ho, lgHo, lgHW);

        for (int kc = 0; kc < Kslice; kc += 64) {
            int kbase = k0 + kc;
            // ---- transform both k-halves + regs -> LDS (n-major lane map, r8) ----
            int nl = tid & 31, kg = tid >> 5;
#pragma unroll
            for (int r = 0; r < 2; ++r) {
                int k4 = kbase + (r << 5) + (kg << 2);
                uint32 pk[4];
                if (MODE == 0) {
                    int ic = k4 >> 4, kh = (k4 >> 2) & 3;
                    int n = n0 + nl;
                    int ow = n & (Ho - 1), oh = (n >> lgHo) & (Ho - 1);
                    int ih = oh * 2 - 1 + kh;
                    bool rowok = (unsigned)ih < (unsigned)Hin;
                    int iwb = ow * 2 - 1;
                    float sc_ = useBN ? scs[ic - c0] : 0.f;
                    float sh_ = useBN ? shs[ic - c0] : 0.f;
#pragma unroll
                    for (int e = 0; e < 4; ++e) {
                        int iw = iwb + e;
                        bool ok = rowok && ((unsigned)iw < (unsigned)Hin);
                        float f = pv[r][e];
                        if (useBN) { f = f * sc_ + sh_; f = f >= 0.f ? f : LEAK * f; }
                        if (!ok) f = 0.f;
                        HL s = split_bf16(f);
                        pk[e] = ((uint32)s.h << 16) | s.l;
                    }
                } else {
#pragma unroll
                    for (int e = 0; e < 4; ++e) {
                        float f = pv[r][e];
                        if (useBN) {
                            int lc = k4 + e - k0;
                            f = f * scs[lc] + shs[lc];
                            f = f >= 0.f ? f : LEAK * f;
                        }
                        HL s = split_bf16(f);
                        pk[e] = ((uint32)s.h << 16) | s.l;
                    }
                }
                *(uint4*)&Bsp[nl * 68 + (r << 5) + (kg << 2)] = make_uint4(pk[0], pk[1], pk[2], pk[3]);
            }
            __syncthreads();

            // ---- prefetch next 64-K tile (raw; latency hidden under 24 MFMAs) ----
            bool more = (kc + 64) < Kslice;
            float pvn[2][4];
            if (more) stage_load<MODE>(pvn, Bf, kbase + 64, n0, tid, Ci, Hin, Ho, lgHo, lgHW);

            // ---- two 32-K substeps from LDS ----
#pragma unroll
            for (int sub = 0; sub < 2; ++sub) {
                int kt = (kbase >> 5) + sub;
                bf16x8 afh[2], afl[2];
#pragma unroll
                for (int mt = 0; mt < 2; ++mt) {
                    int mtAbs = (m0 >> 4) + (w << 1) + mt;
                    size_t abase = (((size_t)mtAbs * Kt + kt) << 6) + lane;
                    afh[mt] = *(const bf16x8*)(Ah + abase * 8);
                    afl[mt] = *(const bf16x8*)(Al + abase * 8);
                }
                bf16x8 bfh[2], bfl[2];
#pragma unroll
                for (int nt = 0; nt < 2; ++nt) {
                    int base = ((nt << 4) + tl) * 68 + (sub << 5) + (quad << 3);
                    uint4 ua = *(const uint4*)&Bsp[base];
                    uint4 ub = *(const uint4*)&Bsp[base + 4];
                    union { uint32 u[4]; bf16x8 v; } H, L;
                    H.u[0] = __builtin_amdgcn_perm(ua.y, ua.x, 0x07060302u);
                    H.u[1] = __builtin_amdgcn_perm(ua.w, ua.z, 0x07060302u);
                    H.u[2] = __builtin_amdgcn_perm(ub.y, ub.x, 0x07060302u);
                    H.u[3] = __builtin_amdgcn_perm(ub.w, ub.z, 0x07060302u);
                    L.u[0] = __builtin_amdgcn_perm(ua.y, ua.x, 0x05040100u);
                    L.u[1] = __builtin_amdgcn_perm(ua.w, ua.z, 0x05040100u);
                    L.u[2] = __builtin_amdgcn_perm(ub.y, ub.x, 0x05040100u);
                    L.u[3] = __builtin_amdgcn_perm(ub.w, ub.z, 0x05040100u);
                    bfh[nt] = H.v; bfl[nt] = L.v;
                }
#pragma unroll
                for (int mt = 0; mt < 2; ++mt)
#pragma unroll
                    for (int nt = 0; nt < 2; ++nt) {
                        acc[mt][nt] = __builtin_amdgcn_mfma_f32_16x16x32_bf16(afh[mt], bfh[nt], acc[mt][nt], 0, 0, 0);
                        acc[mt][nt] = __builtin_amdgcn_mfma_f32_16x16x32_bf16(afh[mt], bfl[nt], acc[mt][nt], 0, 0, 0);
                        acc[mt][nt] = __builtin_amdgcn_mfma_f32_16x16x32_bf16(afl[mt], bfh[nt], acc[mt][nt], 0, 0, 0);
                    }
            }
            __syncthreads();
            if (more) {
#pragma unroll
                for (int r = 0; r < 2; ++r)
#pragma unroll
                    for (int e = 0; e < 4; ++e) pv[r][e] = pvn[r][e];
            }
        }
    }

    // ---- epilogue: D[m = quad*4+reg][n = tl] + optional fused stats (KS==1 paths) ----
    bool doStats = (statsBnt != nullptr);
    if (doStats) {
        if (tid < 2 * Co) scs[tid] = 0.f;
        __syncthreads();
    }
    float ssum[2][4] = {{0.f,0.f,0.f,0.f},{0.f,0.f,0.f,0.f}};
    float ssq [2][4] = {{0.f,0.f,0.f,0.f},{0.f,0.f,0.f,0.f}};
    float* dst = P + (size_t)ks * outSize;
    if (MODE == 0) {
#pragma unroll
        for (int nt = 0; nt < 2; ++nt) {
            int n = n0 + (nt << 4) + tl;
            int ow = n & (Ho - 1), oh = (n >> lgHo) & (Ho - 1), b = n >> (lgHo + lgHo);
#pragma unroll
            for (int mt = 0; mt < 2; ++mt) {
                int mb = m0 + (w << 5) + (mt << 4) + (quad << 2);
#pragma unroll
                for (int r = 0; r < 4; ++r) {
                    int oc = mb + r;
                    float v = acc[mt][nt][r];
                    if (KS == 1) v += bias[oc];
                    if (doStats) { ssum[mt][r] += v; ssq[mt][r] += v * v; }
                    dst[((size_t)(b * Co + oc) * Ho + oh) * Ho + ow] = v;
                }
            }
        }
    } else {
        int kf = 1 << lgk;
        int Ho2 = Hin << lgk;
#pragma unroll
        for (int nt = 0; nt < 2; ++nt) {
            int n = n0 + (nt << 4) + tl;
            int b = n >> lgHW, hw = n & ((1 << lgHW) - 1);
            int h = hw >> lgHin, wp = hw & (Hin - 1);
#pragma unroll
            for (int mt = 0; mt < 2; ++mt) {
                int mb = m0 + (w << 5) + (mt << 4) + (quad << 2);
#pragma unroll
                for (int r = 0; r < 4; ++r) {
                    int m = mb + r;
                    int o = m & (Co - 1), ij = m >> lgCo;
                    int ii = ij >> lgk, jj = ij & (kf - 1);
                    float v = acc[mt][nt][r];
                    if (KS == 1) v += bias[o];
                    if (doStats) { ssum[mt][r] += v; ssq[mt][r] += v * v; }
                    dst[((size_t)(b * Co + o) * Ho2 + (h << lgk) + ii) * Ho2 + (wp << lgk) + jj] = v;
                }
            }
        }
    }
    if (doStats) {
        // reduce over the 16 lanes (tl) sharing identical channels
#pragma unroll
        for (int mt = 0; mt < 2; ++mt)
#pragma unroll
            for (int r = 0; r < 4; ++r) {
                float s = ssum[mt][r], q2 = ssq[mt][r];
#pragma unroll
                for (int m2 = 1; m2 < 16; m2 <<= 1) {
                    s  += __shfl_xor(s,  m2);
                    q2 += __shfl_xor(q2, m2);
                }
                if (tl == 0) {
                    int m = m0 + (w << 5) + (mt << 4) + (quad << 2) + r;
                    int o = (MODE == 0) ? m : (m & (Co - 1));
                    atomicAdd(&scs[o * 2],     s);
                    atomicAdd(&scs[o * 2 + 1], q2);
                }
            }
        __syncthreads();
        float* sb = statsBnt + (blockIdx.x & 7) * statsBank;
        if (tid < 2 * Co) atomicAdd(&sb[tid], scs[tid]);
    }
}

// ================= weight prep address =================
__device__ inline int fragaddr(int m, int k, int K) {
    return ((((m >> 4) * (K >> 5) + (k >> 5)) << 9) | (((k >> 3) & 3) << 7) | ((m & 15) << 3) | (k & 7));
}

#define OUT_CL   786432
#define OUT_CB   786433
#define OUT_IDX  786434
#define OUT_MIND 787458

// ================= enc0 direct conv (Ci=3) with non-atomic per-tile BN stat partials =================
__device__ void conv_body(int bid, int tid,
                          const float* __restrict__ x, const float* __restrict__ w,
                          const float* __restrict__ bias, float* __restrict__ P,
                          float* __restrict__ pst, float (&cst)[4][16])
{
    const int Ci = 3, Hin = 128, Co = 64, Ho = 64, OCT = 8;
    int ntile = (16 * Ho * Ho) >> 8;          // 256
    int tile = bid % ntile;
    int og = bid / ntile;
    int oc0 = og * OCT;

    int px = (tile << 8) + tid;
    int ow = px % Ho; int t = px / Ho;
    int oh = t % Ho;  int b = t / Ho;

    int off[16]; float fm[16];
    int ih0 = oh * 2 - 1, iw0 = ow * 2 - 1;
#pragma unroll
    for (int kh = 0; kh < 4; ++kh)
#pragma unroll
        for (int kw = 0; kw < 4; ++kw) {
            int ih = ih0 + kh, iw = iw0 + kw;
            bool ok = (ih >= 0) && (ih < Hin) && (iw >= 0) && (iw < Hin);
            int ihc = ih < 0 ? 0 : (ih >= Hin ? Hin - 1 : ih);
            int iwc = iw < 0 ? 0 : (iw >= Hin ? Hin - 1 : iw);
            off[kh * 4 + kw] = ihc * Hin + iwc;
            fm[kh * 4 + kw] = ok ? 1.f : 0.f;
        }

    float acc[OCT];
#pragma unroll
    for (int u = 0; u < OCT; ++u) acc[u] = bias[oc0 + u];

    const float* xc = x + (size_t)b * Ci * Hin * Hin;
    const float* wi = w + (size_t)oc0 * Ci * 16;
    int HinHin = Hin * Hin;
    for (int ic = 0; ic < Ci; ++ic) {
        float xv[16];
#pragma unroll
        for (int q = 0; q < 16; ++q) xv[q] = xc[off[q]] * fm[q];
#pragma unroll
        for (int u = 0; u < OCT; ++u) {
            const float* wo = wi + (size_t)u * Ci * 16;
            float a = acc[u];
#pragma unroll
            for (int q = 0; q < 16; ++q) a += xv[q] * wo[q];
            acc[u] = a;
        }
        xc += HinHin;
        wi += 16;
    }
    size_t obase = (((size_t)b * Co + oc0) * Ho + oh) * Ho + ow;
    size_t opl = (size_t)Ho * Ho;
#pragma unroll
    for (int u = 0; u < OCT; ++u) P[obase + u * opl] = acc[u];

    // ---- BN stat partials: butterfly over 64 lanes, combine 4 waves, plain store ----
    float sv[OCT], qv[OCT];
#pragma unroll
    for (int u = 0; u < OCT; ++u) { sv[u] = acc[u]; qv[u] = acc[u] * acc[u]; }
#pragma unroll
    for (int m2 = 1; m2 < 64; m2 <<= 1)
#pragma unroll
        for (int u = 0; u < OCT; ++u) {
            sv[u] += __shfl_xor(sv[u], m2);
            qv[u] += __shfl_xor(qv[u], m2);
        }
    int lane = tid & 63, wv = tid >> 6;
    if (lane == 0) {
#pragma unroll
        for (int u = 0; u < OCT; ++u) { cst[wv][u * 2] = sv[u]; cst[wv][u * 2 + 1] = qv[u]; }
    }
    __syncthreads();
    if (tid < 2 * OCT) {
        float v = cst[0][tid] + cst[1][tid] + cst[2][tid] + cst[3][tid];
        pst[(oc0 + (tid >> 1)) * 512 + tile * 2 + (tid & 1)] = v;
    }
}

// ================= fused prologue: zero BNT/losses + cbT + weight prep + enc0 conv =================
__global__ void prologue(const float* __restrict__ w1, const float* __restrict__ w2,
                         const float* __restrict__ w3, const float* __restrict__ d0,
                         const float* __restrict__ d1, const float* __restrict__ d2,
                         ushort* __restrict__ WH, ushort* __restrict__ WL,
                         const float* __restrict__ cb, float* __restrict__ cbT,
                         float* __restrict__ bnt, float* __restrict__ dout,
                         const float* __restrict__ x, const float* __restrict__ w0,
                         const float* __restrict__ b0, float* __restrict__ Y0,
                         float* __restrict__ pst) {
    __shared__ float cst[4][16];
    int blk = blockIdx.x;
    int tid = threadIdx.x;
    if (blk < 24) {                          // zero BN totals + loss accumulators
        bnt[blk * 256 + tid] = 0.f;
        if (blk == 0 && tid < 2) dout[OUT_CL + tid] = 0.f;
        return;
    }
    if (blk < 536) {                         // codebook transpose
        int idx = (blk - 24) * 256 + tid;
        int k = idx & 511, c = idx >> 9;
        cbT[idx] = cb[k * 256 + c];
        return;
    }
    if (blk >= 9400) {                       // enc0 direct conv (2048 blocks)
        conv_body(blk - 9400, tid, x, w0, b0, Y0, pst, cst);
        return;
    }
    int idx = (blk - 536) * 256 + tid;       // weight split+reorder
    if (idx >= 2269184) return;
    float v; int dst;
    if (idx < 131072) {                      // enc1: M=128 K=1024
        int m = idx >> 10, k = idx & 1023;
        v = w1[idx];
        dst = fragaddr(m, k, 1024);
    } else if (idx < 655360) {               // enc2: M=256 K=2048
        int i = idx - 131072;
        int m = i >> 11, k = i & 2047;
        v = w2[i];
        dst = 131072 + fragaddr(m, k, 2048);
    } else if (idx < 1703936) {              // enc3: M=256 K=4096
        int i = idx - 655360;
        int m = i >> 12, k = i & 4095;
        v = w3[i];
        dst = 655360 + fragaddr(m, k, 4096);
    } else if (idx < 2228224) {              // dec0: M=2048 K=256
        int i = idx - 1703936;
        int m = i >> 8, c = i & 255;
        int o = m & 127, ij = m >> 7;
        v = d0[((size_t)c * 128 + o) * 16 + ij];
        dst = 1703936 + fragaddr(m, c, 256);
    } else if (idx < 2260992) {              // dec1: M=256 K=128
        int i = idx - 2228224;
        int m = i >> 7, c = i & 127;
        int o = m & 63, ij = m >> 6;
        v = d1[((size_t)c * 64 + o) * 4 + ij];
        dst = 2228224 + fragaddr(m, c, 128);
    } else {                                 // dec2: M=128 K=64
        int i = idx - 2260992;
        int m = i >> 6, c = i & 63;
        int o = m & 31, ij = m >> 5;
        v = d2[((size_t)c * 32 + o) * 4 + ij];
        dst = 2260992 + fragaddr(m, c, 64);
    }
    HL s = split_bf16(v);
    WH[dst] = s.h; WL[dst] = s.l;
}

// ================= reduce partials + BN stats =================
__global__ void reduce_bias_stats4(const float4* __restrict__ P, const float* __restrict__ bias,
                                   float4* __restrict__ y, float* __restrict__ bnt,
                                   int outSize4, int KS, int Co, int HW4, int nch) {
    int tid = threadIdx.x;
    int i = blockIdx.x * 256 + tid;
    int c = (i / HW4) % Co;
    float bv = bias[c];
    float4 s = make_float4(bv, bv, bv, bv);
    for (int ks = 0; ks < KS; ++ks) {
        float4 p = P[(size_t)ks * outSize4 + i];
        s.x += p.x; s.y += p.y; s.z += p.z; s.w += p.w;
    }
    y[i] = s;
    float ls  = s.x + s.y + s.z + s.w;
    float ls2 = s.x * s.x + s.y * s.y + s.z * s.z + s.w * s.w;
    __shared__ float as[16], aq[16];
    if (tid < 16) { as[tid] = 0.f; aq[tid] = 0.f; }
    __syncthreads();
    int c0 = ((blockIdx.x * 256) / HW4) % Co;
    atomicAdd(&as[c - c0], ls);
    atomicAdd(&aq[c - c0], ls2);
    __syncthreads();
    if (tid < nch) {
        atomicAdd(&bnt[(c0 + tid) * 2],     as[tid]);
        atomicAdd(&bnt[(c0 + tid) * 2 + 1], aq[tid]);
    }
}

// ================= Vector quantizer: sums 16 enc3 partial slices on load; writes
// pre-split QH/QL bf16 [n][k] row-major for dec0 MODE2; fused loss =================
__global__ void vq_main(const float* __restrict__ Pz, const float* __restrict__ b3,
                        const float* __restrict__ cbT, const float* __restrict__ cb,
                        ushort* __restrict__ qhl, float* __restrict__ dout) {
    int r0 = blockIdx.x * 4;
    int tid = threadIdx.x;
    int lane = tid & 63, w = tid >> 6;

    __shared__ __align__(16) float zT[256][4];
    __shared__ float wred[4][4];
    __shared__ float zn2s[4];
    __shared__ float wbd[4][4];
    __shared__ int   wbi[4][4];
    __shared__ int   bestsh[4];
    __shared__ float bestd[4];

    int b = r0 >> 6, s0 = r0 & 63;
    size_t zi = ((size_t)(b * 256 + tid)) * 64 + s0;
    float bv = b3[tid];
    float4 zv = make_float4(bv, bv, bv, bv);
    const float4* pp = (const float4*)Pz + (zi >> 2);
#pragma unroll
    for (int ks = 0; ks < 16; ++ks) {
        float4 p = pp[(size_t)ks * 65536];
        zv.x += p.x; zv.y += p.y; zv.z += p.z; zv.w += p.w;
    }
    *(float4*)&zT[tid][0] = zv;

    // ---- per-row |z|^2 via butterfly sum over channels ----
    float p0 = zv.x * zv.x, p1 = zv.y * zv.y, p2 = zv.z * zv.z, p3 = zv.w * zv.w;
#pragma unroll
    for (int m2 = 1; m2 < 64; m2 <<= 1) {
        p0 += __shfl_xor(p0, m2); p1 += __shfl_xor(p1, m2);
        p2 += __shfl_xor(p2, m2); p3 += __shfl_xor(p3, m2);
    }
    if (lane == 0) { wred[w][0] = p0; wred[w][1] = p1; wred[w][2] = p2; wred[w][3] = p3; }
    __syncthreads();
    if (tid < 4) zn2s[tid] = wred[0][tid] + wred[1][tid] + wred[2][tid] + wred[3][tid];
    __syncthreads();

    // ---- dot products: thread owns codebook entries k=tid and k=tid+256 ----
    float d0[4], d1[4];
#pragma unroll
    for (int rr = 0; rr < 4; ++rr) { d0[rr] = 0.f; d1[rr] = 0.f; }
    float cn0 = 0.f, cn1 = 0.f;
#pragma unroll 4
    for (int c = 0; c < 256; ++c) {
        float cv0 = cbT[c * 512 + tid];
        float cv1 = cbT[c * 512 + 256 + tid];
        cn0 += cv0 * cv0;
        cn1 += cv1 * cv1;
        float4 za = *(const float4*)&zT[c][0];
        d0[0] += za.x * cv0; d1[0] += za.x * cv1;
        d0[1] += za.y * cv0; d1[1] += za.y * cv1;
        d0[2] += za.z * cv0; d1[2] += za.z * cv1;
        d0[3] += za.w * cv0; d1[3] += za.w * cv1;
    }

    // ---- argmin via butterfly (tie-break: smaller index) ----
#pragma unroll
    for (int rr = 0; rr < 4; ++rr) {
        float dist0 = zn2s[rr] - 2.f * d0[rr] + cn0;
        float dist1 = zn2s[rr] - 2.f * d1[rr] + cn1;
        float bd = dist0; int bi = tid;
        if (dist1 < bd) { bd = dist1; bi = tid + 256; }
#pragma unroll
        for (int m2 = 1; m2 < 64; m2 <<= 1) {
            float od = __shfl_xor(bd, m2); int oi = __shfl_xor(bi, m2);
            if (od < bd || (od == bd && oi < bi)) { bd = od; bi = oi; }
        }
        if (lane == 0) { wbd[w][rr] = bd; wbi[w][rr] = bi; }
    }
    __syncthreads();
    if (tid < 4) {
        float bd = wbd[0][tid]; int bi = wbi[0][tid];
#pragma unroll
        for (int ww = 1; ww < 4; ++ww) {
            float od = wbd[ww][tid]; int oi = wbi[ww][tid];
            if (od < bd || (od == bd && oi < bi)) { bd = od; bi = oi; }
        }
        bestsh[tid] = bi; bestd[tid] = bd;
        dout[OUT_IDX + r0 + tid]  = (float)bi;
        dout[OUT_MIND + r0 + tid] = bd;
    }
    __syncthreads();

    // ---- gather quantized rows, split to bf16 hi/lo, store [n][k] (n = r0+rr) ----
#pragma unroll
    for (int rr = 0; rr < 4; ++rr) {
        float v = cb[(size_t)bestsh[rr] * 256 + tid];
        HL s = split_bf16(v);
        size_t o = (size_t)(r0 + rr) * 256 + tid;
        qhl[o]          = s.h;
        qhl[262144 + o] = s.l;
    }
    if (tid == 0) {
        float ls = (bestd[0] + bestd[1] + bestd[2] + bestd[3]) * (1.f / 262144.f);
        atomicAdd(&dout[OUT_CL], ls);
        atomicAdd(&dout[OUT_CB], ls);
    }
}

// ================= Final: BN(D2, 8-banked stats) + LeakyReLU + 1x1 conv + tanh =================
__global__ void final_conv_tanh(const float* __restrict__ hbuf, const float* __restrict__ bnt,
                                const float* __restrict__ g, const float* __restrict__ bt,
                                const float* __restrict__ w3, const float* __restrict__ b3,
                                float* __restrict__ out) {
    __shared__ float sc[32], sh[32], sw[96];
    int tid = threadIdx.x;
    if (tid < 32) {
        float sm = 0.f, sq = 0.f;
#pragma unroll
        for (int bk = 0; bk < 8; ++bk) {
            sm += bnt[bk * 64 + tid * 2];
            sq += bnt[bk * 64 + tid * 2 + 1];
        }
        float m = sm * (1.f / 262144.f);
        float var = sq * (1.f / 262144.f) - m * m;
        float scale = g[tid] * rsqrtf(var + 1e-5f);
        sc[tid] = scale;
        sh[tid] = bt[tid] - m * scale;
    }
    if (tid < 96) sw[tid] = w3[tid];
    __syncthreads();
    int idx = blockIdx.x * 256 + tid;          // 65536 = 16 * 4096 float4 pixels
    int hw4 = idx & 4095;
    int b   = idx >> 12;
    const float4* hp = (const float4*)hbuf + ((size_t)b * 32) * 4096 + hw4;
    float b0 = b3[0], b1 = b3[1], b2 = b3[2];
    float4 a0 = make_float4(b0, b0, b0, b0);
    float4 a1 = make_float4(b1, b1, b1, b1);
    float4 a2 = make_float4(b2, b2, b2, b2);
#pragma unroll 8
    for (int c = 0; c < 32; ++c) {
        float4 v = hp[(size_t)c * 4096];
        float scv = sc[c], shv = sh[c];
        float vx = v.x * scv + shv; vx = vx >= 0.f ? vx : LEAK * vx;
        float vy = v.y * scv + shv; vy = vy >= 0.f ? vy : LEAK * vy;
        float vz = v.z * scv + shv; vz = vz >= 0.f ? vz : LEAK * vz;
        float vw = v.w * scv + shv; vw = vw >= 0.f ? vw : LEAK * vw;
        float w0 = sw[c], w1 = sw[32 + c], w2 = sw[64 + c];
        a0.x += vx * w0; a0.y += vy * w0; a0.z += vz * w0; a0.w += vw * w0;
        a1.x += vx * w1; a1.y += vy * w1; a1.z += vz * w1; a1.w += vw * w1;
        a2.x += vx * w2; a2.y += vy * w2; a2.z += vz * w2; a2.w += vw * w2;
    }
    float4* op = (float4*)out;
    size_t ob = ((size_t)b * 3) * 4096 + hw4;
    op[ob]            = make_float4(tanhf(a0.x), tanhf(a0.y), tanhf(a0.z), tanhf(a0.w));
    op[ob + 4096]     = make_float4(tanhf(a1.x), tanhf(a1.y), tanhf(a1.z), tanhf(a1.w));
    op[ob + 2 * 4096] = make_float4(tanhf(a2.x), tanhf(a2.y), tanhf(a2.z), tanhf(a2.w));
}

extern "C" void kernel_launch(void* const* d_in, const int* in_sizes, int n_in,
                              void* d_out, int out_size, void* d_ws, size_t ws_size,
                              hipStream_t stream) {
    const float* x      = (const float*)d_in[0];
    const float* enc_w0 = (const float*)d_in[1];
    const float* enc_b0 = (const float*)d_in[2];
    const float* enc_w1 = (const float*)d_in[3];
    const float* enc_b1 = (const float*)d_in[4];
    const float* enc_w2 = (const float*)d_in[5];
    const float* enc_b2 = (const float*)d_in[6];
    const float* enc_w3 = (const float*)d_in[7];
    const float* enc_b3 = (const float*)d_in[8];
    const float* ebn_g0 = (const float*)d_in[9];
    const float* ebn_b0 = (const float*)d_in[10];
    const float* ebn_g1 = (const float*)d_in[11];
    const float* ebn_b1 = (const float*)d_in[12];
    const float* ebn_g2 = (const float*)d_in[13];
    const float* ebn_b2 = (const float*)d_in[14];
    const float* cb     = (const float*)d_in[15];
    const float* dec_w0 = (const float*)d_in[16];
    const float* dec_b0 = (const float*)d_in[17];
    const float* dbn_g0 = (const float*)d_in[18];
    const float* dbn_b0 = (const float*)d_in[19];
    const float* dec_w1 = (const float*)d_in[20];
    const float* dec_b1 = (const float*)d_in[21];
    const float* dbn_g1 = (const float*)d_in[22];
    const float* dbn_b1 = (const float*)d_in[23];
    const float* dec_w2 = (const float*)d_in[24];
    const float* dec_b2 = (const float*)d_in[25];
    const float* dbn_g2 = (const float*)d_in[26];
    const float* dbn_b2 = (const float*)d_in[27];
    const float* dec_w3 = (const float*)d_in[28];
    const float* dec_b3 = (const float*)d_in[29];

    float* out = (float*)d_out;
    float* ws  = (float*)d_ws;

    // ---- workspace (float units) ----
    float*  Y0   = ws;                               // 4194304
    float*  Y1   = ws + 4194304;                     // 2097152
    float*  Y2   = ws + 6291456;                     // 1048576
    float*  PST  = ws + 7340032;                     // 32768 (conv BN0 partials)
    float*  QHL  = ws + 7602176;                     // 262144 fl = 524288 us (QH | QL)
    ushort* WH   = (ushort*)(ws + 7864320);          // 2269184 us
    ushort* WL   = (ushort*)(ws + 8998912);          // 2269184 us
    float*  CBT  = ws + 10133504;                    // 131072
    float*  BNT  = ws + 10264576;                    // 6144 (incl. 8-banked dec1/dec2 stats)
    float*  PART = ws + 10270720;                    // 8388608
    float*  D0   = ws + 18659328;                    // 2097152
    float*  D1   = ws + 20756480;                    // 4194304
    float*  D2   = ws + 24950784;                    // 8388608

    dim3 blk(256);

    // ---- prologue: zero BNT/losses + cbT + weight prep + enc0 conv (fused, independent) ----
    prologue<<<11448, blk, 0, stream>>>(enc_w1, enc_w2, enc_w3, dec_w0, dec_w1, dec_w2,
                                        WH, WL, cb, CBT, BNT, out,
                                        x, enc_w0, enc_b0, Y0, PST);

    // enc1: M=128 N=16384 K=1024, KS=2, 32N tiles -> 1024 blocks; BN0 from PST
    gemm_mfma<0><<<1024, blk, 0, stream>>>(WH, WL, Y0,
        nullptr, ebn_g0, ebn_b0, 1.f / 65536.f, 4, enc_b1, PART,
        1, 512, 1024, 512, 2, 2097152, 64, 64, 128, 32, 5, 0, 0, 0, 0, nullptr, PST, 0, 0);
    reduce_bias_stats4<<<2048, blk, 0, stream>>>((const float4*)PART, enc_b1, (float4*)Y1,
                                                 BNT + 1024, 524288, 2, 128, 256, 1);

    // enc2: M=256 N=4096 K=2048, KS=4, 32N tiles -> 1024 blocks; B=Y1 raw + BN1
    gemm_mfma<0><<<1024, blk, 0, stream>>>(WH + 131072, WL + 131072, Y1,
        BNT + 1024, ebn_g1, ebn_b1, 1.f / 16384.f, 4, enc_b2, PART,
        2, 128, 2048, 512, 4, 1048576, 128, 32, 256, 16, 4, 0, 0, 0, 0, nullptr, nullptr, 0, 0);
    reduce_bias_stats4<<<1024, blk, 0, stream>>>((const float4*)PART, enc_b2, (float4*)Y2,
                                                 BNT + 2048, 262144, 4, 256, 64, 4);

    // enc3: M=256 N=1024 K=4096, KS=16, 32N tiles -> 1024 blocks; partials -> VQ
    gemm_mfma<0><<<1024, blk, 0, stream>>>(WH + 655360, WL + 655360, Y2,
        BNT + 2048, ebn_g2, ebn_b2, 1.f / 4096.f, 4, enc_b3, PART,
        2, 32, 4096, 256, 16, 262144, 256, 16, 256, 8, 3, 0, 0, 0, 0, nullptr, nullptr, 0, 0);

    // ---- VQ: sums 16 partial slices + bias; emits pre-split QH/QL; fused loss ----
    vq_main<<<256, blk, 0, stream>>>(PART, enc_b3, CBT, cb, (ushort*)QHL, out);

    // ---- decoder ----
    // dec0: M=2048 N=1024 K=256, KS=2, 32N tiles -> 1024 blocks; MODE2 pre-split B
    gemm_mfma<2><<<1024, blk, 0, stream>>>(WH + 1703936, WL + 1703936, QHL,
        nullptr, nullptr, nullptr, 0.f, 0, dec_b0, PART,
        16, 32, 256, 128, 2, 2097152, 256, 8, 128, 262144, 0, 6, 3, 7, 2, nullptr, nullptr, 0, 0);
    reduce_bias_stats4<<<2048, blk, 0, stream>>>((const float4*)PART, dec_b0, (float4*)D0,
                                                 BNT + 3072, 524288, 2, 128, 256, 1);

    // dec1: M=256 N=16384 K=128, KS=1, 32N tiles -> 1024 blocks; direct D1 + banked stats
    gemm_mfma<1><<<1024, blk, 0, stream>>>(WH + 2228224, WL + 2228224, D0,
        BNT + 3072, dbn_g0, dbn_b0, 1.f / 16384.f, 0, dec_b1, D1,
        2, 512, 128, 128, 1, 0, 128, 32, 64, 0, 0, 10, 5, 6, 1, BNT + 4096, nullptr, 128, 0);

    // dec2: M=128 N=65536 K=64, KS=1, 32N tiles -> 2048 blocks; banked stats in+out
    gemm_mfma<1><<<2048, blk, 0, stream>>>(WH + 2260992, WL + 2260992, D1,
        BNT + 4096, dbn_g1, dbn_b1, 1.f / 65536.f, 0, dec_b2, D2,
        1, 2048, 64, 64, 1, 0, 64, 64, 32, 0, 0, 12, 6, 5, 1, BNT + 5120, nullptr, 64, 128);

    // final: BN5 (8 banks) + leaky + 1x1 conv + tanh (float4)
    final_conv_tanh<<<256, blk, 0, stream>>>(D2, BNT + 5120, dbn_g2, dbn_b2, dec_w3, dec_b3, out);
}

// Round 9
// 367.043 us; speedup vs baseline: 1.0743x; 1.0355x over previous
//
#include <hip/hip_runtime.h>
#include <math.h>

#define LEAK 0.01f

typedef __bf16 bf16x8 __attribute__((ext_vector_type(8)));
typedef float f32x4 __attribute__((ext_vector_type(4)));
typedef unsigned short ushort;
typedef unsigned int uint32;

struct HL { ushort h, l; };

// split fp32 into bf16 hi + bf16 lo (both RNE): x ~= hi + lo, err ~2^-17 rel
__device__ inline HL split_bf16(float x) {
    unsigned u = __float_as_uint(x);
    unsigned hr = (u + 0x7FFFu + ((u >> 16) & 1u)) >> 16;
    float fh = __uint_as_float(hr << 16);
    float r = x - fh;
    unsigned v = __float_as_uint(r);
    unsigned lr = (v + 0x7FFFu + ((v >> 16) & 1u)) >> 16;
    HL out; out.h = (ushort)hr; out.l = (ushort)lr;
    return out;
}

// ============ staged-B raw load: 32n x 64k fp32 tile, 8 floats/thread (2 k-halves) ============
// r8: N-MAJOR lane mapping (nl = tid&31, kg = tid>>5) — coalesced staging (measured win).
template<int MODE>
__device__ inline void stage_load(float (&pv)[2][4], const float* __restrict__ Bf,
                                  int kbase, int n0, int tid,
                                  int Ci, int Hin, int Ho, int lgHo, int lgHW) {
    int nl = tid & 31, kg = tid >> 5;
    int n = n0 + nl;
#pragma unroll
    for (int r = 0; r < 2; ++r) {
        if (MODE == 0) {
            int k4 = kbase + (r << 5) + (kg << 2);
            int ic = k4 >> 4, kh = (k4 >> 2) & 3;
            int ow = n & (Ho - 1), oh = (n >> lgHo) & (Ho - 1), b = n >> (lgHo + lgHo);
            int ih = oh * 2 - 1 + kh;
            int ihc = ih < 0 ? 0 : (ih >= Hin ? Hin - 1 : ih);
            int iwb = ow * 2 - 1;
            size_t base = ((size_t)(b * Ci + ic) * Hin + ihc) * Hin;
#pragma unroll
            for (int e = 0; e < 4; ++e) {
                int iw = iwb + e;
                int iwc = iw < 0 ? 0 : (iw >= Hin ? Hin - 1 : iw);
                pv[r][e] = Bf[base + iwc];
            }
        } else {
            int c = kbase + (r << 5) + (kg << 2);
            int b = n >> lgHW, hw = n & ((1 << lgHW) - 1);
            size_t base = (((size_t)(b * Ci + c)) << lgHW) + hw;
            size_t str = (size_t)1 << lgHW;
#pragma unroll
            for (int e = 0; e < 4; ++e) pv[r][e] = Bf[base + e * str];
        }
    }
}

// ================= bf16-split MFMA GEMM with fused BN+LeakyReLU on B-load =================
// Block tile 128M x 32N, 4 waves of 32M x 32N. K-step 64.
// MODE 0: conv-im2col B; MODE 1: channel-major B; MODE 2: PRE-SPLIT B from global.
// statsBnt != nullptr (KS==1): fused per-channel sum/sumsq atomics, 8-way banked.
// bntBankStride > 0: input bnt is 8-banked; sum banks in prologue.
// r9 (convoy invariant: GEMM wall time tracks TOTAL block-K-steps, not per-block
// depth): enc1 (Mtiles=1 -> no transform replication) and dec0 (MODE2, transform-free)
// go KS=1 with fused stats + direct output — kills 2 reduce passes, ~110 MB traffic.
template<int MODE>
__global__ __launch_bounds__(256, 3) void gemm_mfma(
    const ushort* __restrict__ Ah, const ushort* __restrict__ Al,
    const float* __restrict__ Bf,
    const float* __restrict__ bnt, const float* __restrict__ gamma,
    const float* __restrict__ beta, float invN, int chanShift,
    const float* __restrict__ bias, float* __restrict__ P,
    int Mtiles, int Ntiles, int K, int Kslice, int KS, int outSize,
    int Ci, int Hin, int Co, int Ho, int lgHo,
    int lgHW, int lgHin, int lgCo, int lgk,
    float* __restrict__ statsBnt, const float* __restrict__ bnPart,
    int statsBank, int bntBankStride)
{
    __shared__ __align__(16) uint32 Bsp[32 * 68];   // [n][64k] packed, stride 68
    __shared__ float scs[256], shs[256];

    int bid = blockIdx.x;
    int ntile = bid % Ntiles; bid /= Ntiles;
    int mtile = bid % Mtiles;
    int ks = bid / Mtiles;
    int tid = threadIdx.x;
    int lane = tid & 63, w = tid >> 6;
    int quad = lane >> 4, tl = lane & 15;
    int n0 = ntile << 5, m0 = mtile << 7, k0 = ks * Kslice;
    int Kt = K >> 5;

    bool useBN = (bnt != nullptr) || (bnPart != nullptr);
    int c0 = k0 >> chanShift;
    if (bnPart != nullptr) {
        // BN0 from conv tile-partials: 64 channels x 256 (sum,sq) pairs
        int c = tid >> 2, qq = tid & 3;
        const float2* pp2 = (const float2*)(bnPart + c * 512) + qq * 64;
        float s = 0.f, s2 = 0.f;
#pragma unroll 8
        for (int p = 0; p < 64; ++p) { float2 v = pp2[p]; s += v.x; s2 += v.y; }
        scs[tid] = s; shs[tid] = s2;
        __syncthreads();
        float scale = 0.f, shift = 0.f;
        if (tid < 64) {
            float st = scs[tid * 4] + scs[tid * 4 + 1] + scs[tid * 4 + 2] + scs[tid * 4 + 3];
            float qt = shs[tid * 4] + shs[tid * 4 + 1] + shs[tid * 4 + 2] + shs[tid * 4 + 3];
            float m = st * invN;
            float var = qt * invN - m * m;
            scale = gamma[tid] * rsqrtf(var + 1e-5f);
            shift = beta[tid] - m * scale;
        }
        __syncthreads();
        // store shifted so the transform's scs[ic - c0] indexing works for any K-slice
        if (tid < 64 && tid >= c0) { scs[tid - c0] = scale; shs[tid - c0] = shift; }
    } else if (bnt != nullptr) {
        int nch = Kslice >> chanShift;
        for (int c = tid; c < nch; c += 256) {
            float sm, sq;
            if (bntBankStride > 0) {
                sm = 0.f; sq = 0.f;
#pragma unroll
                for (int bk = 0; bk < 8; ++bk) {
                    sm += bnt[bk * bntBankStride + (c0 + c) * 2];
                    sq += bnt[bk * bntBankStride + (c0 + c) * 2 + 1];
                }
            } else {
                sm = bnt[(c0 + c) * 2];
                sq = bnt[(c0 + c) * 2 + 1];
            }
            float m = sm * invN;
            float var = sq * invN - m * m;
            float scale = gamma[c0 + c] * rsqrtf(var + 1e-5f);
            scs[c] = scale;
            shs[c] = beta[c0 + c] - m * scale;
        }
    }
    __syncthreads();

    f32x4 zero4 = {0.f, 0.f, 0.f, 0.f};
    f32x4 acc[2][2];
#pragma unroll
    for (int mt = 0; mt < 2; ++mt)
#pragma unroll
        for (int nt = 0; nt < 2; ++nt) acc[mt][nt] = zero4;

    if (MODE == 2) {
        // ---- barrier-free K-loop: B pre-split in global (L2-resident) ----
        const ushort* Bu = (const ushort*)Bf;
        for (int kc = 0; kc < Kslice; kc += 32) {
            int kbase = k0 + kc;
            int kt = kbase >> 5;
            bf16x8 afh[2], afl[2];
#pragma unroll
            for (int mt = 0; mt < 2; ++mt) {
                int mtAbs = (m0 >> 4) + (w << 1) + mt;
                size_t abase = (((size_t)mtAbs * Kt + kt) << 6) + lane;
                afh[mt] = *(const bf16x8*)(Ah + abase * 8);
                afl[mt] = *(const bf16x8*)(Al + abase * 8);
            }
            bf16x8 bfh[2], bfl[2];
#pragma unroll
            for (int nt = 0; nt < 2; ++nt) {
                int n = n0 + (nt << 4) + tl;
                size_t ba = (size_t)n * Ci + kbase + (quad << 3);
                bfh[nt] = *(const bf16x8*)(Bu + ba);
                bfl[nt] = *(const bf16x8*)(Bu + Ho + ba);
            }
#pragma unroll
            for (int mt = 0; mt < 2; ++mt)
#pragma unroll
                for (int nt = 0; nt < 2; ++nt) {
                    acc[mt][nt] = __builtin_amdgcn_mfma_f32_16x16x32_bf16(afh[mt], bfh[nt], acc[mt][nt], 0, 0, 0);
                    acc[mt][nt] = __builtin_amdgcn_mfma_f32_16x16x32_bf16(afh[mt], bfl[nt], acc[mt][nt], 0, 0, 0);
                    acc[mt][nt] = __builtin_amdgcn_mfma_f32_16x16x32_bf16(afl[mt], bfh[nt], acc[mt][nt], 0, 0, 0);
                }
        }
    } else {
        // ---- staged K-loop, BK=64: stage/transform 32n x 64k per barrier pair ----
        float pv[2][4];
        stage_load<MODE>(pv, Bf, k0, n0, tid, Ci, Hin, Ho, lgHo, lgHW);

        for (int kc = 0; kc < Kslice; kc += 64) {
            int kbase = k0 + kc;
            // ---- transform both k-halves + regs -> LDS (n-major lane map, r8) ----
            int nl = tid & 31, kg = tid >> 5;
#pragma unroll
            for (int r = 0; r < 2; ++r) {
                int k4 = kbase + (r << 5) + (kg << 2);
                uint32 pk[4];
                if (MODE == 0) {
                    int ic = k4 >> 4, kh = (k4 >> 2) & 3;
                    int n = n0 + nl;
                    int ow = n & (Ho - 1), oh = (n >> lgHo) & (Ho - 1);
                    int ih = oh * 2 - 1 + kh;
                    bool rowok = (unsigned)ih < (unsigned)Hin;
                    int iwb = ow * 2 - 1;
                    float sc_ = useBN ? scs[ic - c0] : 0.f;
                    float sh_ = useBN ? shs[ic - c0] : 0.f;
#pragma unroll
                    for (int e = 0; e < 4; ++e) {
                        int iw = iwb + e;
                        bool ok = rowok && ((unsigned)iw < (unsigned)Hin);
                        float f = pv[r][e];
                        if (useBN) { f = f * sc_ + sh_; f = f >= 0.f ? f : LEAK * f; }
                        if (!ok) f = 0.f;
                        HL s = split_bf16(f);
                        pk[e] = ((uint32)s.h << 16) | s.l;
                    }
                } else {
#pragma unroll
                    for (int e = 0; e < 4; ++e) {
                        float f = pv[r][e];
                        if (useBN) {
                            int lc = k4 + e - k0;
                            f = f * scs[lc] + shs[lc];
                            f = f >= 0.f ? f : LEAK * f;
                        }
                        HL s = split_bf16(f);
                        pk[e] = ((uint32)s.h << 16) | s.l;
                    }
                }
                *(uint4*)&Bsp[nl * 68 + (r << 5) + (kg << 2)] = make_uint4(pk[0], pk[1], pk[2], pk[3]);
            }
            __syncthreads();

            // ---- prefetch next 64-K tile (raw; latency hidden under 24 MFMAs) ----
            bool more = (kc + 64) < Kslice;
            float pvn[2][4];
            if (more) stage_load<MODE>(pvn, Bf, kbase + 64, n0, tid, Ci, Hin, Ho, lgHo, lgHW);

            // ---- two 32-K substeps from LDS ----
#pragma unroll
            for (int sub = 0; sub < 2; ++sub) {
                int kt = (kbase >> 5) + sub;
                bf16x8 afh[2], afl[2];
#pragma unroll
                for (int mt = 0; mt < 2; ++mt) {
                    int mtAbs = (m0 >> 4) + (w << 1) + mt;
                    size_t abase = (((size_t)mtAbs * Kt + kt) << 6) + lane;
                    afh[mt] = *(const bf16x8*)(Ah + abase * 8);
                    afl[mt] = *(const bf16x8*)(Al + abase * 8);
                }
                bf16x8 bfh[2], bfl[2];
#pragma unroll
                for (int nt = 0; nt < 2; ++nt) {
                    int base = ((nt << 4) + tl) * 68 + (sub << 5) + (quad << 3);
                    uint4 ua = *(const uint4*)&Bsp[base];
                    uint4 ub = *(const uint4*)&Bsp[base + 4];
                    union { uint32 u[4]; bf16x8 v; } H, L;
                    H.u[0] = __builtin_amdgcn_perm(ua.y, ua.x, 0x07060302u);
                    H.u[1] = __builtin_amdgcn_perm(ua.w, ua.z, 0x07060302u);
                    H.u[2] = __builtin_amdgcn_perm(ub.y, ub.x, 0x07060302u);
                    H.u[3] = __builtin_amdgcn_perm(ub.w, ub.z, 0x07060302u);
                    L.u[0] = __builtin_amdgcn_perm(ua.y, ua.x, 0x05040100u);
                    L.u[1] = __builtin_amdgcn_perm(ua.w, ua.z, 0x05040100u);
                    L.u[2] = __builtin_amdgcn_perm(ub.y, ub.x, 0x05040100u);
                    L.u[3] = __builtin_amdgcn_perm(ub.w, ub.z, 0x05040100u);
                    bfh[nt] = H.v; bfl[nt] = L.v;
                }
#pragma unroll
                for (int mt = 0; mt < 2; ++mt)
#pragma unroll
                    for (int nt = 0; nt < 2; ++nt) {
                        acc[mt][nt] = __builtin_amdgcn_mfma_f32_16x16x32_bf16(afh[mt], bfh[nt], acc[mt][nt], 0, 0, 0);
                        acc[mt][nt] = __builtin_amdgcn_mfma_f32_16x16x32_bf16(afh[mt], bfl[nt], acc[mt][nt], 0, 0, 0);
                        acc[mt][nt] = __builtin_amdgcn_mfma_f32_16x16x32_bf16(afl[mt], bfh[nt], acc[mt][nt], 0, 0, 0);
                    }
            }
            __syncthreads();
            if (more) {
#pragma unroll
                for (int r = 0; r < 2; ++r)
#pragma unroll
                    for (int e = 0; e < 4; ++e) pv[r][e] = pvn[r][e];
            }
        }
    }

    // ---- epilogue: D[m = quad*4+reg][n = tl] + optional fused stats (KS==1 paths) ----
    bool doStats = (statsBnt != nullptr);
    if (doStats) {
        if (tid < 2 * Co) scs[tid] = 0.f;
        __syncthreads();
    }
    float ssum[2][4] = {{0.f,0.f,0.f,0.f},{0.f,0.f,0.f,0.f}};
    float ssq [2][4] = {{0.f,0.f,0.f,0.f},{0.f,0.f,0.f,0.f}};
    float* dst = P + (size_t)ks * outSize;
    if (MODE == 0) {
#pragma unroll
        for (int nt = 0; nt < 2; ++nt) {
            int n = n0 + (nt << 4) + tl;
            int ow = n & (Ho - 1), oh = (n >> lgHo) & (Ho - 1), b = n >> (lgHo + lgHo);
#pragma unroll
            for (int mt = 0; mt < 2; ++mt) {
                int mb = m0 + (w << 5) + (mt << 4) + (quad << 2);
#pragma unroll
                for (int r = 0; r < 4; ++r) {
                    int oc = mb + r;
                    float v = acc[mt][nt][r];
                    if (KS == 1) v += bias[oc];
                    if (doStats) { ssum[mt][r] += v; ssq[mt][r] += v * v; }
                    dst[((size_t)(b * Co + oc) * Ho + oh) * Ho + ow] = v;
                }
            }
        }
    } else {
        int kf = 1 << lgk;
        int Ho2 = Hin << lgk;
#pragma unroll
        for (int nt = 0; nt < 2; ++nt) {
            int n = n0 + (nt << 4) + tl;
            int b = n >> lgHW, hw = n & ((1 << lgHW) - 1);
            int h = hw >> lgHin, wp = hw & (Hin - 1);
#pragma unroll
            for (int mt = 0; mt < 2; ++mt) {
                int mb = m0 + (w << 5) + (mt << 4) + (quad << 2);
#pragma unroll
                for (int r = 0; r < 4; ++r) {
                    int m = mb + r;
                    int o = m & (Co - 1), ij = m >> lgCo;
                    int ii = ij >> lgk, jj = ij & (kf - 1);
                    float v = acc[mt][nt][r];
                    if (KS == 1) v += bias[o];
                    if (doStats) { ssum[mt][r] += v; ssq[mt][r] += v * v; }
                    dst[((size_t)(b * Co + o) * Ho2 + (h << lgk) + ii) * Ho2 + (wp << lgk) + jj] = v;
                }
            }
        }
    }
    if (doStats) {
        // reduce over the 16 lanes (tl) sharing identical channels
#pragma unroll
        for (int mt = 0; mt < 2; ++mt)
#pragma unroll
            for (int r = 0; r < 4; ++r) {
                float s = ssum[mt][r], q2 = ssq[mt][r];
#pragma unroll
                for (int m2 = 1; m2 < 16; m2 <<= 1) {
                    s  += __shfl_xor(s,  m2);
                    q2 += __shfl_xor(q2, m2);
                }
                if (tl == 0) {
                    int m = m0 + (w << 5) + (mt << 4) + (quad << 2) + r;
                    int o = (MODE == 0) ? m : (m & (Co - 1));
                    atomicAdd(&scs[o * 2],     s);
                    atomicAdd(&scs[o * 2 + 1], q2);
                }
            }
        __syncthreads();
        float* sb = statsBnt + (blockIdx.x & 7) * statsBank;
        if (tid < 2 * Co) atomicAdd(&sb[tid], scs[tid]);
    }
}

// ================= weight prep address =================
__device__ inline int fragaddr(int m, int k, int K) {
    return ((((m >> 4) * (K >> 5) + (k >> 5)) << 9) | (((k >> 3) & 3) << 7) | ((m & 15) << 3) | (k & 7));
}

#define OUT_CL   786432
#define OUT_CB   786433
#define OUT_IDX  786434
#define OUT_MIND 787458

// ================= enc0 direct conv (Ci=3) with non-atomic per-tile BN stat partials =================
__device__ void conv_body(int bid, int tid,
                          const float* __restrict__ x, const float* __restrict__ w,
                          const float* __restrict__ bias, float* __restrict__ P,
                          float* __restrict__ pst, float (&cst)[4][16])
{
    const int Ci = 3, Hin = 128, Co = 64, Ho = 64, OCT = 8;
    int ntile = (16 * Ho * Ho) >> 8;          // 256
    int tile = bid % ntile;
    int og = bid / ntile;
    int oc0 = og * OCT;

    int px = (tile << 8) + tid;
    int ow = px % Ho; int t = px / Ho;
    int oh = t % Ho;  int b = t / Ho;

    int off[16]; float fm[16];
    int ih0 = oh * 2 - 1, iw0 = ow * 2 - 1;
#pragma unroll
    for (int kh = 0; kh < 4; ++kh)
#pragma unroll
        for (int kw = 0; kw < 4; ++kw) {
            int ih = ih0 + kh, iw = iw0 + kw;
            bool ok = (ih >= 0) && (ih < Hin) && (iw >= 0) && (iw < Hin);
            int ihc = ih < 0 ? 0 : (ih >= Hin ? Hin - 1 : ih);
            int iwc = iw < 0 ? 0 : (iw >= Hin ? Hin - 1 : iw);
            off[kh * 4 + kw] = ihc * Hin + iwc;
            fm[kh * 4 + kw] = ok ? 1.f : 0.f;
        }

    float acc[OCT];
#pragma unroll
    for (int u = 0; u < OCT; ++u) acc[u] = bias[oc0 + u];

    const float* xc = x + (size_t)b * Ci * Hin * Hin;
    const float* wi = w + (size_t)oc0 * Ci * 16;
    int HinHin = Hin * Hin;
    for (int ic = 0; ic < Ci; ++ic) {
        float xv[16];
#pragma unroll
        for (int q = 0; q < 16; ++q) xv[q] = xc[off[q]] * fm[q];
#pragma unroll
        for (int u = 0; u < OCT; ++u) {
            const float* wo = wi + (size_t)u * Ci * 16;
            float a = acc[u];
#pragma unroll
            for (int q = 0; q < 16; ++q) a += xv[q] * wo[q];
            acc[u] = a;
        }
        xc += HinHin;
        wi += 16;
    }
    size_t obase = (((size_t)b * Co + oc0) * Ho + oh) * Ho + ow;
    size_t opl = (size_t)Ho * Ho;
#pragma unroll
    for (int u = 0; u < OCT; ++u) P[obase + u * opl] = acc[u];

    // ---- BN stat partials: butterfly over 64 lanes, combine 4 waves, plain store ----
    float sv[OCT], qv[OCT];
#pragma unroll
    for (int u = 0; u < OCT; ++u) { sv[u] = acc[u]; qv[u] = acc[u] * acc[u]; }
#pragma unroll
    for (int m2 = 1; m2 < 64; m2 <<= 1)
#pragma unroll
        for (int u = 0; u < OCT; ++u) {
            sv[u] += __shfl_xor(sv[u], m2);
            qv[u] += __shfl_xor(qv[u], m2);
        }
    int lane = tid & 63, wv = tid >> 6;
    if (lane == 0) {
#pragma unroll
        for (int u = 0; u < OCT; ++u) { cst[wv][u * 2] = sv[u]; cst[wv][u * 2 + 1] = qv[u]; }
    }
    __syncthreads();
    if (tid < 2 * OCT) {
        float v = cst[0][tid] + cst[1][tid] + cst[2][tid] + cst[3][tid];
        pst[(oc0 + (tid >> 1)) * 512 + tile * 2 + (tid & 1)] = v;
    }
}

// ================= fused prologue: zero BNT/losses + cbT + weight prep + enc0 conv =================
__global__ void prologue(const float* __restrict__ w1, const float* __restrict__ w2,
                         const float* __restrict__ w3, const float* __restrict__ d0,
                         const float* __restrict__ d1, const float* __restrict__ d2,
                         ushort* __restrict__ WH, ushort* __restrict__ WL,
                         const float* __restrict__ cb, float* __restrict__ cbT,
                         float* __restrict__ bnt, float* __restrict__ dout,
                         const float* __restrict__ x, const float* __restrict__ w0,
                         const float* __restrict__ b0, float* __restrict__ Y0,
                         float* __restrict__ pst) {
    __shared__ float cst[4][16];
    int blk = blockIdx.x;
    int tid = threadIdx.x;
    if (blk < 24) {                          // zero BN totals + loss accumulators
        bnt[blk * 256 + tid] = 0.f;
        if (blk == 0 && tid < 2) dout[OUT_CL + tid] = 0.f;
        return;
    }
    if (blk < 536) {                         // codebook transpose
        int idx = (blk - 24) * 256 + tid;
        int k = idx & 511, c = idx >> 9;
        cbT[idx] = cb[k * 256 + c];
        return;
    }
    if (blk >= 9400) {                       // enc0 direct conv (2048 blocks)
        conv_body(blk - 9400, tid, x, w0, b0, Y0, pst, cst);
        return;
    }
    int idx = (blk - 536) * 256 + tid;       // weight split+reorder
    if (idx >= 2269184) return;
    float v; int dst;
    if (idx < 131072) {                      // enc1: M=128 K=1024
        int m = idx >> 10, k = idx & 1023;
        v = w1[idx];
        dst = fragaddr(m, k, 1024);
    } else if (idx < 655360) {               // enc2: M=256 K=2048
        int i = idx - 131072;
        int m = i >> 11, k = i & 2047;
        v = w2[i];
        dst = 131072 + fragaddr(m, k, 2048);
    } else if (idx < 1703936) {              // enc3: M=256 K=4096
        int i = idx - 655360;
        int m = i >> 12, k = i & 4095;
        v = w3[i];
        dst = 655360 + fragaddr(m, k, 4096);
    } else if (idx < 2228224) {              // dec0: M=2048 K=256
        int i = idx - 1703936;
        int m = i >> 8, c = i & 255;
        int o = m & 127, ij = m >> 7;
        v = d0[((size_t)c * 128 + o) * 16 + ij];
        dst = 1703936 + fragaddr(m, c, 256);
    } else if (idx < 2260992) {              // dec1: M=256 K=128
        int i = idx - 2228224;
        int m = i >> 7, c = i & 127;
        int o = m & 63, ij = m >> 6;
        v = d1[((size_t)c * 64 + o) * 4 + ij];
        dst = 2228224 + fragaddr(m, c, 128);
    } else {                                 // dec2: M=128 K=64
        int i = idx - 2260992;
        int m = i >> 6, c = i & 63;
        int o = m & 31, ij = m >> 5;
        v = d2[((size_t)c * 32 + o) * 4 + ij];
        dst = 2260992 + fragaddr(m, c, 64);
    }
    HL s = split_bf16(v);
    WH[dst] = s.h; WL[dst] = s.l;
}

// ================= reduce partials + BN stats (enc2 only) =================
__global__ void reduce_bias_stats4(const float4* __restrict__ P, const float* __restrict__ bias,
                                   float4* __restrict__ y, float* __restrict__ bnt,
                                   int outSize4, int KS, int Co, int HW4, int nch) {
    int tid = threadIdx.x;
    int i = blockIdx.x * 256 + tid;
    int c = (i / HW4) % Co;
    float bv = bias[c];
    float4 s = make_float4(bv, bv, bv, bv);
    for (int ks = 0; ks < KS; ++ks) {
        float4 p = P[(size_t)ks * outSize4 + i];
        s.x += p.x; s.y += p.y; s.z += p.z; s.w += p.w;
    }
    y[i] = s;
    float ls  = s.x + s.y + s.z + s.w;
    float ls2 = s.x * s.x + s.y * s.y + s.z * s.z + s.w * s.w;
    __shared__ float as[16], aq[16];
    if (tid < 16) { as[tid] = 0.f; aq[tid] = 0.f; }
    __syncthreads();
    int c0 = ((blockIdx.x * 256) / HW4) % Co;
    atomicAdd(&as[c - c0], ls);
    atomicAdd(&aq[c - c0], ls2);
    __syncthreads();
    if (tid < nch) {
        atomicAdd(&bnt[(c0 + tid) * 2],     as[tid]);
        atomicAdd(&bnt[(c0 + tid) * 2 + 1], aq[tid]);
    }
}

// ================= Vector quantizer: sums 16 enc3 partial slices on load; writes
// pre-split QH/QL bf16 [n][k] row-major for dec0 MODE2; fused loss =================
__global__ void vq_main(const float* __restrict__ Pz, const float* __restrict__ b3,
                        const float* __restrict__ cbT, const float* __restrict__ cb,
                        ushort* __restrict__ qhl, float* __restrict__ dout) {
    int r0 = blockIdx.x * 4;
    int tid = threadIdx.x;
    int lane = tid & 63, w = tid >> 6;

    __shared__ __align__(16) float zT[256][4];
    __shared__ float wred[4][4];
    __shared__ float zn2s[4];
    __shared__ float wbd[4][4];
    __shared__ int   wbi[4][4];
    __shared__ int   bestsh[4];
    __shared__ float bestd[4];

    int b = r0 >> 6, s0 = r0 & 63;
    size_t zi = ((size_t)(b * 256 + tid)) * 64 + s0;
    float bv = b3[tid];
    float4 zv = make_float4(bv, bv, bv, bv);
    const float4* pp = (const float4*)Pz + (zi >> 2);
#pragma unroll
    for (int ks = 0; ks < 16; ++ks) {
        float4 p = pp[(size_t)ks * 65536];
        zv.x += p.x; zv.y += p.y; zv.z += p.z; zv.w += p.w;
    }
    *(float4*)&zT[tid][0] = zv;

    // ---- per-row |z|^2 via butterfly sum over channels ----
    float p0 = zv.x * zv.x, p1 = zv.y * zv.y, p2 = zv.z * zv.z, p3 = zv.w * zv.w;
#pragma unroll
    for (int m2 = 1; m2 < 64; m2 <<= 1) {
        p0 += __shfl_xor(p0, m2); p1 += __shfl_xor(p1, m2);
        p2 += __shfl_xor(p2, m2); p3 += __shfl_xor(p3, m2);
    }
    if (lane == 0) { wred[w][0] = p0; wred[w][1] = p1; wred[w][2] = p2; wred[w][3] = p3; }
    __syncthreads();
    if (tid < 4) zn2s[tid] = wred[0][tid] + wred[1][tid] + wred[2][tid] + wred[3][tid];
    __syncthreads();

    // ---- dot products: thread owns codebook entries k=tid and k=tid+256 ----
    float d0[4], d1[4];
#pragma unroll
    for (int rr = 0; rr < 4; ++rr) { d0[rr] = 0.f; d1[rr] = 0.f; }
    float cn0 = 0.f, cn1 = 0.f;
#pragma unroll 4
    for (int c = 0; c < 256; ++c) {
        float cv0 = cbT[c * 512 + tid];
        float cv1 = cbT[c * 512 + 256 + tid];
        cn0 += cv0 * cv0;
        cn1 += cv1 * cv1;
        float4 za = *(const float4*)&zT[c][0];
        d0[0] += za.x * cv0; d1[0] += za.x * cv1;
        d0[1] += za.y * cv0; d1[1] += za.y * cv1;
        d0[2] += za.z * cv0; d1[2] += za.z * cv1;
        d0[3] += za.w * cv0; d1[3] += za.w * cv1;
    }

    // ---- argmin via butterfly (tie-break: smaller index) ----
#pragma unroll
    for (int rr = 0; rr < 4; ++rr) {
        float dist0 = zn2s[rr] - 2.f * d0[rr] + cn0;
        float dist1 = zn2s[rr] - 2.f * d1[rr] + cn1;
        float bd = dist0; int bi = tid;
        if (dist1 < bd) { bd = dist1; bi = tid + 256; }
#pragma unroll
        for (int m2 = 1; m2 < 64; m2 <<= 1) {
            float od = __shfl_xor(bd, m2); int oi = __shfl_xor(bi, m2);
            if (od < bd || (od == bd && oi < bi)) { bd = od; bi = oi; }
        }
        if (lane == 0) { wbd[w][rr] = bd; wbi[w][rr] = bi; }
    }
    __syncthreads();
    if (tid < 4) {
        float bd = wbd[0][tid]; int bi = wbi[0][tid];
#pragma unroll
        for (int ww = 1; ww < 4; ++ww) {
            float od = wbd[ww][tid]; int oi = wbi[ww][tid];
            if (od < bd || (od == bd && oi < bi)) { bd = od; bi = oi; }
        }
        bestsh[tid] = bi; bestd[tid] = bd;
        dout[OUT_IDX + r0 + tid]  = (float)bi;
        dout[OUT_MIND + r0 + tid] = bd;
    }
    __syncthreads();

    // ---- gather quantized rows, split to bf16 hi/lo, store [n][k] (n = r0+rr) ----
#pragma unroll
    for (int rr = 0; rr < 4; ++rr) {
        float v = cb[(size_t)bestsh[rr] * 256 + tid];
        HL s = split_bf16(v);
        size_t o = (size_t)(r0 + rr) * 256 + tid;
        qhl[o]          = s.h;
        qhl[262144 + o] = s.l;
    }
    if (tid == 0) {
        float ls = (bestd[0] + bestd[1] + bestd[2] + bestd[3]) * (1.f / 262144.f);
        atomicAdd(&dout[OUT_CL], ls);
        atomicAdd(&dout[OUT_CB], ls);
    }
}

// ================= Final: BN(D2, 8-banked stats) + LeakyReLU + 1x1 conv + tanh =================
__global__ void final_conv_tanh(const float* __restrict__ hbuf, const float* __restrict__ bnt,
                                const float* __restrict__ g, const float* __restrict__ bt,
                                const float* __restrict__ w3, const float* __restrict__ b3,
                                float* __restrict__ out) {
    __shared__ float sc[32], sh[32], sw[96];
    int tid = threadIdx.x;
    if (tid < 32) {
        float sm = 0.f, sq = 0.f;
#pragma unroll
        for (int bk = 0; bk < 8; ++bk) {
            sm += bnt[bk * 64 + tid * 2];
            sq += bnt[bk * 64 + tid * 2 + 1];
        }
        float m = sm * (1.f / 262144.f);
        float var = sq * (1.f / 262144.f) - m * m;
        float scale = g[tid] * rsqrtf(var + 1e-5f);
        sc[tid] = scale;
        sh[tid] = bt[tid] - m * scale;
    }
    if (tid < 96) sw[tid] = w3[tid];
    __syncthreads();
    int idx = blockIdx.x * 256 + tid;          // 65536 = 16 * 4096 float4 pixels
    int hw4 = idx & 4095;
    int b   = idx >> 12;
    const float4* hp = (const float4*)hbuf + ((size_t)b * 32) * 4096 + hw4;
    float b0 = b3[0], b1 = b3[1], b2 = b3[2];
    float4 a0 = make_float4(b0, b0, b0, b0);
    float4 a1 = make_float4(b1, b1, b1, b1);
    float4 a2 = make_float4(b2, b2, b2, b2);
#pragma unroll 8
    for (int c = 0; c < 32; ++c) {
        float4 v = hp[(size_t)c * 4096];
        float scv = sc[c], shv = sh[c];
        float vx = v.x * scv + shv; vx = vx >= 0.f ? vx : LEAK * vx;
        float vy = v.y * scv + shv; vy = vy >= 0.f ? vy : LEAK * vy;
        float vz = v.z * scv + shv; vz = vz >= 0.f ? vz : LEAK * vz;
        float vw = v.w * scv + shv; vw = vw >= 0.f ? vw : LEAK * vw;
        float w0 = sw[c], w1 = sw[32 + c], w2 = sw[64 + c];
        a0.x += vx * w0; a0.y += vy * w0; a0.z += vz * w0; a0.w += vw * w0;
        a1.x += vx * w1; a1.y += vy * w1; a1.z += vz * w1; a1.w += vw * w1;
        a2.x += vx * w2; a2.y += vy * w2; a2.z += vz * w2; a2.w += vw * w2;
    }
    float4* op = (float4*)out;
    size_t ob = ((size_t)b * 3) * 4096 + hw4;
    op[ob]            = make_float4(tanhf(a0.x), tanhf(a0.y), tanhf(a0.z), tanhf(a0.w));
    op[ob + 4096]     = make_float4(tanhf(a1.x), tanhf(a1.y), tanhf(a1.z), tanhf(a1.w));
    op[ob + 2 * 4096] = make_float4(tanhf(a2.x), tanhf(a2.y), tanhf(a2.z), tanhf(a2.w));
}

extern "C" void kernel_launch(void* const* d_in, const int* in_sizes, int n_in,
                              void* d_out, int out_size, void* d_ws, size_t ws_size,
                              hipStream_t stream) {
    const float* x      = (const float*)d_in[0];
    const float* enc_w0 = (const float*)d_in[1];
    const float* enc_b0 = (const float*)d_in[2];
    const float* enc_w1 = (const float*)d_in[3];
    const float* enc_b1 = (const float*)d_in[4];
    const float* enc_w2 = (const float*)d_in[5];
    const float* enc_b2 = (const float*)d_in[6];
    const float* enc_w3 = (const float*)d_in[7];
    const float* enc_b3 = (const float*)d_in[8];
    const float* ebn_g0 = (const float*)d_in[9];
    const float* ebn_b0 = (const float*)d_in[10];
    const float* ebn_g1 = (const float*)d_in[11];
    const float* ebn_b1 = (const float*)d_in[12];
    const float* ebn_g2 = (const float*)d_in[13];
    const float* ebn_b2 = (const float*)d_in[14];
    const float* cb     = (const float*)d_in[15];
    const float* dec_w0 = (const float*)d_in[16];
    const float* dec_b0 = (const float*)d_in[17];
    const float* dbn_g0 = (const float*)d_in[18];
    const float* dbn_b0 = (const float*)d_in[19];
    const float* dec_w1 = (const float*)d_in[20];
    const float* dec_b1 = (const float*)d_in[21];
    const float* dbn_g1 = (const float*)d_in[22];
    const float* dbn_b1 = (const float*)d_in[23];
    const float* dec_w2 = (const float*)d_in[24];
    const float* dec_b2 = (const float*)d_in[25];
    const float* dbn_g2 = (const float*)d_in[26];
    const float* dbn_b2 = (const float*)d_in[27];
    const float* dec_w3 = (const float*)d_in[28];
    const float* dec_b3 = (const float*)d_in[29];

    float* out = (float*)d_out;
    float* ws  = (float*)d_ws;

    // ---- workspace (float units) ----
    float*  Y0   = ws;                               // 4194304
    float*  Y1   = ws + 4194304;                     // 2097152
    float*  Y2   = ws + 6291456;                     // 1048576
    float*  PST  = ws + 7340032;                     // 32768 (conv BN0 partials)
    float*  QHL  = ws + 7602176;                     // 262144 fl = 524288 us (QH | QL)
    ushort* WH   = (ushort*)(ws + 7864320);          // 2269184 us
    ushort* WL   = (ushort*)(ws + 8998912);          // 2269184 us
    float*  CBT  = ws + 10133504;                    // 131072
    float*  BNT  = ws + 10264576;                    // 6144: enc1 8x256 @0 | enc2 512 @2048
                                                     //   | dec0 8x256 @2560 | dec1 8x128 @4608
                                                     //   | dec2 8x64 @5632
    float*  PART = ws + 10270720;                    // 8388608
    float*  D0   = ws + 18659328;                    // 2097152
    float*  D1   = ws + 20756480;                    // 4194304
    float*  D2   = ws + 24950784;                    // 8388608

    dim3 blk(256);

    // ---- prologue: zero BNT/losses + cbT + weight prep + enc0 conv (fused, independent) ----
    prologue<<<11448, blk, 0, stream>>>(enc_w1, enc_w2, enc_w3, dec_w0, dec_w1, dec_w2,
                                        WH, WL, cb, CBT, BNT, out,
                                        x, enc_w0, enc_b0, Y0, PST);

    // enc1: M=128 N=16384 K=1024, Mtiles=1 x Ntiles=512, KS=1 -> 512 blocks
    //       (no transform replication); direct Y1 + bias + 8-banked fused stats @BNT+0
    gemm_mfma<0><<<512, blk, 0, stream>>>(WH, WL, Y0,
        nullptr, ebn_g0, ebn_b0, 1.f / 65536.f, 4, enc_b1, Y1,
        1, 512, 1024, 1024, 1, 0, 64, 64, 128, 32, 5, 0, 0, 0, 0, BNT, PST, 256, 0);

    // enc2: M=256 N=4096 K=2048, KS=4, 32N tiles -> 1024 blocks; BN1 from 8 banks @BNT+0
    gemm_mfma<0><<<1024, blk, 0, stream>>>(WH + 131072, WL + 131072, Y1,
        BNT, ebn_g1, ebn_b1, 1.f / 16384.f, 4, enc_b2, PART,
        2, 128, 2048, 512, 4, 1048576, 128, 32, 256, 16, 4, 0, 0, 0, 0, nullptr, nullptr, 0, 256);
    reduce_bias_stats4<<<1024, blk, 0, stream>>>((const float4*)PART, enc_b2, (float4*)Y2,
                                                 BNT + 2048, 262144, 4, 256, 64, 4);

    // enc3: M=256 N=1024 K=4096, KS=16, 32N tiles -> 1024 blocks; partials -> VQ
    gemm_mfma<0><<<1024, blk, 0, stream>>>(WH + 655360, WL + 655360, Y2,
        BNT + 2048, ebn_g2, ebn_b2, 1.f / 4096.f, 4, enc_b3, PART,
        2, 32, 4096, 256, 16, 262144, 256, 16, 256, 8, 3, 0, 0, 0, 0, nullptr, nullptr, 0, 0);

    // ---- VQ: sums 16 partial slices + bias; emits pre-split QH/QL; fused loss ----
    vq_main<<<256, blk, 0, stream>>>(PART, enc_b3, CBT, cb, (ushort*)QHL, out);

    // ---- decoder ----
    // dec0: M=2048 N=1024 K=256, Mtiles=16 x Ntiles=32, KS=1 -> 512 blocks; MODE2
    //       (transform-free); direct D0 + bias + 8-banked fused stats @BNT+2560
    gemm_mfma<2><<<512, blk, 0, stream>>>(WH + 1703936, WL + 1703936, QHL,
        nullptr, nullptr, nullptr, 0.f, 0, dec_b0, D0,
        16, 32, 256, 256, 1, 0, 256, 8, 128, 262144, 0, 6, 3, 7, 2, BNT + 2560, nullptr, 256, 0);

    // dec1: M=256 N=16384 K=128, KS=1, 32N tiles -> 1024 blocks; BN3 from banks @BNT+2560;
    //       direct D1 + 8-banked stats @BNT+4608
    gemm_mfma<1><<<1024, blk, 0, stream>>>(WH + 2228224, WL + 2228224, D0,
        BNT + 2560, dbn_g0, dbn_b0, 1.f / 16384.f, 0, dec_b1, D1,
        2, 512, 128, 128, 1, 0, 128, 32, 64, 0, 0, 10, 5, 6, 1, BNT + 4608, nullptr, 128, 256);

    // dec2: M=128 N=65536 K=64, KS=1, 32N tiles -> 2048 blocks; BN4 from banks @BNT+4608;
    //       direct D2 + 8-banked stats @BNT+5632
    gemm_mfma<1><<<2048, blk, 0, stream>>>(WH + 2260992, WL + 2260992, D1,
        BNT + 4608, dbn_g1, dbn_b1, 1.f / 65536.f, 0, dec_b2, D2,
        1, 2048, 64, 64, 1, 0, 64, 64, 32, 0, 0, 12, 6, 5, 1, BNT + 5632, nullptr, 64, 128);

    // final: BN5 (8 banks @BNT+5632) + leaky + 1x1 conv + tanh (float4)
    final_conv_tanh<<<256, blk, 0, stream>>>(D2, BNT + 5632, dbn_g2, dbn_b2, dec_w3, dec_b3, out);
}

// Round 10
// 364.648 us; speedup vs baseline: 1.0813x; 1.0066x over previous
//
#include <hip/hip_runtime.h>
#include <math.h>

#define LEAK 0.01f

typedef __bf16 bf16x8 __attribute__((ext_vector_type(8)));
typedef float f32x4 __attribute__((ext_vector_type(4)));
typedef unsigned short ushort;
typedef unsigned int uint32;

struct HL { ushort h, l; };

// split fp32 into bf16 hi + bf16 lo (both RNE): x ~= hi + lo, err ~2^-17 rel
__device__ inline HL split_bf16(float x) {
    unsigned u = __float_as_uint(x);
    unsigned hr = (u + 0x7FFFu + ((u >> 16) & 1u)) >> 16;
    float fh = __uint_as_float(hr << 16);
    float r = x - fh;
    unsigned v = __float_as_uint(r);
    unsigned lr = (v + 0x7FFFu + ((v >> 16) & 1u)) >> 16;
    HL out; out.h = (ushort)hr; out.l = (ushort)lr;
    return out;
}

// ============ staged-B raw load: 32n x 64k fp32 tile, 8 floats/thread (2 k-halves) ============
// r8: N-MAJOR lane mapping (nl = tid&31, kg = tid>>5) — coalesced staging (measured win).
template<int MODE>
__device__ inline void stage_load(float (&pv)[2][4], const float* __restrict__ Bf,
                                  int kbase, int n0, int tid,
                                  int Ci, int Hin, int Ho, int lgHo, int lgHW) {
    int nl = tid & 31, kg = tid >> 5;
    int n = n0 + nl;
#pragma unroll
    for (int r = 0; r < 2; ++r) {
        if (MODE == 0) {
            int k4 = kbase + (r << 5) + (kg << 2);
            int ic = k4 >> 4, kh = (k4 >> 2) & 3;
            int ow = n & (Ho - 1), oh = (n >> lgHo) & (Ho - 1), b = n >> (lgHo + lgHo);
            int ih = oh * 2 - 1 + kh;
            int ihc = ih < 0 ? 0 : (ih >= Hin ? Hin - 1 : ih);
            int iwb = ow * 2 - 1;
            size_t base = ((size_t)(b * Ci + ic) * Hin + ihc) * Hin;
#pragma unroll
            for (int e = 0; e < 4; ++e) {
                int iw = iwb + e;
                int iwc = iw < 0 ? 0 : (iw >= Hin ? Hin - 1 : iw);
                pv[r][e] = Bf[base + iwc];
            }
        } else {
            int c = kbase + (r << 5) + (kg << 2);
            int b = n >> lgHW, hw = n & ((1 << lgHW) - 1);
            size_t base = (((size_t)(b * Ci + c)) << lgHW) + hw;
            size_t str = (size_t)1 << lgHW;
#pragma unroll
            for (int e = 0; e < 4; ++e) pv[r][e] = Bf[base + e * str];
        }
    }
}

// ================= bf16-split MFMA GEMM with fused BN+LeakyReLU on B-load =================
// Block tile 128M x 32N, 4 waves of 32M x 32N. K-step 64.
// r10: PREFETCH DISTANCE 2 — step s issues the gather for step s+2 (named pvA/pvB
// register sets, statically indexed via two call sites), so gather latency is hidden
// under a FULL step body (MFMA(s) + transform(s+1) + MFMA(s+1) ~ 1500+cy) instead of
// one MFMA section (~300-600cy). r9 counters: ~4000cy/step with ~1000cy of work ->
// ~3000cy stall attributed to the staging-gather wait at next step's transform.
// MODE 0: conv-im2col B; MODE 1: channel-major B; MODE 2: PRE-SPLIT B from global.
// statsBnt != nullptr (KS==1): fused per-channel sum/sumsq atomics, 8-way banked.
// bntBankStride > 0: input bnt is 8-banked; sum banks in prologue.
template<int MODE>
__global__ __launch_bounds__(256, 3) void gemm_mfma(
    const ushort* __restrict__ Ah, const ushort* __restrict__ Al,
    const float* __restrict__ Bf,
    const float* __restrict__ bnt, const float* __restrict__ gamma,
    const float* __restrict__ beta, float invN, int chanShift,
    const float* __restrict__ bias, float* __restrict__ P,
    int Mtiles, int Ntiles, int K, int Kslice, int KS, int outSize,
    int Ci, int Hin, int Co, int Ho, int lgHo,
    int lgHW, int lgHin, int lgCo, int lgk,
    float* __restrict__ statsBnt, const float* __restrict__ bnPart,
    int statsBank, int bntBankStride)
{
    __shared__ __align__(16) uint32 Bsp[32 * 68];   // [n][64k] packed, stride 68
    __shared__ float scs[256], shs[256];

    int bid = blockIdx.x;
    int ntile = bid % Ntiles; bid /= Ntiles;
    int mtile = bid % Mtiles;
    int ks = bid / Mtiles;
    int tid = threadIdx.x;
    int lane = tid & 63, w = tid >> 6;
    int quad = lane >> 4, tl = lane & 15;
    int n0 = ntile << 5, m0 = mtile << 7, k0 = ks * Kslice;
    int Kt = K >> 5;

    bool useBN = (bnt != nullptr) || (bnPart != nullptr);
    int c0 = k0 >> chanShift;
    if (bnPart != nullptr) {
        // BN0 from conv tile-partials: 64 channels x 256 (sum,sq) pairs
        int c = tid >> 2, qq = tid & 3;
        const float2* pp2 = (const float2*)(bnPart + c * 512) + qq * 64;
        float s = 0.f, s2 = 0.f;
#pragma unroll 8
        for (int p = 0; p < 64; ++p) { float2 v = pp2[p]; s += v.x; s2 += v.y; }
        scs[tid] = s; shs[tid] = s2;
        __syncthreads();
        float scale = 0.f, shift = 0.f;
        if (tid < 64) {
            float st = scs[tid * 4] + scs[tid * 4 + 1] + scs[tid * 4 + 2] + scs[tid * 4 + 3];
            float qt = shs[tid * 4] + shs[tid * 4 + 1] + shs[tid * 4 + 2] + shs[tid * 4 + 3];
            float m = st * invN;
            float var = qt * invN - m * m;
            scale = gamma[tid] * rsqrtf(var + 1e-5f);
            shift = beta[tid] - m * scale;
        }
        __syncthreads();
        // store shifted so the transform's scs[ic - c0] indexing works for any K-slice
        if (tid < 64 && tid >= c0) { scs[tid - c0] = scale; shs[tid - c0] = shift; }
    } else if (bnt != nullptr) {
        int nch = Kslice >> chanShift;
        for (int c = tid; c < nch; c += 256) {
            float sm, sq;
            if (bntBankStride > 0) {
                sm = 0.f; sq = 0.f;
#pragma unroll
                for (int bk = 0; bk < 8; ++bk) {
                    sm += bnt[bk * bntBankStride + (c0 + c) * 2];
                    sq += bnt[bk * bntBankStride + (c0 + c) * 2 + 1];
                }
            } else {
                sm = bnt[(c0 + c) * 2];
                sq = bnt[(c0 + c) * 2 + 1];
            }
            float m = sm * invN;
            float var = sq * invN - m * m;
            float scale = gamma[c0 + c] * rsqrtf(var + 1e-5f);
            scs[c] = scale;
            shs[c] = beta[c0 + c] - m * scale;
        }
    }
    __syncthreads();

    f32x4 zero4 = {0.f, 0.f, 0.f, 0.f};
    f32x4 acc[2][2];
#pragma unroll
    for (int mt = 0; mt < 2; ++mt)
#pragma unroll
        for (int nt = 0; nt < 2; ++nt) acc[mt][nt] = zero4;

    if (MODE == 2) {
        // ---- barrier-free K-loop: B pre-split in global (L2-resident) ----
        const ushort* Bu = (const ushort*)Bf;
        for (int kc = 0; kc < Kslice; kc += 32) {
            int kbase = k0 + kc;
            int kt = kbase >> 5;
            bf16x8 afh[2], afl[2];
#pragma unroll
            for (int mt = 0; mt < 2; ++mt) {
                int mtAbs = (m0 >> 4) + (w << 1) + mt;
                size_t abase = (((size_t)mtAbs * Kt + kt) << 6) + lane;
                afh[mt] = *(const bf16x8*)(Ah + abase * 8);
                afl[mt] = *(const bf16x8*)(Al + abase * 8);
            }
            bf16x8 bfh[2], bfl[2];
#pragma unroll
            for (int nt = 0; nt < 2; ++nt) {
                int n = n0 + (nt << 4) + tl;
                size_t ba = (size_t)n * Ci + kbase + (quad << 3);
                bfh[nt] = *(const bf16x8*)(Bu + ba);
                bfl[nt] = *(const bf16x8*)(Bu + Ho + ba);
            }
#pragma unroll
            for (int mt = 0; mt < 2; ++mt)
#pragma unroll
                for (int nt = 0; nt < 2; ++nt) {
                    acc[mt][nt] = __builtin_amdgcn_mfma_f32_16x16x32_bf16(afh[mt], bfh[nt], acc[mt][nt], 0, 0, 0);
                    acc[mt][nt] = __builtin_amdgcn_mfma_f32_16x16x32_bf16(afh[mt], bfl[nt], acc[mt][nt], 0, 0, 0);
                    acc[mt][nt] = __builtin_amdgcn_mfma_f32_16x16x32_bf16(afl[mt], bfh[nt], acc[mt][nt], 0, 0, 0);
                }
        }
    } else {
        // ---- staged K-loop, BK=64, prefetch distance 2 (pvA even steps / pvB odd) ----
        int nsteps = Kslice >> 6;
        float pvA[2][4], pvB[2][4];
        stage_load<MODE>(pvA, Bf, k0, n0, tid, Ci, Hin, Ho, lgHo, lgHW);
        if (nsteps > 1) stage_load<MODE>(pvB, Bf, k0 + 64, n0, tid, Ci, Hin, Ho, lgHo, lgHW);

        auto step = [&](float (&pv)[2][4], int sidx) {
            int kbase = k0 + (sidx << 6);
            // ---- transform both k-halves + regs -> LDS (n-major lane map, r8) ----
            int nl = tid & 31, kg = tid >> 5;
#pragma unroll
            for (int r = 0; r < 2; ++r) {
                int k4 = kbase + (r << 5) + (kg << 2);
                uint32 pk[4];
                if (MODE == 0) {
                    int ic = k4 >> 4, kh = (k4 >> 2) & 3;
                    int n = n0 + nl;
                    int ow = n & (Ho - 1), oh = (n >> lgHo) & (Ho - 1);
                    int ih = oh * 2 - 1 + kh;
                    bool rowok = (unsigned)ih < (unsigned)Hin;
                    int iwb = ow * 2 - 1;
                    float sc_ = useBN ? scs[ic - c0] : 0.f;
                    float sh_ = useBN ? shs[ic - c0] : 0.f;
#pragma unroll
                    for (int e = 0; e < 4; ++e) {
                        int iw = iwb + e;
                        bool ok = rowok && ((unsigned)iw < (unsigned)Hin);
                        float f = pv[r][e];
                        if (useBN) { f = f * sc_ + sh_; f = f >= 0.f ? f : LEAK * f; }
                        if (!ok) f = 0.f;
                        HL s = split_bf16(f);
                        pk[e] = ((uint32)s.h << 16) | s.l;
                    }
                } else {
#pragma unroll
                    for (int e = 0; e < 4; ++e) {
                        float f = pv[r][e];
                        if (useBN) {
                            int lc = k4 + e - k0;
                            f = f * scs[lc] + shs[lc];
                            f = f >= 0.f ? f : LEAK * f;
                        }
                        HL s = split_bf16(f);
                        pk[e] = ((uint32)s.h << 16) | s.l;
                    }
                }
                *(uint4*)&Bsp[nl * 68 + (r << 5) + (kg << 2)] = make_uint4(pk[0], pk[1], pk[2], pk[3]);
            }
            __syncthreads();

            // ---- distance-2 prefetch: refill THIS register set for step sidx+2 ----
            if (sidx + 2 < nsteps)
                stage_load<MODE>(pv, Bf, kbase + 128, n0, tid, Ci, Hin, Ho, lgHo, lgHW);

            // ---- two 32-K substeps from LDS ----
#pragma unroll
            for (int sub = 0; sub < 2; ++sub) {
                int kt = (kbase >> 5) + sub;
                bf16x8 afh[2], afl[2];
#pragma unroll
                for (int mt = 0; mt < 2; ++mt) {
                    int mtAbs = (m0 >> 4) + (w << 1) + mt;
                    size_t abase = (((size_t)mtAbs * Kt + kt) << 6) + lane;
                    afh[mt] = *(const bf16x8*)(Ah + abase * 8);
                    afl[mt] = *(const bf16x8*)(Al + abase * 8);
                }
                bf16x8 bfh[2], bfl[2];
#pragma unroll
                for (int nt = 0; nt < 2; ++nt) {
                    int base = ((nt << 4) + tl) * 68 + (sub << 5) + (quad << 3);
                    uint4 ua = *(const uint4*)&Bsp[base];
                    uint4 ub = *(const uint4*)&Bsp[base + 4];
                    union { uint32 u[4]; bf16x8 v; } H, L;
                    H.u[0] = __builtin_amdgcn_perm(ua.y, ua.x, 0x07060302u);
                    H.u[1] = __builtin_amdgcn_perm(ua.w, ua.z, 0x07060302u);
                    H.u[2] = __builtin_amdgcn_perm(ub.y, ub.x, 0x07060302u);
                    H.u[3] = __builtin_amdgcn_perm(ub.w, ub.z, 0x07060302u);
                    L.u[0] = __builtin_amdgcn_perm(ua.y, ua.x, 0x05040100u);
                    L.u[1] = __builtin_amdgcn_perm(ua.w, ua.z, 0x05040100u);
                    L.u[2] = __builtin_amdgcn_perm(ub.y, ub.x, 0x05040100u);
                    L.u[3] = __builtin_amdgcn_perm(ub.w, ub.z, 0x05040100u);
                    bfh[nt] = H.v; bfl[nt] = L.v;
                }
#pragma unroll
                for (int mt = 0; mt < 2; ++mt)
#pragma unroll
                    for (int nt = 0; nt < 2; ++nt) {
                        acc[mt][nt] = __builtin_amdgcn_mfma_f32_16x16x32_bf16(afh[mt], bfh[nt], acc[mt][nt], 0, 0, 0);
                        acc[mt][nt] = __builtin_amdgcn_mfma_f32_16x16x32_bf16(afh[mt], bfl[nt], acc[mt][nt], 0, 0, 0);
                        acc[mt][nt] = __builtin_amdgcn_mfma_f32_16x16x32_bf16(afl[mt], bfh[nt], acc[mt][nt], 0, 0, 0);
                    }
            }
            __syncthreads();
        };

        for (int s = 0; s < nsteps; s += 2) {
            step(pvA, s);
            if (s + 1 < nsteps) step(pvB, s + 1);
        }
    }

    // ---- epilogue: D[m = quad*4+reg][n = tl] + optional fused stats (KS==1 paths) ----
    bool doStats = (statsBnt != nullptr);
    if (doStats) {
        if (tid < 2 * Co) scs[tid] = 0.f;
        __syncthreads();
    }
    float ssum[2][4] = {{0.f,0.f,0.f,0.f},{0.f,0.f,0.f,0.f}};
    float ssq [2][4] = {{0.f,0.f,0.f,0.f},{0.f,0.f,0.f,0.f}};
    float* dst = P + (size_t)ks * outSize;
    if (MODE == 0) {
#pragma unroll
        for (int nt = 0; nt < 2; ++nt) {
            int n = n0 + (nt << 4) + tl;
            int ow = n & (Ho - 1), oh = (n >> lgHo) & (Ho - 1), b = n >> (lgHo + lgHo);
#pragma unroll
            for (int mt = 0; mt < 2; ++mt) {
                int mb = m0 + (w << 5) + (mt << 4) + (quad << 2);
#pragma unroll
                for (int r = 0; r < 4; ++r) {
                    int oc = mb + r;
                    float v = acc[mt][nt][r];
                    if (KS == 1) v += bias[oc];
                    if (doStats) { ssum[mt][r] += v; ssq[mt][r] += v * v; }
                    dst[((size_t)(b * Co + oc) * Ho + oh) * Ho + ow] = v;
                }
            }
        }
    } else {
        int kf = 1 << lgk;
        int Ho2 = Hin << lgk;
#pragma unroll
        for (int nt = 0; nt < 2; ++nt) {
            int n = n0 + (nt << 4) + tl;
            int b = n >> lgHW, hw = n & ((1 << lgHW) - 1);
            int h = hw >> lgHin, wp = hw & (Hin - 1);
#pragma unroll
            for (int mt = 0; mt < 2; ++mt) {
                int mb = m0 + (w << 5) + (mt << 4) + (quad << 2);
#pragma unroll
                for (int r = 0; r < 4; ++r) {
                    int m = mb + r;
                    int o = m & (Co - 1), ij = m >> lgCo;
                    int ii = ij >> lgk, jj = ij & (kf - 1);
                    float v = acc[mt][nt][r];
                    if (KS == 1) v += bias[o];
                    if (doStats) { ssum[mt][r] += v; ssq[mt][r] += v * v; }
                    dst[((size_t)(b * Co + o) * Ho2 + (h << lgk) + ii) * Ho2 + (wp << lgk) + jj] = v;
                }
            }
        }
    }
    if (doStats) {
        // reduce over the 16 lanes (tl) sharing identical channels
#pragma unroll
        for (int mt = 0; mt < 2; ++mt)
#pragma unroll
            for (int r = 0; r < 4; ++r) {
                float s = ssum[mt][r], q2 = ssq[mt][r];
#pragma unroll
                for (int m2 = 1; m2 < 16; m2 <<= 1) {
                    s  += __shfl_xor(s,  m2);
                    q2 += __shfl_xor(q2, m2);
                }
                if (tl == 0) {
                    int m = m0 + (w << 5) + (mt << 4) + (quad << 2) + r;
                    int o = (MODE == 0) ? m : (m & (Co - 1));
                    atomicAdd(&scs[o * 2],     s);
                    atomicAdd(&scs[o * 2 + 1], q2);
                }
            }
        __syncthreads();
        float* sb = statsBnt + (blockIdx.x & 7) * statsBank;
        if (tid < 2 * Co) atomicAdd(&sb[tid], scs[tid]);
    }
}

// ================= weight prep address =================
__device__ inline int fragaddr(int m, int k, int K) {
    return ((((m >> 4) * (K >> 5) + (k >> 5)) << 9) | (((k >> 3) & 3) << 7) | ((m & 15) << 3) | (k & 7));
}

#define OUT_CL   786432
#define OUT_CB   786433
#define OUT_IDX  786434
#define OUT_MIND 787458

// ================= enc0 direct conv (Ci=3) with non-atomic per-tile BN stat partials =================
__device__ void conv_body(int bid, int tid,
                          const float* __restrict__ x, const float* __restrict__ w,
                          const float* __restrict__ bias, float* __restrict__ P,
                          float* __restrict__ pst, float (&cst)[4][16])
{
    const int Ci = 3, Hin = 128, Co = 64, Ho = 64, OCT = 8;
    int ntile = (16 * Ho * Ho) >> 8;          // 256
    int tile = bid % ntile;
    int og = bid / ntile;
    int oc0 = og * OCT;

    int px = (tile << 8) + tid;
    int ow = px % Ho; int t = px / Ho;
    int oh = t % Ho;  int b = t / Ho;

    int off[16]; float fm[16];
    int ih0 = oh * 2 - 1, iw0 = ow * 2 - 1;
#pragma unroll
    for (int kh = 0; kh < 4; ++kh)
#pragma unroll
        for (int kw = 0; kw < 4; ++kw) {
            int ih = ih0 + kh, iw = iw0 + kw;
            bool ok = (ih >= 0) && (ih < Hin) && (iw >= 0) && (iw < Hin);
            int ihc = ih < 0 ? 0 : (ih >= Hin ? Hin - 1 : ih);
            int iwc = iw < 0 ? 0 : (iw >= Hin ? Hin - 1 : iw);
            off[kh * 4 + kw] = ihc * Hin + iwc;
            fm[kh * 4 + kw] = ok ? 1.f : 0.f;
        }

    float acc[OCT];
#pragma unroll
    for (int u = 0; u < OCT; ++u) acc[u] = bias[oc0 + u];

    const float* xc = x + (size_t)b * Ci * Hin * Hin;
    const float* wi = w + (size_t)oc0 * Ci * 16;
    int HinHin = Hin * Hin;
    for (int ic = 0; ic < Ci; ++ic) {
        float xv[16];
#pragma unroll
        for (int q = 0; q < 16; ++q) xv[q] = xc[off[q]] * fm[q];
#pragma unroll
        for (int u = 0; u < OCT; ++u) {
            const float* wo = wi + (size_t)u * Ci * 16;
            float a = acc[u];
#pragma unroll
            for (int q = 0; q < 16; ++q) a += xv[q] * wo[q];
            acc[u] = a;
        }
        xc += HinHin;
        wi += 16;
    }
    size_t obase = (((size_t)b * Co + oc0) * Ho + oh) * Ho + ow;
    size_t opl = (size_t)Ho * Ho;
#pragma unroll
    for (int u = 0; u < OCT; ++u) P[obase + u * opl] = acc[u];

    // ---- BN stat partials: butterfly over 64 lanes, combine 4 waves, plain store ----
    float sv[OCT], qv[OCT];
#pragma unroll
    for (int u = 0; u < OCT; ++u) { sv[u] = acc[u]; qv[u] = acc[u] * acc[u]; }
#pragma unroll
    for (int m2 = 1; m2 < 64; m2 <<= 1)
#pragma unroll
        for (int u = 0; u < OCT; ++u) {
            sv[u] += __shfl_xor(sv[u], m2);
            qv[u] += __shfl_xor(qv[u], m2);
        }
    int lane = tid & 63, wv = tid >> 6;
    if (lane == 0) {
#pragma unroll
        for (int u = 0; u < OCT; ++u) { cst[wv][u * 2] = sv[u]; cst[wv][u * 2 + 1] = qv[u]; }
    }
    __syncthreads();
    if (tid < 2 * OCT) {
        float v = cst[0][tid] + cst[1][tid] + cst[2][tid] + cst[3][tid];
        pst[(oc0 + (tid >> 1)) * 512 + tile * 2 + (tid & 1)] = v;
    }
}

// ================= fused prologue: zero BNT/losses + cbT + weight prep + enc0 conv =================
__global__ void prologue(const float* __restrict__ w1, const float* __restrict__ w2,
                         const float* __restrict__ w3, const float* __restrict__ d0,
                         const float* __restrict__ d1, const float* __restrict__ d2,
                         ushort* __restrict__ WH, ushort* __restrict__ WL,
                         const float* __restrict__ cb, float* __restrict__ cbT,
                         float* __restrict__ bnt, float* __restrict__ dout,
                         const float* __restrict__ x, const float* __restrict__ w0,
                         const float* __restrict__ b0, float* __restrict__ Y0,
                         float* __restrict__ pst) {
    __shared__ float cst[4][16];
    int blk = blockIdx.x;
    int tid = threadIdx.x;
    if (blk < 24) {                          // zero BN totals + loss accumulators
        bnt[blk * 256 + tid] = 0.f;
        if (blk == 0 && tid < 2) dout[OUT_CL + tid] = 0.f;
        return;
    }
    if (blk < 536) {                         // codebook transpose
        int idx = (blk - 24) * 256 + tid;
        int k = idx & 511, c = idx >> 9;
        cbT[idx] = cb[k * 256 + c];
        return;
    }
    if (blk >= 9400) {                       // enc0 direct conv (2048 blocks)
        conv_body(blk - 9400, tid, x, w0, b0, Y0, pst, cst);
        return;
    }
    int idx = (blk - 536) * 256 + tid;       // weight split+reorder
    if (idx >= 2269184) return;
    float v; int dst;
    if (idx < 131072) {                      // enc1: M=128 K=1024
        int m = idx >> 10, k = idx & 1023;
        v = w1[idx];
        dst = fragaddr(m, k, 1024);
    } else if (idx < 655360) {               // enc2: M=256 K=2048
        int i = idx - 131072;
        int m = i >> 11, k = i & 2047;
        v = w2[i];
        dst = 131072 + fragaddr(m, k, 2048);
    } else if (idx < 1703936) {              // enc3: M=256 K=4096
        int i = idx - 655360;
        int m = i >> 12, k = i & 4095;
        v = w3[i];
        dst = 655360 + fragaddr(m, k, 4096);
    } else if (idx < 2228224) {              // dec0: M=2048 K=256
        int i = idx - 1703936;
        int m = i >> 8, c = i & 255;
        int o = m & 127, ij = m >> 7;
        v = d0[((size_t)c * 128 + o) * 16 + ij];
        dst = 1703936 + fragaddr(m, c, 256);
    } else if (idx < 2260992) {              // dec1: M=256 K=128
        int i = idx - 2228224;
        int m = i >> 7, c = i & 127;
        int o = m & 63, ij = m >> 6;
        v = d1[((size_t)c * 64 + o) * 4 + ij];
        dst = 2228224 + fragaddr(m, c, 128);
    } else {                                 // dec2: M=128 K=64
        int i = idx - 2260992;
        int m = i >> 6, c = i & 63;
        int o = m & 31, ij = m >> 5;
        v = d2[((size_t)c * 32 + o) * 4 + ij];
        dst = 2260992 + fragaddr(m, c, 64);
    }
    HL s = split_bf16(v);
    WH[dst] = s.h; WL[dst] = s.l;
}

// ================= reduce partials + BN stats (enc2 only) =================
__global__ void reduce_bias_stats4(const float4* __restrict__ P, const float* __restrict__ bias,
                                   float4* __restrict__ y, float* __restrict__ bnt,
                                   int outSize4, int KS, int Co, int HW4, int nch) {
    int tid = threadIdx.x;
    int i = blockIdx.x * 256 + tid;
    int c = (i / HW4) % Co;
    float bv = bias[c];
    float4 s = make_float4(bv, bv, bv, bv);
    for (int ks = 0; ks < KS; ++ks) {
        float4 p = P[(size_t)ks * outSize4 + i];
        s.x += p.x; s.y += p.y; s.z += p.z; s.w += p.w;
    }
    y[i] = s;
    float ls  = s.x + s.y + s.z + s.w;
    float ls2 = s.x * s.x + s.y * s.y + s.z * s.z + s.w * s.w;
    __shared__ float as[16], aq[16];
    if (tid < 16) { as[tid] = 0.f; aq[tid] = 0.f; }
    __syncthreads();
    int c0 = ((blockIdx.x * 256) / HW4) % Co;
    atomicAdd(&as[c - c0], ls);
    atomicAdd(&aq[c - c0], ls2);
    __syncthreads();
    if (tid < nch) {
        atomicAdd(&bnt[(c0 + tid) * 2],     as[tid]);
        atomicAdd(&bnt[(c0 + tid) * 2 + 1], aq[tid]);
    }
}

// ================= Vector quantizer: sums 16 enc3 partial slices on load; writes
// pre-split QH/QL bf16 [n][k] row-major for dec0 MODE2; fused loss =================
__global__ void vq_main(const float* __restrict__ Pz, const float* __restrict__ b3,
                        const float* __restrict__ cbT, const float* __restrict__ cb,
                        ushort* __restrict__ qhl, float* __restrict__ dout) {
    int r0 = blockIdx.x * 4;
    int tid = threadIdx.x;
    int lane = tid & 63, w = tid >> 6;

    __shared__ __align__(16) float zT[256][4];
    __shared__ float wred[4][4];
    __shared__ float zn2s[4];
    __shared__ float wbd[4][4];
    __shared__ int   wbi[4][4];
    __shared__ int   bestsh[4];
    __shared__ float bestd[4];

    int b = r0 >> 6, s0 = r0 & 63;
    size_t zi = ((size_t)(b * 256 + tid)) * 64 + s0;
    float bv = b3[tid];
    float4 zv = make_float4(bv, bv, bv, bv);
    const float4* pp = (const float4*)Pz + (zi >> 2);
#pragma unroll
    for (int ks = 0; ks < 16; ++ks) {
        float4 p = pp[(size_t)ks * 65536];
        zv.x += p.x; zv.y += p.y; zv.z += p.z; zv.w += p.w;
    }
    *(float4*)&zT[tid][0] = zv;

    // ---- per-row |z|^2 via butterfly sum over channels ----
    float p0 = zv.x * zv.x, p1 = zv.y * zv.y, p2 = zv.z * zv.z, p3 = zv.w * zv.w;
#pragma unroll
    for (int m2 = 1; m2 < 64; m2 <<= 1) {
        p0 += __shfl_xor(p0, m2); p1 += __shfl_xor(p1, m2);
        p2 += __shfl_xor(p2, m2); p3 += __shfl_xor(p3, m2);
    }
    if (lane == 0) { wred[w][0] = p0; wred[w][1] = p1; wred[w][2] = p2; wred[w][3] = p3; }
    __syncthreads();
    if (tid < 4) zn2s[tid] = wred[0][tid] + wred[1][tid] + wred[2][tid] + wred[3][tid];
    __syncthreads();

    // ---- dot products: thread owns codebook entries k=tid and k=tid+256 ----
    float d0[4], d1[4];
#pragma unroll
    for (int rr = 0; rr < 4; ++rr) { d0[rr] = 0.f; d1[rr] = 0.f; }
    float cn0 = 0.f, cn1 = 0.f;
#pragma unroll 4
    for (int c = 0; c < 256; ++c) {
        float cv0 = cbT[c * 512 + tid];
        float cv1 = cbT[c * 512 + 256 + tid];
        cn0 += cv0 * cv0;
        cn1 += cv1 * cv1;
        float4 za = *(const float4*)&zT[c][0];
        d0[0] += za.x * cv0; d1[0] += za.x * cv1;
        d0[1] += za.y * cv0; d1[1] += za.y * cv1;
        d0[2] += za.z * cv0; d1[2] += za.z * cv1;
        d0[3] += za.w * cv0; d1[3] += za.w * cv1;
    }

    // ---- argmin via butterfly (tie-break: smaller index) ----
#pragma unroll
    for (int rr = 0; rr < 4; ++rr) {
        float dist0 = zn2s[rr] - 2.f * d0[rr] + cn0;
        float dist1 = zn2s[rr] - 2.f * d1[rr] + cn1;
        float bd = dist0; int bi = tid;
        if (dist1 < bd) { bd = dist1; bi = tid + 256; }
#pragma unroll
        for (int m2 = 1; m2 < 64; m2 <<= 1) {
            float od = __shfl_xor(bd, m2); int oi = __shfl_xor(bi, m2);
            if (od < bd || (od == bd && oi < bi)) { bd = od; bi = oi; }
        }
        if (lane == 0) { wbd[w][rr] = bd; wbi[w][rr] = bi; }
    }
    __syncthreads();
    if (tid < 4) {
        float bd = wbd[0][tid]; int bi = wbi[0][tid];
#pragma unroll
        for (int ww = 1; ww < 4; ++ww) {
            float od = wbd[ww][tid]; int oi = wbi[ww][tid];
            if (od < bd || (od == bd && oi < bi)) { bd = od; bi = oi; }
        }
        bestsh[tid] = bi; bestd[tid] = bd;
        dout[OUT_IDX + r0 + tid]  = (float)bi;
        dout[OUT_MIND + r0 + tid] = bd;
    }
    __syncthreads();

    // ---- gather quantized rows, split to bf16 hi/lo, store [n][k] (n = r0+rr) ----
#pragma unroll
    for (int rr = 0; rr < 4; ++rr) {
        float v = cb[(size_t)bestsh[rr] * 256 + tid];
        HL s = split_bf16(v);
        size_t o = (size_t)(r0 + rr) * 256 + tid;
        qhl[o]          = s.h;
        qhl[262144 + o] = s.l;
    }
    if (tid == 0) {
        float ls = (bestd[0] + bestd[1] + bestd[2] + bestd[3]) * (1.f / 262144.f);
        atomicAdd(&dout[OUT_CL], ls);
        atomicAdd(&dout[OUT_CB], ls);
    }
}

// ================= Final: BN(D2, 8-banked stats) + LeakyReLU + 1x1 conv + tanh =================
__global__ void final_conv_tanh(const float* __restrict__ hbuf, const float* __restrict__ bnt,
                                const float* __restrict__ g, const float* __restrict__ bt,
                                const float* __restrict__ w3, const float* __restrict__ b3,
                                float* __restrict__ out) {
    __shared__ float sc[32], sh[32], sw[96];
    int tid = threadIdx.x;
    if (tid < 32) {
        float sm = 0.f, sq = 0.f;
#pragma unroll
        for (int bk = 0; bk < 8; ++bk) {
            sm += bnt[bk * 64 + tid * 2];
            sq += bnt[bk * 64 + tid * 2 + 1];
        }
        float m = sm * (1.f / 262144.f);
        float var = sq * (1.f / 262144.f) - m * m;
        float scale = g[tid] * rsqrtf(var + 1e-5f);
        sc[tid] = scale;
        sh[tid] = bt[tid] - m * scale;
    }
    if (tid < 96) sw[tid] = w3[tid];
    __syncthreads();
    int idx = blockIdx.x * 256 + tid;          // 65536 = 16 * 4096 float4 pixels
    int hw4 = idx & 4095;
    int b   = idx >> 12;
    const float4* hp = (const float4*)hbuf + ((size_t)b * 32) * 4096 + hw4;
    float b0 = b3[0], b1 = b3[1], b2 = b3[2];
    float4 a0 = make_float4(b0, b0, b0, b0);
    float4 a1 = make_float4(b1, b1, b1, b1);
    float4 a2 = make_float4(b2, b2, b2, b2);
#pragma unroll 8
    for (int c = 0; c < 32; ++c) {
        float4 v = hp[(size_t)c * 4096];
        float scv = sc[c], shv = sh[c];
        float vx = v.x * scv + shv; vx = vx >= 0.f ? vx : LEAK * vx;
        float vy = v.y * scv + shv; vy = vy >= 0.f ? vy : LEAK * vy;
        float vz = v.z * scv + shv; vz = vz >= 0.f ? vz : LEAK * vz;
        float vw = v.w * scv + shv; vw = vw >= 0.f ? vw : LEAK * vw;
        float w0 = sw[c], w1 = sw[32 + c], w2 = sw[64 + c];
        a0.x += vx * w0; a0.y += vy * w0; a0.z += vz * w0; a0.w += vw * w0;
        a1.x += vx * w1; a1.y += vy * w1; a1.z += vz * w1; a1.w += vw * w1;
        a2.x += vx * w2; a2.y += vy * w2; a2.z += vz * w2; a2.w += vw * w2;
    }
    float4* op = (float4*)out;
    size_t ob = ((size_t)b * 3) * 4096 + hw4;
    op[ob]            = make_float4(tanhf(a0.x), tanhf(a0.y), tanhf(a0.z), tanhf(a0.w));
    op[ob + 4096]     = make_float4(tanhf(a1.x), tanhf(a1.y), tanhf(a1.z), tanhf(a1.w));
    op[ob + 2 * 4096] = make_float4(tanhf(a2.x), tanhf(a2.y), tanhf(a2.z), tanhf(a2.w));
}

extern "C" void kernel_launch(void* const* d_in, const int* in_sizes, int n_in,
                              void* d_out, int out_size, void* d_ws, size_t ws_size,
                              hipStream_t stream) {
    const float* x      = (const float*)d_in[0];
    const float* enc_w0 = (const float*)d_in[1];
    const float* enc_b0 = (const float*)d_in[2];
    const float* enc_w1 = (const float*)d_in[3];
    const float* enc_b1 = (const float*)d_in[4];
    const float* enc_w2 = (const float*)d_in[5];
    const float* enc_b2 = (const float*)d_in[6];
    const float* enc_w3 = (const float*)d_in[7];
    const float* enc_b3 = (const float*)d_in[8];
    const float* ebn_g0 = (const float*)d_in[9];
    const float* ebn_b0 = (const float*)d_in[10];
    const float* ebn_g1 = (const float*)d_in[11];
    const float* ebn_b1 = (const float*)d_in[12];
    const float* ebn_g2 = (const float*)d_in[13];
    const float* ebn_b2 = (const float*)d_in[14];
    const float* cb     = (const float*)d_in[15];
    const float* dec_w0 = (const float*)d_in[16];
    const float* dec_b0 = (const float*)d_in[17];
    const float* dbn_g0 = (const float*)d_in[18];
    const float* dbn_b0 = (const float*)d_in[19];
    const float* dec_w1 = (const float*)d_in[20];
    const float* dec_b1 = (const float*)d_in[21];
    const float* dbn_g1 = (const float*)d_in[22];
    const float* dbn_b1 = (const float*)d_in[23];
    const float* dec_w2 = (const float*)d_in[24];
    const float* dec_b2 = (const float*)d_in[25];
    const float* dbn_g2 = (const float*)d_in[26];
    const float* dbn_b2 = (const float*)d_in[27];
    const float* dec_w3 = (const float*)d_in[28];
    const float* dec_b3 = (const float*)d_in[29];

    float* out = (float*)d_out;
    float* ws  = (float*)d_ws;

    // ---- workspace (float units) ----
    float*  Y0   = ws;                               // 4194304
    float*  Y1   = ws + 4194304;                     // 2097152
    float*  Y2   = ws + 6291456;                     // 1048576
    float*  PST  = ws + 7340032;                     // 32768 (conv BN0 partials)
    float*  QHL  = ws + 7602176;                     // 262144 fl = 524288 us (QH | QL)
    ushort* WH   = (ushort*)(ws + 7864320);          // 2269184 us
    ushort* WL   = (ushort*)(ws + 8998912);          // 2269184 us
    float*  CBT  = ws + 10133504;                    // 131072
    float*  BNT  = ws + 10264576;                    // 6144: enc1 8x256 @0 | enc2 512 @2048
                                                     //   | dec0 8x256 @2560 | dec1 8x128 @4608
                                                     //   | dec2 8x64 @5632
    float*  PART = ws + 10270720;                    // 8388608
    float*  D0   = ws + 18659328;                    // 2097152
    float*  D1   = ws + 20756480;                    // 4194304
    float*  D2   = ws + 24950784;                    // 8388608

    dim3 blk(256);

    // ---- prologue: zero BNT/losses + cbT + weight prep + enc0 conv (fused, independent) ----
    prologue<<<11448, blk, 0, stream>>>(enc_w1, enc_w2, enc_w3, dec_w0, dec_w1, dec_w2,
                                        WH, WL, cb, CBT, BNT, out,
                                        x, enc_w0, enc_b0, Y0, PST);

    // enc1: M=128 N=16384 K=1024, Mtiles=1 x Ntiles=512, KS=1 -> 512 blocks
    //       (no transform replication); direct Y1 + bias + 8-banked fused stats @BNT+0
    gemm_mfma<0><<<512, blk, 0, stream>>>(WH, WL, Y0,
        nullptr, ebn_g0, ebn_b0, 1.f / 65536.f, 4, enc_b1, Y1,
        1, 512, 1024, 1024, 1, 0, 64, 64, 128, 32, 5, 0, 0, 0, 0, BNT, PST, 256, 0);

    // enc2: M=256 N=4096 K=2048, KS=4, 32N tiles -> 1024 blocks; BN1 from 8 banks @BNT+0
    gemm_mfma<0><<<1024, blk, 0, stream>>>(WH + 131072, WL + 131072, Y1,
        BNT, ebn_g1, ebn_b1, 1.f / 16384.f, 4, enc_b2, PART,
        2, 128, 2048, 512, 4, 1048576, 128, 32, 256, 16, 4, 0, 0, 0, 0, nullptr, nullptr, 0, 256);
    reduce_bias_stats4<<<1024, blk, 0, stream>>>((const float4*)PART, enc_b2, (float4*)Y2,
                                                 BNT + 2048, 262144, 4, 256, 64, 4);

    // enc3: M=256 N=1024 K=4096, KS=16, 32N tiles -> 1024 blocks; partials -> VQ
    gemm_mfma<0><<<1024, blk, 0, stream>>>(WH + 655360, WL + 655360, Y2,
        BNT + 2048, ebn_g2, ebn_b2, 1.f / 4096.f, 4, enc_b3, PART,
        2, 32, 4096, 256, 16, 262144, 256, 16, 256, 8, 3, 0, 0, 0, 0, nullptr, nullptr, 0, 0);

    // ---- VQ: sums 16 partial slices + bias; emits pre-split QH/QL; fused loss ----
    vq_main<<<256, blk, 0, stream>>>(PART, enc_b3, CBT, cb, (ushort*)QHL, out);

    // ---- decoder ----
    // dec0: M=2048 N=1024 K=256, Mtiles=16 x Ntiles=32, KS=1 -> 512 blocks; MODE2
    //       (transform-free); direct D0 + bias + 8-banked fused stats @BNT+2560
    gemm_mfma<2><<<512, blk, 0, stream>>>(WH + 1703936, WL + 1703936, QHL,
        nullptr, nullptr, nullptr, 0.f, 0, dec_b0, D0,
        16, 32, 256, 256, 1, 0, 256, 8, 128, 262144, 0, 6, 3, 7, 2, BNT + 2560, nullptr, 256, 0);

    // dec1: M=256 N=16384 K=128, KS=1, 32N tiles -> 1024 blocks; BN3 from banks @BNT+2560;
    //       direct D1 + 8-banked stats @BNT+4608
    gemm_mfma<1><<<1024, blk, 0, stream>>>(WH + 2228224, WL + 2228224, D0,
        BNT + 2560, dbn_g0, dbn_b0, 1.f / 16384.f, 0, dec_b1, D1,
        2, 512, 128, 128, 1, 0, 128, 32, 64, 0, 0, 10, 5, 6, 1, BNT + 4608, nullptr, 128, 256);

    // dec2: M=128 N=65536 K=64, KS=1, 32N tiles -> 2048 blocks; BN4 from banks @BNT+4608;
    //       direct D2 + 8-banked stats @BNT+5632
    gemm_mfma<1><<<2048, blk, 0, stream>>>(WH + 2260992, WL + 2260992, D1,
        BNT + 4608, dbn_g1, dbn_b1, 1.f / 65536.f, 0, dec_b2, D2,
        1, 2048, 64, 64, 1, 0, 64, 64, 32, 0, 0, 12, 6, 5, 1, BNT + 5632, nullptr, 64, 128);

    // final: BN5 (8 banks @BNT+5632) + leaky + 1x1 conv + tanh (float4)
    final_conv_tanh<<<256, blk, 0, stream>>>(D2, BNT + 5632, dbn_g2, dbn_b2, dec_w3, dec_b3, out);
}

// Round 11
// 352.720 us; speedup vs baseline: 1.1179x; 1.0338x over previous
//
#include <hip/hip_runtime.h>
#include <math.h>

#define LEAK 0.01f

typedef __bf16 bf16x8 __attribute__((ext_vector_type(8)));
typedef float f32x4 __attribute__((ext_vector_type(4)));
typedef unsigned short ushort;
typedef unsigned int uint32;

struct HL { ushort h, l; };

// split fp32 into bf16 hi + bf16 lo (both RNE): x ~= hi + lo, err ~2^-17 rel
__device__ inline HL split_bf16(float x) {
    unsigned u = __float_as_uint(x);
    unsigned hr = (u + 0x7FFFu + ((u >> 16) & 1u)) >> 16;
    float fh = __uint_as_float(hr << 16);
    float r = x - fh;
    unsigned v = __float_as_uint(r);
    unsigned lr = (v + 0x7FFFu + ((v >> 16) & 1u)) >> 16;
    HL out; out.h = (ushort)hr; out.l = (ushort)lr;
    return out;
}

// ============ staged-B raw load: 32n x 64k fp32 tile, 8 floats/thread (2 k-halves) ============
// r8: N-MAJOR lane mapping (nl = tid&31, kg = tid>>5) — coalesced staging (measured win).
template<int MODE>
__device__ inline void stage_load(float (&pv)[2][4], const float* __restrict__ Bf,
                                  int kbase, int n0, int tid,
                                  int Ci, int Hin, int Ho, int lgHo, int lgHW) {
    int nl = tid & 31, kg = tid >> 5;
    int n = n0 + nl;
#pragma unroll
    for (int r = 0; r < 2; ++r) {
        if (MODE == 0) {
            int k4 = kbase + (r << 5) + (kg << 2);
            int ic = k4 >> 4, kh = (k4 >> 2) & 3;
            int ow = n & (Ho - 1), oh = (n >> lgHo) & (Ho - 1), b = n >> (lgHo + lgHo);
            int ih = oh * 2 - 1 + kh;
            int ihc = ih < 0 ? 0 : (ih >= Hin ? Hin - 1 : ih);
            int iwb = ow * 2 - 1;
            size_t base = ((size_t)(b * Ci + ic) * Hin + ihc) * Hin;
#pragma unroll
            for (int e = 0; e < 4; ++e) {
                int iw = iwb + e;
                int iwc = iw < 0 ? 0 : (iw >= Hin ? Hin - 1 : iw);
                pv[r][e] = Bf[base + iwc];
            }
        } else {
            int c = kbase + (r << 5) + (kg << 2);
            int b = n >> lgHW, hw = n & ((1 << lgHW) - 1);
            size_t base = (((size_t)(b * Ci + c)) << lgHW) + hw;
            size_t str = (size_t)1 << lgHW;
#pragma unroll
            for (int e = 0; e < 4; ++e) pv[r][e] = Bf[base + e * str];
        }
    }
}

// ================= bf16-split MFMA GEMM with fused BN+LeakyReLU on B-load =================
// Block tile 128M x 32N, 4 waves of 32M x 32N. K-step 64, prefetch distance 2.
// r11: (a) A-fragment loads for BOTH 32-K substeps hoisted to right after the barrier
// (they don't touch LDS) — sub1's ~200-400cy L2 latency hides under sub0's
// ds_read+MFMA instead of sitting exposed before its own MFMAs; (b) s_setprio(1)
// around MFMA clusters — 2 independent blocks/CU give the phase diversity where
// setprio pays (m191); the MFMA-entering wave preempts the other block's staging.
// MODE 0: conv-im2col B; MODE 1: channel-major B; MODE 2: PRE-SPLIT B from global.
// statsBnt != nullptr (KS==1): fused per-channel sum/sumsq atomics, 8-way banked.
// bntBankStride > 0: input bnt is 8-banked; sum banks in prologue.
template<int MODE>
__global__ __launch_bounds__(256, 3) void gemm_mfma(
    const ushort* __restrict__ Ah, const ushort* __restrict__ Al,
    const float* __restrict__ Bf,
    const float* __restrict__ bnt, const float* __restrict__ gamma,
    const float* __restrict__ beta, float invN, int chanShift,
    const float* __restrict__ bias, float* __restrict__ P,
    int Mtiles, int Ntiles, int K, int Kslice, int KS, int outSize,
    int Ci, int Hin, int Co, int Ho, int lgHo,
    int lgHW, int lgHin, int lgCo, int lgk,
    float* __restrict__ statsBnt, const float* __restrict__ bnPart,
    int statsBank, int bntBankStride)
{
    __shared__ __align__(16) uint32 Bsp[32 * 68];   // [n][64k] packed, stride 68
    __shared__ float scs[256], shs[256];

    int bid = blockIdx.x;
    int ntile = bid % Ntiles; bid /= Ntiles;
    int mtile = bid % Mtiles;
    int ks = bid / Mtiles;
    int tid = threadIdx.x;
    int lane = tid & 63, w = tid >> 6;
    int quad = lane >> 4, tl = lane & 15;
    int n0 = ntile << 5, m0 = mtile << 7, k0 = ks * Kslice;
    int Kt = K >> 5;

    bool useBN = (bnt != nullptr) || (bnPart != nullptr);
    int c0 = k0 >> chanShift;
    if (bnPart != nullptr) {
        // BN0 from conv tile-partials: 64 channels x 256 (sum,sq) pairs
        int c = tid >> 2, qq = tid & 3;
        const float2* pp2 = (const float2*)(bnPart + c * 512) + qq * 64;
        float s = 0.f, s2 = 0.f;
#pragma unroll 8
        for (int p = 0; p < 64; ++p) { float2 v = pp2[p]; s += v.x; s2 += v.y; }
        scs[tid] = s; shs[tid] = s2;
        __syncthreads();
        float scale = 0.f, shift = 0.f;
        if (tid < 64) {
            float st = scs[tid * 4] + scs[tid * 4 + 1] + scs[tid * 4 + 2] + scs[tid * 4 + 3];
            float qt = shs[tid * 4] + shs[tid * 4 + 1] + shs[tid * 4 + 2] + shs[tid * 4 + 3];
            float m = st * invN;
            float var = qt * invN - m * m;
            scale = gamma[tid] * rsqrtf(var + 1e-5f);
            shift = beta[tid] - m * scale;
        }
        __syncthreads();
        // store shifted so the transform's scs[ic - c0] indexing works for any K-slice
        if (tid < 64 && tid >= c0) { scs[tid - c0] = scale; shs[tid - c0] = shift; }
    } else if (bnt != nullptr) {
        int nch = Kslice >> chanShift;
        for (int c = tid; c < nch; c += 256) {
            float sm, sq;
            if (bntBankStride > 0) {
                sm = 0.f; sq = 0.f;
#pragma unroll
                for (int bk = 0; bk < 8; ++bk) {
                    sm += bnt[bk * bntBankStride + (c0 + c) * 2];
                    sq += bnt[bk * bntBankStride + (c0 + c) * 2 + 1];
                }
            } else {
                sm = bnt[(c0 + c) * 2];
                sq = bnt[(c0 + c) * 2 + 1];
            }
            float m = sm * invN;
            float var = sq * invN - m * m;
            float scale = gamma[c0 + c] * rsqrtf(var + 1e-5f);
            scs[c] = scale;
            shs[c] = beta[c0 + c] - m * scale;
        }
    }
    __syncthreads();

    f32x4 zero4 = {0.f, 0.f, 0.f, 0.f};
    f32x4 acc[2][2];
#pragma unroll
    for (int mt = 0; mt < 2; ++mt)
#pragma unroll
        for (int nt = 0; nt < 2; ++nt) acc[mt][nt] = zero4;

    if (MODE == 2) {
        // ---- barrier-free K-loop: B pre-split in global (L2-resident) ----
        const ushort* Bu = (const ushort*)Bf;
        for (int kc = 0; kc < Kslice; kc += 32) {
            int kbase = k0 + kc;
            int kt = kbase >> 5;
            bf16x8 afh[2], afl[2];
#pragma unroll
            for (int mt = 0; mt < 2; ++mt) {
                int mtAbs = (m0 >> 4) + (w << 1) + mt;
                size_t abase = (((size_t)mtAbs * Kt + kt) << 6) + lane;
                afh[mt] = *(const bf16x8*)(Ah + abase * 8);
                afl[mt] = *(const bf16x8*)(Al + abase * 8);
            }
            bf16x8 bfh[2], bfl[2];
#pragma unroll
            for (int nt = 0; nt < 2; ++nt) {
                int n = n0 + (nt << 4) + tl;
                size_t ba = (size_t)n * Ci + kbase + (quad << 3);
                bfh[nt] = *(const bf16x8*)(Bu + ba);
                bfl[nt] = *(const bf16x8*)(Bu + Ho + ba);
            }
            __builtin_amdgcn_s_setprio(1);
#pragma unroll
            for (int mt = 0; mt < 2; ++mt)
#pragma unroll
                for (int nt = 0; nt < 2; ++nt) {
                    acc[mt][nt] = __builtin_amdgcn_mfma_f32_16x16x32_bf16(afh[mt], bfh[nt], acc[mt][nt], 0, 0, 0);
                    acc[mt][nt] = __builtin_amdgcn_mfma_f32_16x16x32_bf16(afh[mt], bfl[nt], acc[mt][nt], 0, 0, 0);
                    acc[mt][nt] = __builtin_amdgcn_mfma_f32_16x16x32_bf16(afl[mt], bfh[nt], acc[mt][nt], 0, 0, 0);
                }
            __builtin_amdgcn_s_setprio(0);
        }
    } else {
        // ---- staged K-loop, BK=64, prefetch distance 2 (pvA even steps / pvB odd) ----
        int nsteps = Kslice >> 6;
        float pvA[2][4], pvB[2][4];
        stage_load<MODE>(pvA, Bf, k0, n0, tid, Ci, Hin, Ho, lgHo, lgHW);
        if (nsteps > 1) stage_load<MODE>(pvB, Bf, k0 + 64, n0, tid, Ci, Hin, Ho, lgHo, lgHW);

        auto step = [&](float (&pv)[2][4], int sidx) {
            int kbase = k0 + (sidx << 6);
            // ---- transform both k-halves + regs -> LDS (n-major lane map, r8) ----
            int nl = tid & 31, kg = tid >> 5;
#pragma unroll
            for (int r = 0; r < 2; ++r) {
                int k4 = kbase + (r << 5) + (kg << 2);
                uint32 pk[4];
                if (MODE == 0) {
                    int ic = k4 >> 4, kh = (k4 >> 2) & 3;
                    int n = n0 + nl;
                    int ow = n & (Ho - 1), oh = (n >> lgHo) & (Ho - 1);
                    int ih = oh * 2 - 1 + kh;
                    bool rowok = (unsigned)ih < (unsigned)Hin;
                    int iwb = ow * 2 - 1;
                    float sc_ = useBN ? scs[ic - c0] : 0.f;
                    float sh_ = useBN ? shs[ic - c0] : 0.f;
#pragma unroll
                    for (int e = 0; e < 4; ++e) {
                        int iw = iwb + e;
                        bool ok = rowok && ((unsigned)iw < (unsigned)Hin);
                        float f = pv[r][e];
                        if (useBN) { f = f * sc_ + sh_; f = f >= 0.f ? f : LEAK * f; }
                        if (!ok) f = 0.f;
                        HL s = split_bf16(f);
                        pk[e] = ((uint32)s.h << 16) | s.l;
                    }
                } else {
#pragma unroll
                    for (int e = 0; e < 4; ++e) {
                        float f = pv[r][e];
                        if (useBN) {
                            int lc = k4 + e - k0;
                            f = f * scs[lc] + shs[lc];
                            f = f >= 0.f ? f : LEAK * f;
                        }
                        HL s = split_bf16(f);
                        pk[e] = ((uint32)s.h << 16) | s.l;
                    }
                }
                *(uint4*)&Bsp[nl * 68 + (r << 5) + (kg << 2)] = make_uint4(pk[0], pk[1], pk[2], pk[3]);
            }
            __syncthreads();

            // ---- r11: hoist A fragments for BOTH subs (independent of LDS) ----
            bf16x8 afh[2][2], afl[2][2];
#pragma unroll
            for (int sub = 0; sub < 2; ++sub) {
                int kt = (kbase >> 5) + sub;
#pragma unroll
                for (int mt = 0; mt < 2; ++mt) {
                    int mtAbs = (m0 >> 4) + (w << 1) + mt;
                    size_t abase = (((size_t)mtAbs * Kt + kt) << 6) + lane;
                    afh[sub][mt] = *(const bf16x8*)(Ah + abase * 8);
                    afl[sub][mt] = *(const bf16x8*)(Al + abase * 8);
                }
            }

            // ---- distance-2 prefetch: refill THIS register set for step sidx+2 ----
            if (sidx + 2 < nsteps)
                stage_load<MODE>(pv, Bf, kbase + 128, n0, tid, Ci, Hin, Ho, lgHo, lgHW);

            // ---- two 32-K substeps from LDS ----
#pragma unroll
            for (int sub = 0; sub < 2; ++sub) {
                bf16x8 bfh[2], bfl[2];
#pragma unroll
                for (int nt = 0; nt < 2; ++nt) {
                    int base = ((nt << 4) + tl) * 68 + (sub << 5) + (quad << 3);
                    uint4 ua = *(const uint4*)&Bsp[base];
                    uint4 ub = *(const uint4*)&Bsp[base + 4];
                    union { uint32 u[4]; bf16x8 v; } H, L;
                    H.u[0] = __builtin_amdgcn_perm(ua.y, ua.x, 0x07060302u);
                    H.u[1] = __builtin_amdgcn_perm(ua.w, ua.z, 0x07060302u);
                    H.u[2] = __builtin_amdgcn_perm(ub.y, ub.x, 0x07060302u);
                    H.u[3] = __builtin_amdgcn_perm(ub.w, ub.z, 0x07060302u);
                    L.u[0] = __builtin_amdgcn_perm(ua.y, ua.x, 0x05040100u);
                    L.u[1] = __builtin_amdgcn_perm(ua.w, ua.z, 0x05040100u);
                    L.u[2] = __builtin_amdgcn_perm(ub.y, ub.x, 0x05040100u);
                    L.u[3] = __builtin_amdgcn_perm(ub.w, ub.z, 0x05040100u);
                    bfh[nt] = H.v; bfl[nt] = L.v;
                }
                __builtin_amdgcn_s_setprio(1);
#pragma unroll
                for (int mt = 0; mt < 2; ++mt)
#pragma unroll
                    for (int nt = 0; nt < 2; ++nt) {
                        acc[mt][nt] = __builtin_amdgcn_mfma_f32_16x16x32_bf16(afh[sub][mt], bfh[nt], acc[mt][nt], 0, 0, 0);
                        acc[mt][nt] = __builtin_amdgcn_mfma_f32_16x16x32_bf16(afh[sub][mt], bfl[nt], acc[mt][nt], 0, 0, 0);
                        acc[mt][nt] = __builtin_amdgcn_mfma_f32_16x16x32_bf16(afl[sub][mt], bfh[nt], acc[mt][nt], 0, 0, 0);
                    }
                __builtin_amdgcn_s_setprio(0);
            }
            __syncthreads();
        };

        for (int s = 0; s < nsteps; s += 2) {
            step(pvA, s);
            if (s + 1 < nsteps) step(pvB, s + 1);
        }
    }

    // ---- epilogue: D[m = quad*4+reg][n = tl] + optional fused stats (KS==1 paths) ----
    bool doStats = (statsBnt != nullptr);
    if (doStats) {
        if (tid < 2 * Co) scs[tid] = 0.f;
        __syncthreads();
    }
    float ssum[2][4] = {{0.f,0.f,0.f,0.f},{0.f,0.f,0.f,0.f}};
    float ssq [2][4] = {{0.f,0.f,0.f,0.f},{0.f,0.f,0.f,0.f}};
    float* dst = P + (size_t)ks * outSize;
    if (MODE == 0) {
#pragma unroll
        for (int nt = 0; nt < 2; ++nt) {
            int n = n0 + (nt << 4) + tl;
            int ow = n & (Ho - 1), oh = (n >> lgHo) & (Ho - 1), b = n >> (lgHo + lgHo);
#pragma unroll
            for (int mt = 0; mt < 2; ++mt) {
                int mb = m0 + (w << 5) + (mt << 4) + (quad << 2);
#pragma unroll
                for (int r = 0; r < 4; ++r) {
                    int oc = mb + r;
                    float v = acc[mt][nt][r];
                    if (KS == 1) v += bias[oc];
                    if (doStats) { ssum[mt][r] += v; ssq[mt][r] += v * v; }
                    dst[((size_t)(b * Co + oc) * Ho + oh) * Ho + ow] = v;
                }
            }
        }
    } else {
        int kf = 1 << lgk;
        int Ho2 = Hin << lgk;
#pragma unroll
        for (int nt = 0; nt < 2; ++nt) {
            int n = n0 + (nt << 4) + tl;
            int b = n >> lgHW, hw = n & ((1 << lgHW) - 1);
            int h = hw >> lgHin, wp = hw & (Hin - 1);
#pragma unroll
            for (int mt = 0; mt < 2; ++mt) {
                int mb = m0 + (w << 5) + (mt << 4) + (quad << 2);
#pragma unroll
                for (int r = 0; r < 4; ++r) {
                    int m = mb + r;
                    int o = m & (Co - 1), ij = m >> lgCo;
                    int ii = ij >> lgk, jj = ij & (kf - 1);
                    float v = acc[mt][nt][r];
                    if (KS == 1) v += bias[o];
                    if (doStats) { ssum[mt][r] += v; ssq[mt][r] += v * v; }
                    dst[((size_t)(b * Co + o) * Ho2 + (h << lgk) + ii) * Ho2 + (wp << lgk) + jj] = v;
                }
            }
        }
    }
    if (doStats) {
        // reduce over the 16 lanes (tl) sharing identical channels
#pragma unroll
        for (int mt = 0; mt < 2; ++mt)
#pragma unroll
            for (int r = 0; r < 4; ++r) {
                float s = ssum[mt][r], q2 = ssq[mt][r];
#pragma unroll
                for (int m2 = 1; m2 < 16; m2 <<= 1) {
                    s  += __shfl_xor(s,  m2);
                    q2 += __shfl_xor(q2, m2);
                }
                if (tl == 0) {
                    int m = m0 + (w << 5) + (mt << 4) + (quad << 2) + r;
                    int o = (MODE == 0) ? m : (m & (Co - 1));
                    atomicAdd(&scs[o * 2],     s);
                    atomicAdd(&scs[o * 2 + 1], q2);
                }
            }
        __syncthreads();
        float* sb = statsBnt + (blockIdx.x & 7) * statsBank;
        if (tid < 2 * Co) atomicAdd(&sb[tid], scs[tid]);
    }
}

// ================= weight prep address =================
__device__ inline int fragaddr(int m, int k, int K) {
    return ((((m >> 4) * (K >> 5) + (k >> 5)) << 9) | (((k >> 3) & 3) << 7) | ((m & 15) << 3) | (k & 7));
}

#define OUT_CL   786432
#define OUT_CB   786433
#define OUT_IDX  786434
#define OUT_MIND 787458

// ================= enc0 direct conv (Ci=3) with non-atomic per-tile BN stat partials =================
__device__ void conv_body(int bid, int tid,
                          const float* __restrict__ x, const float* __restrict__ w,
                          const float* __restrict__ bias, float* __restrict__ P,
                          float* __restrict__ pst, float (&cst)[4][16])
{
    const int Ci = 3, Hin = 128, Co = 64, Ho = 64, OCT = 8;
    int ntile = (16 * Ho * Ho) >> 8;          // 256
    int tile = bid % ntile;
    int og = bid / ntile;
    int oc0 = og * OCT;

    int px = (tile << 8) + tid;
    int ow = px % Ho; int t = px / Ho;
    int oh = t % Ho;  int b = t / Ho;

    int off[16]; float fm[16];
    int ih0 = oh * 2 - 1, iw0 = ow * 2 - 1;
#pragma unroll
    for (int kh = 0; kh < 4; ++kh)
#pragma unroll
        for (int kw = 0; kw < 4; ++kw) {
            int ih = ih0 + kh, iw = iw0 + kw;
            bool ok = (ih >= 0) && (ih < Hin) && (iw >= 0) && (iw < Hin);
            int ihc = ih < 0 ? 0 : (ih >= Hin ? Hin - 1 : ih);
            int iwc = iw < 0 ? 0 : (iw >= Hin ? Hin - 1 : iw);
            off[kh * 4 + kw] = ihc * Hin + iwc;
            fm[kh * 4 + kw] = ok ? 1.f : 0.f;
        }

    float acc[OCT];
#pragma unroll
    for (int u = 0; u < OCT; ++u) acc[u] = bias[oc0 + u];

    const float* xc = x + (size_t)b * Ci * Hin * Hin;
    const float* wi = w + (size_t)oc0 * Ci * 16;
    int HinHin = Hin * Hin;
    for (int ic = 0; ic < Ci; ++ic) {
        float xv[16];
#pragma unroll
        for (int q = 0; q < 16; ++q) xv[q] = xc[off[q]] * fm[q];
#pragma unroll
        for (int u = 0; u < OCT; ++u) {
            const float* wo = wi + (size_t)u * Ci * 16;
            float a = acc[u];
#pragma unroll
            for (int q = 0; q < 16; ++q) a += xv[q] * wo[q];
            acc[u] = a;
        }
        xc += HinHin;
        wi += 16;
    }
    size_t obase = (((size_t)b * Co + oc0) * Ho + oh) * Ho + ow;
    size_t opl = (size_t)Ho * Ho;
#pragma unroll
    for (int u = 0; u < OCT; ++u) P[obase + u * opl] = acc[u];

    // ---- BN stat partials: butterfly over 64 lanes, combine 4 waves, plain store ----
    float sv[OCT], qv[OCT];
#pragma unroll
    for (int u = 0; u < OCT; ++u) { sv[u] = acc[u]; qv[u] = acc[u] * acc[u]; }
#pragma unroll
    for (int m2 = 1; m2 < 64; m2 <<= 1)
#pragma unroll
        for (int u = 0; u < OCT; ++u) {
            sv[u] += __shfl_xor(sv[u], m2);
            qv[u] += __shfl_xor(qv[u], m2);
        }
    int lane = tid & 63, wv = tid >> 6;
    if (lane == 0) {
#pragma unroll
        for (int u = 0; u < OCT; ++u) { cst[wv][u * 2] = sv[u]; cst[wv][u * 2 + 1] = qv[u]; }
    }
    __syncthreads();
    if (tid < 2 * OCT) {
        float v = cst[0][tid] + cst[1][tid] + cst[2][tid] + cst[3][tid];
        pst[(oc0 + (tid >> 1)) * 512 + tile * 2 + (tid & 1)] = v;
    }
}

// ================= fused prologue: zero BNT/losses + cbT + weight prep + enc0 conv =================
__global__ void prologue(const float* __restrict__ w1, const float* __restrict__ w2,
                         const float* __restrict__ w3, const float* __restrict__ d0,
                         const float* __restrict__ d1, const float* __restrict__ d2,
                         ushort* __restrict__ WH, ushort* __restrict__ WL,
                         const float* __restrict__ cb, float* __restrict__ cbT,
                         float* __restrict__ bnt, float* __restrict__ dout,
                         const float* __restrict__ x, const float* __restrict__ w0,
                         const float* __restrict__ b0, float* __restrict__ Y0,
                         float* __restrict__ pst) {
    __shared__ float cst[4][16];
    int blk = blockIdx.x;
    int tid = threadIdx.x;
    if (blk < 24) {                          // zero BN totals + loss accumulators
        bnt[blk * 256 + tid] = 0.f;
        if (blk == 0 && tid < 2) dout[OUT_CL + tid] = 0.f;
        return;
    }
    if (blk < 536) {                         // codebook transpose
        int idx = (blk - 24) * 256 + tid;
        int k = idx & 511, c = idx >> 9;
        cbT[idx] = cb[k * 256 + c];
        return;
    }
    if (blk >= 9400) {                       // enc0 direct conv (2048 blocks)
        conv_body(blk - 9400, tid, x, w0, b0, Y0, pst, cst);
        return;
    }
    int idx = (blk - 536) * 256 + tid;       // weight split+reorder
    if (idx >= 2269184) return;
    float v; int dst;
    if (idx < 131072) {                      // enc1: M=128 K=1024
        int m = idx >> 10, k = idx & 1023;
        v = w1[idx];
        dst = fragaddr(m, k, 1024);
    } else if (idx < 655360) {               // enc2: M=256 K=2048
        int i = idx - 131072;
        int m = i >> 11, k = i & 2047;
        v = w2[i];
        dst = 131072 + fragaddr(m, k, 2048);
    } else if (idx < 1703936) {              // enc3: M=256 K=4096
        int i = idx - 655360;
        int m = i >> 12, k = i & 4095;
        v = w3[i];
        dst = 655360 + fragaddr(m, k, 4096);
    } else if (idx < 2228224) {              // dec0: M=2048 K=256
        int i = idx - 1703936;
        int m = i >> 8, c = i & 255;
        int o = m & 127, ij = m >> 7;
        v = d0[((size_t)c * 128 + o) * 16 + ij];
        dst = 1703936 + fragaddr(m, c, 256);
    } else if (idx < 2260992) {              // dec1: M=256 K=128
        int i = idx - 2228224;
        int m = i >> 7, c = i & 127;
        int o = m & 63, ij = m >> 6;
        v = d1[((size_t)c * 64 + o) * 4 + ij];
        dst = 2228224 + fragaddr(m, c, 128);
    } else {                                 // dec2: M=128 K=64
        int i = idx - 2260992;
        int m = i >> 6, c = i & 63;
        int o = m & 31, ij = m >> 5;
        v = d2[((size_t)c * 32 + o) * 4 + ij];
        dst = 2260992 + fragaddr(m, c, 64);
    }
    HL s = split_bf16(v);
    WH[dst] = s.h; WL[dst] = s.l;
}

// ================= reduce partials + BN stats (enc2 only) =================
__global__ void reduce_bias_stats4(const float4* __restrict__ P, const float* __restrict__ bias,
                                   float4* __restrict__ y, float* __restrict__ bnt,
                                   int outSize4, int KS, int Co, int HW4, int nch) {
    int tid = threadIdx.x;
    int i = blockIdx.x * 256 + tid;
    int c = (i / HW4) % Co;
    float bv = bias[c];
    float4 s = make_float4(bv, bv, bv, bv);
    for (int ks = 0; ks < KS; ++ks) {
        float4 p = P[(size_t)ks * outSize4 + i];
        s.x += p.x; s.y += p.y; s.z += p.z; s.w += p.w;
    }
    y[i] = s;
    float ls  = s.x + s.y + s.z + s.w;
    float ls2 = s.x * s.x + s.y * s.y + s.z * s.z + s.w * s.w;
    __shared__ float as[16], aq[16];
    if (tid < 16) { as[tid] = 0.f; aq[tid] = 0.f; }
    __syncthreads();
    int c0 = ((blockIdx.x * 256) / HW4) % Co;
    atomicAdd(&as[c - c0], ls);
    atomicAdd(&aq[c - c0], ls2);
    __syncthreads();
    if (tid < nch) {
        atomicAdd(&bnt[(c0 + tid) * 2],     as[tid]);
        atomicAdd(&bnt[(c0 + tid) * 2 + 1], aq[tid]);
    }
}

// ================= Vector quantizer: sums 16 enc3 partial slices on load; writes
// pre-split QH/QL bf16 [n][k] row-major for dec0 MODE2; fused loss =================
__global__ void vq_main(const float* __restrict__ Pz, const float* __restrict__ b3,
                        const float* __restrict__ cbT, const float* __restrict__ cb,
                        ushort* __restrict__ qhl, float* __restrict__ dout) {
    int r0 = blockIdx.x * 4;
    int tid = threadIdx.x;
    int lane = tid & 63, w = tid >> 6;

    __shared__ __align__(16) float zT[256][4];
    __shared__ float wred[4][4];
    __shared__ float zn2s[4];
    __shared__ float wbd[4][4];
    __shared__ int   wbi[4][4];
    __shared__ int   bestsh[4];
    __shared__ float bestd[4];

    int b = r0 >> 6, s0 = r0 & 63;
    size_t zi = ((size_t)(b * 256 + tid)) * 64 + s0;
    float bv = b3[tid];
    float4 zv = make_float4(bv, bv, bv, bv);
    const float4* pp = (const float4*)Pz + (zi >> 2);
#pragma unroll
    for (int ks = 0; ks < 16; ++ks) {
        float4 p = pp[(size_t)ks * 65536];
        zv.x += p.x; zv.y += p.y; zv.z += p.z; zv.w += p.w;
    }
    *(float4*)&zT[tid][0] = zv;

    // ---- per-row |z|^2 via butterfly sum over channels ----
    float p0 = zv.x * zv.x, p1 = zv.y * zv.y, p2 = zv.z * zv.z, p3 = zv.w * zv.w;
#pragma unroll
    for (int m2 = 1; m2 < 64; m2 <<= 1) {
        p0 += __shfl_xor(p0, m2); p1 += __shfl_xor(p1, m2);
        p2 += __shfl_xor(p2, m2); p3 += __shfl_xor(p3, m2);
    }
    if (lane == 0) { wred[w][0] = p0; wred[w][1] = p1; wred[w][2] = p2; wred[w][3] = p3; }
    __syncthreads();
    if (tid < 4) zn2s[tid] = wred[0][tid] + wred[1][tid] + wred[2][tid] + wred[3][tid];
    __syncthreads();

    // ---- dot products: thread owns codebook entries k=tid and k=tid+256 ----
    float d0[4], d1[4];
#pragma unroll
    for (int rr = 0; rr < 4; ++rr) { d0[rr] = 0.f; d1[rr] = 0.f; }
    float cn0 = 0.f, cn1 = 0.f;
#pragma unroll 4
    for (int c = 0; c < 256; ++c) {
        float cv0 = cbT[c * 512 + tid];
        float cv1 = cbT[c * 512 + 256 + tid];
        cn0 += cv0 * cv0;
        cn1 += cv1 * cv1;
        float4 za = *(const float4*)&zT[c][0];
        d0[0] += za.x * cv0; d1[0] += za.x * cv1;
        d0[1] += za.y * cv0; d1[1] += za.y * cv1;
        d0[2] += za.z * cv0; d1[2] += za.z * cv1;
        d0[3] += za.w * cv0; d1[3] += za.w * cv1;
    }

    // ---- argmin via butterfly (tie-break: smaller index) ----
#pragma unroll
    for (int rr = 0; rr < 4; ++rr) {
        float dist0 = zn2s[rr] - 2.f * d0[rr] + cn0;
        float dist1 = zn2s[rr] - 2.f * d1[rr] + cn1;
        float bd = dist0; int bi = tid;
        if (dist1 < bd) { bd = dist1; bi = tid + 256; }
#pragma unroll
        for (int m2 = 1; m2 < 64; m2 <<= 1) {
            float od = __shfl_xor(bd, m2); int oi = __shfl_xor(bi, m2);
            if (od < bd || (od == bd && oi < bi)) { bd = od; bi = oi; }
        }
        if (lane == 0) { wbd[w][rr] = bd; wbi[w][rr] = bi; }
    }
    __syncthreads();
    if (tid < 4) {
        float bd = wbd[0][tid]; int bi = wbi[0][tid];
#pragma unroll
        for (int ww = 1; ww < 4; ++ww) {
            float od = wbd[ww][tid]; int oi = wbi[ww][tid];
            if (od < bd || (od == bd && oi < bi)) { bd = od; bi = oi; }
        }
        bestsh[tid] = bi; bestd[tid] = bd;
        dout[OUT_IDX + r0 + tid]  = (float)bi;
        dout[OUT_MIND + r0 + tid] = bd;
    }
    __syncthreads();

    // ---- gather quantized rows, split to bf16 hi/lo, store [n][k] (n = r0+rr) ----
#pragma unroll
    for (int rr = 0; rr < 4; ++rr) {
        float v = cb[(size_t)bestsh[rr] * 256 + tid];
        HL s = split_bf16(v);
        size_t o = (size_t)(r0 + rr) * 256 + tid;
        qhl[o]          = s.h;
        qhl[262144 + o] = s.l;
    }
    if (tid == 0) {
        float ls = (bestd[0] + bestd[1] + bestd[2] + bestd[3]) * (1.f / 262144.f);
        atomicAdd(&dout[OUT_CL], ls);
        atomicAdd(&dout[OUT_CB], ls);
    }
}

// ================= Final: BN(D2, 8-banked stats) + LeakyReLU + 1x1 conv + tanh =================
__global__ void final_conv_tanh(const float* __restrict__ hbuf, const float* __restrict__ bnt,
                                const float* __restrict__ g, const float* __restrict__ bt,
                                const float* __restrict__ w3, const float* __restrict__ b3,
                                float* __restrict__ out) {
    __shared__ float sc[32], sh[32], sw[96];
    int tid = threadIdx.x;
    if (tid < 32) {
        float sm = 0.f, sq = 0.f;
#pragma unroll
        for (int bk = 0; bk < 8; ++bk) {
            sm += bnt[bk * 64 + tid * 2];
            sq += bnt[bk * 64 + tid * 2 + 1];
        }
        float m = sm * (1.f / 262144.f);
        float var = sq * (1.f / 262144.f) - m * m;
        float scale = g[tid] * rsqrtf(var + 1e-5f);
        sc[tid] = scale;
        sh[tid] = bt[tid] - m * scale;
    }
    if (tid < 96) sw[tid] = w3[tid];
    __syncthreads();
    int idx = blockIdx.x * 256 + tid;          // 65536 = 16 * 4096 float4 pixels
    int hw4 = idx & 4095;
    int b   = idx >> 12;
    const float4* hp = (const float4*)hbuf + ((size_t)b * 32) * 4096 + hw4;
    float b0 = b3[0], b1 = b3[1], b2 = b3[2];
    float4 a0 = make_float4(b0, b0, b0, b0);
    float4 a1 = make_float4(b1, b1, b1, b1);
    float4 a2 = make_float4(b2, b2, b2, b2);
#pragma unroll 8
    for (int c = 0; c < 32; ++c) {
        float4 v = hp[(size_t)c * 4096];
        float scv = sc[c], shv = sh[c];
        float vx = v.x * scv + shv; vx = vx >= 0.f ? vx : LEAK * vx;
        float vy = v.y * scv + shv; vy = vy >= 0.f ? vy : LEAK * vy;
        float vz = v.z * scv + shv; vz = vz >= 0.f ? vz : LEAK * vz;
        float vw = v.w * scv + shv; vw = vw >= 0.f ? vw : LEAK * vw;
        float w0 = sw[c], w1 = sw[32 + c], w2 = sw[64 + c];
        a0.x += vx * w0; a0.y += vy * w0; a0.z += vz * w0; a0.w += vw * w0;
        a1.x += vx * w1; a1.y += vy * w1; a1.z += vz * w1; a1.w += vw * w1;
        a2.x += vx * w2; a2.y += vy * w2; a2.z += vz * w2; a2.w += vw * w2;
    }
    float4* op = (float4*)out;
    size_t ob = ((size_t)b * 3) * 4096 + hw4;
    op[ob]            = make_float4(tanhf(a0.x), tanhf(a0.y), tanhf(a0.z), tanhf(a0.w));
    op[ob + 4096]     = make_float4(tanhf(a1.x), tanhf(a1.y), tanhf(a1.z), tanhf(a1.w));
    op[ob + 2 * 4096] = make_float4(tanhf(a2.x), tanhf(a2.y), tanhf(a2.z), tanhf(a2.w));
}

extern "C" void kernel_launch(void* const* d_in, const int* in_sizes, int n_in,
                              void* d_out, int out_size, void* d_ws, size_t ws_size,
                              hipStream_t stream) {
    const float* x      = (const float*)d_in[0];
    const float* enc_w0 = (const float*)d_in[1];
    const float* enc_b0 = (const float*)d_in[2];
    const float* enc_w1 = (const float*)d_in[3];
    const float* enc_b1 = (const float*)d_in[4];
    const float* enc_w2 = (const float*)d_in[5];
    const float* enc_b2 = (const float*)d_in[6];
    const float* enc_w3 = (const float*)d_in[7];
    const float* enc_b3 = (const float*)d_in[8];
    const float* ebn_g0 = (const float*)d_in[9];
    const float* ebn_b0 = (const float*)d_in[10];
    const float* ebn_g1 = (const float*)d_in[11];
    const float* ebn_b1 = (const float*)d_in[12];
    const float* ebn_g2 = (const float*)d_in[13];
    const float* ebn_b2 = (const float*)d_in[14];
    const float* cb     = (const float*)d_in[15];
    const float* dec_w0 = (const float*)d_in[16];
    const float* dec_b0 = (const float*)d_in[17];
    const float* dbn_g0 = (const float*)d_in[18];
    const float* dbn_b0 = (const float*)d_in[19];
    const float* dec_w1 = (const float*)d_in[20];
    const float* dec_b1 = (const float*)d_in[21];
    const float* dbn_g1 = (const float*)d_in[22];
    const float* dbn_b1 = (const float*)d_in[23];
    const float* dec_w2 = (const float*)d_in[24];
    const float* dec_b2 = (const float*)d_in[25];
    const float* dbn_g2 = (const float*)d_in[26];
    const float* dbn_b2 = (const float*)d_in[27];
    const float* dec_w3 = (const float*)d_in[28];
    const float* dec_b3 = (const float*)d_in[29];

    float* out = (float*)d_out;
    float* ws  = (float*)d_ws;

    // ---- workspace (float units) ----
    float*  Y0   = ws;                               // 4194304
    float*  Y1   = ws + 4194304;                     // 2097152
    float*  Y2   = ws + 6291456;                     // 1048576
    float*  PST  = ws + 7340032;                     // 32768 (conv BN0 partials)
    float*  QHL  = ws + 7602176;                     // 262144 fl = 524288 us (QH | QL)
    ushort* WH   = (ushort*)(ws + 7864320);          // 2269184 us
    ushort* WL   = (ushort*)(ws + 8998912);          // 2269184 us
    float*  CBT  = ws + 10133504;                    // 131072
    float*  BNT  = ws + 10264576;                    // 6144: enc1 8x256 @0 | enc2 512 @2048
                                                     //   | dec0 8x256 @2560 | dec1 8x128 @4608
                                                     //   | dec2 8x64 @5632
    float*  PART = ws + 10270720;                    // 8388608
    float*  D0   = ws + 18659328;                    // 2097152
    float*  D1   = ws + 20756480;                    // 4194304
    float*  D2   = ws + 24950784;                    // 8388608

    dim3 blk(256);

    // ---- prologue: zero BNT/losses + cbT + weight prep + enc0 conv (fused, independent) ----
    prologue<<<11448, blk, 0, stream>>>(enc_w1, enc_w2, enc_w3, dec_w0, dec_w1, dec_w2,
                                        WH, WL, cb, CBT, BNT, out,
                                        x, enc_w0, enc_b0, Y0, PST);

    // enc1: M=128 N=16384 K=1024, Mtiles=1 x Ntiles=512, KS=1 -> 512 blocks
    //       (no transform replication); direct Y1 + bias + 8-banked fused stats @BNT+0
    gemm_mfma<0><<<512, blk, 0, stream>>>(WH, WL, Y0,
        nullptr, ebn_g0, ebn_b0, 1.f / 65536.f, 4, enc_b1, Y1,
        1, 512, 1024, 1024, 1, 0, 64, 64, 128, 32, 5, 0, 0, 0, 0, BNT, PST, 256, 0);

    // enc2: M=256 N=4096 K=2048, KS=4, 32N tiles -> 1024 blocks; BN1 from 8 banks @BNT+0
    gemm_mfma<0><<<1024, blk, 0, stream>>>(WH + 131072, WL + 131072, Y1,
        BNT, ebn_g1, ebn_b1, 1.f / 16384.f, 4, enc_b2, PART,
        2, 128, 2048, 512, 4, 1048576, 128, 32, 256, 16, 4, 0, 0, 0, 0, nullptr, nullptr, 0, 256);
    reduce_bias_stats4<<<1024, blk, 0, stream>>>((const float4*)PART, enc_b2, (float4*)Y2,
                                                 BNT + 2048, 262144, 4, 256, 64, 4);

    // enc3: M=256 N=1024 K=4096, KS=16, 32N tiles -> 1024 blocks; partials -> VQ
    gemm_mfma<0><<<1024, blk, 0, stream>>>(WH + 655360, WL + 655360, Y2,
        BNT + 2048, ebn_g2, ebn_b2, 1.f / 4096.f, 4, enc_b3, PART,
        2, 32, 4096, 256, 16, 262144, 256, 16, 256, 8, 3, 0, 0, 0, 0, nullptr, nullptr, 0, 0);

    // ---- VQ: sums 16 partial slices + bias; emits pre-split QH/QL; fused loss ----
    vq_main<<<256, blk, 0, stream>>>(PART, enc_b3, CBT, cb, (ushort*)QHL, out);

    // ---- decoder ----
    // dec0: M=2048 N=1024 K=256, Mtiles=16 x Ntiles=32, KS=1 -> 512 blocks; MODE2
    //       (transform-free); direct D0 + bias + 8-banked fused stats @BNT+2560
    gemm_mfma<2><<<512, blk, 0, stream>>>(WH + 1703936, WL + 1703936, QHL,
        nullptr, nullptr, nullptr, 0.f, 0, dec_b0, D0,
        16, 32, 256, 256, 1, 0, 256, 8, 128, 262144, 0, 6, 3, 7, 2, BNT + 2560, nullptr, 256, 0);

    // dec1: M=256 N=16384 K=128, KS=1, 32N tiles -> 1024 blocks; BN3 from banks @BNT+2560;
    //       direct D1 + 8-banked stats @BNT+4608
    gemm_mfma<1><<<1024, blk, 0, stream>>>(WH + 2228224, WL + 2228224, D0,
        BNT + 2560, dbn_g0, dbn_b0, 1.f / 16384.f, 0, dec_b1, D1,
        2, 512, 128, 128, 1, 0, 128, 32, 64, 0, 0, 10, 5, 6, 1, BNT + 4608, nullptr, 128, 256);

    // dec2: M=128 N=65536 K=64, KS=1, 32N tiles -> 2048 blocks; BN4 from banks @BNT+4608;
    //       direct D2 + 8-banked stats @BNT+5632
    gemm_mfma<1><<<2048, blk, 0, stream>>>(WH + 2260992, WL + 2260992, D1,
        BNT + 4608, dbn_g1, dbn_b1, 1.f / 65536.f, 0, dec_b2, D2,
        1, 2048, 64, 64, 1, 0, 64, 64, 32, 0, 0, 12, 6, 5, 1, BNT + 5632, nullptr, 64, 128);

    // final: BN5 (8 banks @BNT+5632) + leaky + 1x1 conv + tanh (float4)
    final_conv_tanh<<<256, blk, 0, stream>>>(D2, BNT + 5632, dbn_g2, dbn_b2, dec_w3, dec_b3, out);
}

// Round 12
// 351.866 us; speedup vs baseline: 1.1206x; 1.0024x over previous
//
#include <hip/hip_runtime.h>
#include <math.h>

#define LEAK 0.01f

typedef __bf16 bf16x8 __attribute__((ext_vector_type(8)));
typedef float f32x4 __attribute__((ext_vector_type(4)));
typedef unsigned short ushort;
typedef unsigned int uint32;

struct HL { ushort h, l; };

// split fp32 into bf16 hi + bf16 lo (both RNE): x ~= hi + lo, err ~2^-17 rel
__device__ inline HL split_bf16(float x) {
    unsigned u = __float_as_uint(x);
    unsigned hr = (u + 0x7FFFu + ((u >> 16) & 1u)) >> 16;
    float fh = __uint_as_float(hr << 16);
    float r = x - fh;
    unsigned v = __float_as_uint(r);
    unsigned lr = (v + 0x7FFFu + ((v >> 16) & 1u)) >> 16;
    HL out; out.h = (ushort)hr; out.l = (ushort)lr;
    return out;
}

// ============ staged-B raw load: 32n x 64k fp32 tile, 8 floats/thread (2 k-halves) ============
// r8: N-MAJOR lane mapping (nl = tid&31, kg = tid>>5) — coalesced staging (measured win).
template<int MODE>
__device__ inline void stage_load(float (&pv)[2][4], const float* __restrict__ Bf,
                                  int kbase, int n0, int tid,
                                  int Ci, int Hin, int Ho, int lgHo, int lgHW) {
    int nl = tid & 31, kg = tid >> 5;
    int n = n0 + nl;
#pragma unroll
    for (int r = 0; r < 2; ++r) {
        if (MODE == 0) {
            int k4 = kbase + (r << 5) + (kg << 2);
            int ic = k4 >> 4, kh = (k4 >> 2) & 3;
            int ow = n & (Ho - 1), oh = (n >> lgHo) & (Ho - 1), b = n >> (lgHo + lgHo);
            int ih = oh * 2 - 1 + kh;
            int ihc = ih < 0 ? 0 : (ih >= Hin ? Hin - 1 : ih);
            int iwb = ow * 2 - 1;
            size_t base = ((size_t)(b * Ci + ic) * Hin + ihc) * Hin;
#pragma unroll
            for (int e = 0; e < 4; ++e) {
                int iw = iwb + e;
                int iwc = iw < 0 ? 0 : (iw >= Hin ? Hin - 1 : iw);
                pv[r][e] = Bf[base + iwc];
            }
        } else {
            int c = kbase + (r << 5) + (kg << 2);
            int b = n >> lgHW, hw = n & ((1 << lgHW) - 1);
            size_t base = (((size_t)(b * Ci + c)) << lgHW) + hw;
            size_t str = (size_t)1 << lgHW;
#pragma unroll
            for (int e = 0; e < 4; ++e) pv[r][e] = Bf[base + e * str];
        }
    }
}

// ================= bf16-split MFMA GEMM with fused BN+LeakyReLU on B-load =================
// Block tile (128*MT)M x 32N, 4 waves of (32*MT)M x 32N. K-step 64, prefetch dist 2.
// r12: MT=2 for the M=256 GEMMs (enc2/enc3/dec1) — Mtiles=2 had every B tile staged+
// transformed TWICE since round 0 (the r2 sin at x2). MT=2 computes both M-halves from
// ONE staged B tile: total transform work halves, MFMA total unchanged, B re-fetch
// halves. MT=1 keeps r11's both-subs A-hoist; MT=2 loads A per-sub (VGPR cap, L2
// latency still overlaps the ds_read+perm that follows).
// MODE 0: conv-im2col B; MODE 1: channel-major B; MODE 2: PRE-SPLIT B from global.
// statsBnt != nullptr (KS==1): fused per-channel sum/sumsq atomics, 8-way banked.
// bntBankStride > 0: input bnt is 8-banked; sum banks in prologue.
template<int MODE, int MT>
__global__ __launch_bounds__(256, 3) void gemm_mfma(
    const ushort* __restrict__ Ah, const ushort* __restrict__ Al,
    const float* __restrict__ Bf,
    const float* __restrict__ bnt, const float* __restrict__ gamma,
    const float* __restrict__ beta, float invN, int chanShift,
    const float* __restrict__ bias, float* __restrict__ P,
    int Mtiles, int Ntiles, int K, int Kslice, int KS, int outSize,
    int Ci, int Hin, int Co, int Ho, int lgHo,
    int lgHW, int lgHin, int lgCo, int lgk,
    float* __restrict__ statsBnt, const float* __restrict__ bnPart,
    int statsBank, int bntBankStride)
{
    __shared__ __align__(16) uint32 Bsp[32 * 68];   // [n][64k] packed, stride 68
    __shared__ float scs[256], shs[256];

    int bid = blockIdx.x;
    int ntile = bid % Ntiles; bid /= Ntiles;
    int mtile = bid % Mtiles;
    int ks = bid / Mtiles;
    int tid = threadIdx.x;
    int lane = tid & 63, w = tid >> 6;
    int quad = lane >> 4, tl = lane & 15;
    int n0 = ntile << 5, m0 = mtile * (128 * MT), k0 = ks * Kslice;
    int Kt = K >> 5;

    bool useBN = (bnt != nullptr) || (bnPart != nullptr);
    int c0 = k0 >> chanShift;
    if (bnPart != nullptr) {
        // BN0 from conv tile-partials: 64 channels x 256 (sum,sq) pairs
        int c = tid >> 2, qq = tid & 3;
        const float2* pp2 = (const float2*)(bnPart + c * 512) + qq * 64;
        float s = 0.f, s2 = 0.f;
#pragma unroll 8
        for (int p = 0; p < 64; ++p) { float2 v = pp2[p]; s += v.x; s2 += v.y; }
        scs[tid] = s; shs[tid] = s2;
        __syncthreads();
        float scale = 0.f, shift = 0.f;
        if (tid < 64) {
            float st = scs[tid * 4] + scs[tid * 4 + 1] + scs[tid * 4 + 2] + scs[tid * 4 + 3];
            float qt = shs[tid * 4] + shs[tid * 4 + 1] + shs[tid * 4 + 2] + shs[tid * 4 + 3];
            float m = st * invN;
            float var = qt * invN - m * m;
            scale = gamma[tid] * rsqrtf(var + 1e-5f);
            shift = beta[tid] - m * scale;
        }
        __syncthreads();
        // store shifted so the transform's scs[ic - c0] indexing works for any K-slice
        if (tid < 64 && tid >= c0) { scs[tid - c0] = scale; shs[tid - c0] = shift; }
    } else if (bnt != nullptr) {
        int nch = Kslice >> chanShift;
        for (int c = tid; c < nch; c += 256) {
            float sm, sq;
            if (bntBankStride > 0) {
                sm = 0.f; sq = 0.f;
#pragma unroll
                for (int bk = 0; bk < 8; ++bk) {
                    sm += bnt[bk * bntBankStride + (c0 + c) * 2];
                    sq += bnt[bk * bntBankStride + (c0 + c) * 2 + 1];
                }
            } else {
                sm = bnt[(c0 + c) * 2];
                sq = bnt[(c0 + c) * 2 + 1];
            }
            float m = sm * invN;
            float var = sq * invN - m * m;
            float scale = gamma[c0 + c] * rsqrtf(var + 1e-5f);
            scs[c] = scale;
            shs[c] = beta[c0 + c] - m * scale;
        }
    }
    __syncthreads();

    f32x4 zero4 = {0.f, 0.f, 0.f, 0.f};
    f32x4 acc[2 * MT][2];
#pragma unroll
    for (int mt = 0; mt < 2 * MT; ++mt)
#pragma unroll
        for (int nt = 0; nt < 2; ++nt) acc[mt][nt] = zero4;

    if (MODE == 2) {
        // ---- barrier-free K-loop: B pre-split in global (L2-resident) ----
        const ushort* Bu = (const ushort*)Bf;
        for (int kc = 0; kc < Kslice; kc += 32) {
            int kbase = k0 + kc;
            int kt = kbase >> 5;
            bf16x8 afh[2 * MT], afl[2 * MT];
#pragma unroll
            for (int mt = 0; mt < 2 * MT; ++mt) {
                int mtAbs = (m0 >> 4) + w * (2 * MT) + mt;
                size_t abase = (((size_t)mtAbs * Kt + kt) << 6) + lane;
                afh[mt] = *(const bf16x8*)(Ah + abase * 8);
                afl[mt] = *(const bf16x8*)(Al + abase * 8);
            }
            bf16x8 bfh[2], bfl[2];
#pragma unroll
            for (int nt = 0; nt < 2; ++nt) {
                int n = n0 + (nt << 4) + tl;
                size_t ba = (size_t)n * Ci + kbase + (quad << 3);
                bfh[nt] = *(const bf16x8*)(Bu + ba);
                bfl[nt] = *(const bf16x8*)(Bu + Ho + ba);
            }
            __builtin_amdgcn_s_setprio(1);
#pragma unroll
            for (int mt = 0; mt < 2 * MT; ++mt)
#pragma unroll
                for (int nt = 0; nt < 2; ++nt) {
                    acc[mt][nt] = __builtin_amdgcn_mfma_f32_16x16x32_bf16(afh[mt], bfh[nt], acc[mt][nt], 0, 0, 0);
                    acc[mt][nt] = __builtin_amdgcn_mfma_f32_16x16x32_bf16(afh[mt], bfl[nt], acc[mt][nt], 0, 0, 0);
                    acc[mt][nt] = __builtin_amdgcn_mfma_f32_16x16x32_bf16(afl[mt], bfh[nt], acc[mt][nt], 0, 0, 0);
                }
            __builtin_amdgcn_s_setprio(0);
        }
    } else {
        // ---- staged K-loop, BK=64, prefetch distance 2 (pvA even steps / pvB odd) ----
        int nsteps = Kslice >> 6;
        float pvA[2][4], pvB[2][4];
        stage_load<MODE>(pvA, Bf, k0, n0, tid, Ci, Hin, Ho, lgHo, lgHW);
        if (nsteps > 1) stage_load<MODE>(pvB, Bf, k0 + 64, n0, tid, Ci, Hin, Ho, lgHo, lgHW);

        auto step = [&](float (&pv)[2][4], int sidx) {
            int kbase = k0 + (sidx << 6);
            // ---- transform both k-halves + regs -> LDS (n-major lane map, r8) ----
            int nl = tid & 31, kg = tid >> 5;
#pragma unroll
            for (int r = 0; r < 2; ++r) {
                int k4 = kbase + (r << 5) + (kg << 2);
                uint32 pk[4];
                if (MODE == 0) {
                    int ic = k4 >> 4, kh = (k4 >> 2) & 3;
                    int n = n0 + nl;
                    int ow = n & (Ho - 1), oh = (n >> lgHo) & (Ho - 1);
                    int ih = oh * 2 - 1 + kh;
                    bool rowok = (unsigned)ih < (unsigned)Hin;
                    int iwb = ow * 2 - 1;
                    float sc_ = useBN ? scs[ic - c0] : 0.f;
                    float sh_ = useBN ? shs[ic - c0] : 0.f;
#pragma unroll
                    for (int e = 0; e < 4; ++e) {
                        int iw = iwb + e;
                        bool ok = rowok && ((unsigned)iw < (unsigned)Hin);
                        float f = pv[r][e];
                        if (useBN) { f = f * sc_ + sh_; f = f >= 0.f ? f : LEAK * f; }
                        if (!ok) f = 0.f;
                        HL s = split_bf16(f);
                        pk[e] = ((uint32)s.h << 16) | s.l;
                    }
                } else {
#pragma unroll
                    for (int e = 0; e < 4; ++e) {
                        float f = pv[r][e];
                        if (useBN) {
                            int lc = k4 + e - k0;
                            f = f * scs[lc] + shs[lc];
                            f = f >= 0.f ? f : LEAK * f;
                        }
                        HL s = split_bf16(f);
                        pk[e] = ((uint32)s.h << 16) | s.l;
                    }
                }
                *(uint4*)&Bsp[nl * 68 + (r << 5) + (kg << 2)] = make_uint4(pk[0], pk[1], pk[2], pk[3]);
            }
            __syncthreads();

            // ---- MT==1: hoist A fragments for BOTH subs (r11, measured win) ----
            bf16x8 afhP[2][2], aflP[2][2];
            if constexpr (MT == 1) {
#pragma unroll
                for (int sub = 0; sub < 2; ++sub) {
                    int kt = (kbase >> 5) + sub;
#pragma unroll
                    for (int mt = 0; mt < 2; ++mt) {
                        int mtAbs = (m0 >> 4) + (w << 1) + mt;
                        size_t abase = (((size_t)mtAbs * Kt + kt) << 6) + lane;
                        afhP[sub][mt] = *(const bf16x8*)(Ah + abase * 8);
                        aflP[sub][mt] = *(const bf16x8*)(Al + abase * 8);
                    }
                }
            }

            // ---- distance-2 prefetch: refill THIS register set for step sidx+2 ----
            if (sidx + 2 < nsteps)
                stage_load<MODE>(pv, Bf, kbase + 128, n0, tid, Ci, Hin, Ho, lgHo, lgHW);

            // ---- two 32-K substeps from LDS ----
#pragma unroll
            for (int sub = 0; sub < 2; ++sub) {
                bf16x8 afh[2 * MT], afl[2 * MT];
                if constexpr (MT == 1) {
#pragma unroll
                    for (int mt = 0; mt < 2; ++mt) { afh[mt] = afhP[sub][mt]; afl[mt] = aflP[sub][mt]; }
                } else {
                    int kt = (kbase >> 5) + sub;
#pragma unroll
                    for (int mt = 0; mt < 2 * MT; ++mt) {
                        int mtAbs = (m0 >> 4) + w * (2 * MT) + mt;
                        size_t abase = (((size_t)mtAbs * Kt + kt) << 6) + lane;
                        afh[mt] = *(const bf16x8*)(Ah + abase * 8);
                        afl[mt] = *(const bf16x8*)(Al + abase * 8);
                    }
                }
                bf16x8 bfh[2], bfl[2];
#pragma unroll
                for (int nt = 0; nt < 2; ++nt) {
                    int base = ((nt << 4) + tl) * 68 + (sub << 5) + (quad << 3);
                    uint4 ua = *(const uint4*)&Bsp[base];
                    uint4 ub = *(const uint4*)&Bsp[base + 4];
                    union { uint32 u[4]; bf16x8 v; } H, L;
                    H.u[0] = __builtin_amdgcn_perm(ua.y, ua.x, 0x07060302u);
                    H.u[1] = __builtin_amdgcn_perm(ua.w, ua.z, 0x07060302u);
                    H.u[2] = __builtin_amdgcn_perm(ub.y, ub.x, 0x07060302u);
                    H.u[3] = __builtin_amdgcn_perm(ub.w, ub.z, 0x07060302u);
                    L.u[0] = __builtin_amdgcn_perm(ua.y, ua.x, 0x05040100u);
                    L.u[1] = __builtin_amdgcn_perm(ua.w, ua.z, 0x05040100u);
                    L.u[2] = __builtin_amdgcn_perm(ub.y, ub.x, 0x05040100u);
                    L.u[3] = __builtin_amdgcn_perm(ub.w, ub.z, 0x05040100u);
                    bfh[nt] = H.v; bfl[nt] = L.v;
                }
                __builtin_amdgcn_s_setprio(1);
#pragma unroll
                for (int mt = 0; mt < 2 * MT; ++mt)
#pragma unroll
                    for (int nt = 0; nt < 2; ++nt) {
                        acc[mt][nt] = __builtin_amdgcn_mfma_f32_16x16x32_bf16(afh[mt], bfh[nt], acc[mt][nt], 0, 0, 0);
                        acc[mt][nt] = __builtin_amdgcn_mfma_f32_16x16x32_bf16(afh[mt], bfl[nt], acc[mt][nt], 0, 0, 0);
                        acc[mt][nt] = __builtin_amdgcn_mfma_f32_16x16x32_bf16(afl[mt], bfh[nt], acc[mt][nt], 0, 0, 0);
                    }
                __builtin_amdgcn_s_setprio(0);
            }
            __syncthreads();
        };

        for (int s = 0; s < nsteps; s += 2) {
            step(pvA, s);
            if (s + 1 < nsteps) step(pvB, s + 1);
        }
    }

    // ---- epilogue: D[m = quad*4+reg][n = tl] + optional fused stats (KS==1 paths) ----
    bool doStats = (statsBnt != nullptr);
    if (doStats) {
        if (tid < 2 * Co) scs[tid] = 0.f;
        __syncthreads();
    }
    float ssum[2 * MT][4] = {};
    float ssq [2 * MT][4] = {};
    float* dst = P + (size_t)ks * outSize;
    if (MODE == 0) {
#pragma unroll
        for (int nt = 0; nt < 2; ++nt) {
            int n = n0 + (nt << 4) + tl;
            int ow = n & (Ho - 1), oh = (n >> lgHo) & (Ho - 1), b = n >> (lgHo + lgHo);
#pragma unroll
            for (int mt = 0; mt < 2 * MT; ++mt) {
                int mb = m0 + w * (32 * MT) + (mt << 4) + (quad << 2);
#pragma unroll
                for (int r = 0; r < 4; ++r) {
                    int oc = mb + r;
                    float v = acc[mt][nt][r];
                    if (KS == 1) v += bias[oc];
                    if (doStats) { ssum[mt][r] += v; ssq[mt][r] += v * v; }
                    dst[((size_t)(b * Co + oc) * Ho + oh) * Ho + ow] = v;
                }
            }
        }
    } else {
        int kf = 1 << lgk;
        int Ho2 = Hin << lgk;
#pragma unroll
        for (int nt = 0; nt < 2; ++nt) {
            int n = n0 + (nt << 4) + tl;
            int b = n >> lgHW, hw = n & ((1 << lgHW) - 1);
            int h = hw >> lgHin, wp = hw & (Hin - 1);
#pragma unroll
            for (int mt = 0; mt < 2 * MT; ++mt) {
                int mb = m0 + w * (32 * MT) + (mt << 4) + (quad << 2);
#pragma unroll
                for (int r = 0; r < 4; ++r) {
                    int m = mb + r;
                    int o = m & (Co - 1), ij = m >> lgCo;
                    int ii = ij >> lgk, jj = ij & (kf - 1);
                    float v = acc[mt][nt][r];
                    if (KS == 1) v += bias[o];
                    if (doStats) { ssum[mt][r] += v; ssq[mt][r] += v * v; }
                    dst[((size_t)(b * Co + o) * Ho2 + (h << lgk) + ii) * Ho2 + (wp << lgk) + jj] = v;
                }
            }
        }
    }
    if (doStats) {
        // reduce over the 16 lanes (tl) sharing identical channels
#pragma unroll
        for (int mt = 0; mt < 2 * MT; ++mt)
#pragma unroll
            for (int r = 0; r < 4; ++r) {
                float s = ssum[mt][r], q2 = ssq[mt][r];
#pragma unroll
                for (int m2 = 1; m2 < 16; m2 <<= 1) {
                    s  += __shfl_xor(s,  m2);
                    q2 += __shfl_xor(q2, m2);
                }
                if (tl == 0) {
                    int m = m0 + w * (32 * MT) + (mt << 4) + (quad << 2) + r;
                    int o = (MODE == 0) ? m : (m & (Co - 1));
                    atomicAdd(&scs[o * 2],     s);
                    atomicAdd(&scs[o * 2 + 1], q2);
                }
            }
        __syncthreads();
        float* sb = statsBnt + (blockIdx.x & 7) * statsBank;
        if (tid < 2 * Co) atomicAdd(&sb[tid], scs[tid]);
    }
}

// ================= weight prep address =================
__device__ inline int fragaddr(int m, int k, int K) {
    return ((((m >> 4) * (K >> 5) + (k >> 5)) << 9) | (((k >> 3) & 3) << 7) | ((m & 15) << 3) | (k & 7));
}

#define OUT_CL   786432
#define OUT_CB   786433
#define OUT_IDX  786434
#define OUT_MIND 787458

// ================= enc0 direct conv (Ci=3) with non-atomic per-tile BN stat partials =================
__device__ void conv_body(int bid, int tid,
                          const float* __restrict__ x, const float* __restrict__ w,
                          const float* __restrict__ bias, float* __restrict__ P,
                          float* __restrict__ pst, float (&cst)[4][16])
{
    const int Ci = 3, Hin = 128, Co = 64, Ho = 64, OCT = 8;
    int ntile = (16 * Ho * Ho) >> 8;          // 256
    int tile = bid % ntile;
    int og = bid / ntile;
    int oc0 = og * OCT;

    int px = (tile << 8) + tid;
    int ow = px % Ho; int t = px / Ho;
    int oh = t % Ho;  int b = t / Ho;

    int off[16]; float fm[16];
    int ih0 = oh * 2 - 1, iw0 = ow * 2 - 1;
#pragma unroll
    for (int kh = 0; kh < 4; ++kh)
#pragma unroll
        for (int kw = 0; kw < 4; ++kw) {
            int ih = ih0 + kh, iw = iw0 + kw;
            bool ok = (ih >= 0) && (ih < Hin) && (iw >= 0) && (iw < Hin);
            int ihc = ih < 0 ? 0 : (ih >= Hin ? Hin - 1 : ih);
            int iwc = iw < 0 ? 0 : (iw >= Hin ? Hin - 1 : iw);
            off[kh * 4 + kw] = ihc * Hin + iwc;
            fm[kh * 4 + kw] = ok ? 1.f : 0.f;
        }

    float acc[OCT];
#pragma unroll
    for (int u = 0; u < OCT; ++u) acc[u] = bias[oc0 + u];

    const float* xc = x + (size_t)b * Ci * Hin * Hin;
    const float* wi = w + (size_t)oc0 * Ci * 16;
    int HinHin = Hin * Hin;
    for (int ic = 0; ic < Ci; ++ic) {
        float xv[16];
#pragma unroll
        for (int q = 0; q < 16; ++q) xv[q] = xc[off[q]] * fm[q];
#pragma unroll
        for (int u = 0; u < OCT; ++u) {
            const float* wo = wi + (size_t)u * Ci * 16;
            float a = acc[u];
#pragma unroll
            for (int q = 0; q < 16; ++q) a += xv[q] * wo[q];
            acc[u] = a;
        }
        xc += HinHin;
        wi += 16;
    }
    size_t obase = (((size_t)b * Co + oc0) * Ho + oh) * Ho + ow;
    size_t opl = (size_t)Ho * Ho;
#pragma unroll
    for (int u = 0; u < OCT; ++u) P[obase + u * opl] = acc[u];

    // ---- BN stat partials: butterfly over 64 lanes, combine 4 waves, plain store ----
    float sv[OCT], qv[OCT];
#pragma unroll
    for (int u = 0; u < OCT; ++u) { sv[u] = acc[u]; qv[u] = acc[u] * acc[u]; }
#pragma unroll
    for (int m2 = 1; m2 < 64; m2 <<= 1)
#pragma unroll
        for (int u = 0; u < OCT; ++u) {
            sv[u] += __shfl_xor(sv[u], m2);
            qv[u] += __shfl_xor(qv[u], m2);
        }
    int lane = tid & 63, wv = tid >> 6;
    if (lane == 0) {
#pragma unroll
        for (int u = 0; u < OCT; ++u) { cst[wv][u * 2] = sv[u]; cst[wv][u * 2 + 1] = qv[u]; }
    }
    __syncthreads();
    if (tid < 2 * OCT) {
        float v = cst[0][tid] + cst[1][tid] + cst[2][tid] + cst[3][tid];
        pst[(oc0 + (tid >> 1)) * 512 + tile * 2 + (tid & 1)] = v;
    }
}

// ================= fused prologue: zero BNT/losses + cbT + weight prep + enc0 conv =================
__global__ void prologue(const float* __restrict__ w1, const float* __restrict__ w2,
                         const float* __restrict__ w3, const float* __restrict__ d0,
                         const float* __restrict__ d1, const float* __restrict__ d2,
                         ushort* __restrict__ WH, ushort* __restrict__ WL,
                         const float* __restrict__ cb, float* __restrict__ cbT,
                         float* __restrict__ bnt, float* __restrict__ dout,
                         const float* __restrict__ x, const float* __restrict__ w0,
                         const float* __restrict__ b0, float* __restrict__ Y0,
                         float* __restrict__ pst) {
    __shared__ float cst[4][16];
    int blk = blockIdx.x;
    int tid = threadIdx.x;
    if (blk < 24) {                          // zero BN totals + loss accumulators
        bnt[blk * 256 + tid] = 0.f;
        if (blk == 0 && tid < 2) dout[OUT_CL + tid] = 0.f;
        return;
    }
    if (blk < 536) {                         // codebook transpose
        int idx = (blk - 24) * 256 + tid;
        int k = idx & 511, c = idx >> 9;
        cbT[idx] = cb[k * 256 + c];
        return;
    }
    if (blk >= 9400) {                       // enc0 direct conv (2048 blocks)
        conv_body(blk - 9400, tid, x, w0, b0, Y0, pst, cst);
        return;
    }
    int idx = (blk - 536) * 256 + tid;       // weight split+reorder
    if (idx >= 2269184) return;
    float v; int dst;
    if (idx < 131072) {                      // enc1: M=128 K=1024
        int m = idx >> 10, k = idx & 1023;
        v = w1[idx];
        dst = fragaddr(m, k, 1024);
    } else if (idx < 655360) {               // enc2: M=256 K=2048
        int i = idx - 131072;
        int m = i >> 11, k = i & 2047;
        v = w2[i];
        dst = 131072 + fragaddr(m, k, 2048);
    } else if (idx < 1703936) {              // enc3: M=256 K=4096
        int i = idx - 655360;
        int m = i >> 12, k = i & 4095;
        v = w3[i];
        dst = 655360 + fragaddr(m, k, 4096);
    } else if (idx < 2228224) {              // dec0: M=2048 K=256
        int i = idx - 1703936;
        int m = i >> 8, c = i & 255;
        int o = m & 127, ij = m >> 7;
        v = d0[((size_t)c * 128 + o) * 16 + ij];
        dst = 1703936 + fragaddr(m, c, 256);
    } else if (idx < 2260992) {              // dec1: M=256 K=128
        int i = idx - 2228224;
        int m = i >> 7, c = i & 127;
        int o = m & 63, ij = m >> 6;
        v = d1[((size_t)c * 64 + o) * 4 + ij];
        dst = 2228224 + fragaddr(m, c, 128);
    } else {                                 // dec2: M=128 K=64
        int i = idx - 2260992;
        int m = i >> 6, c = i & 63;
        int o = m & 31, ij = m >> 5;
        v = d2[((size_t)c * 32 + o) * 4 + ij];
        dst = 2260992 + fragaddr(m, c, 64);
    }
    HL s = split_bf16(v);
    WH[dst] = s.h; WL[dst] = s.l;
}

// ================= reduce partials + BN stats (enc2 only) =================
__global__ void reduce_bias_stats4(const float4* __restrict__ P, const float* __restrict__ bias,
                                   float4* __restrict__ y, float* __restrict__ bnt,
                                   int outSize4, int KS, int Co, int HW4, int nch) {
    int tid = threadIdx.x;
    int i = blockIdx.x * 256 + tid;
    int c = (i / HW4) % Co;
    float bv = bias[c];
    float4 s = make_float4(bv, bv, bv, bv);
    for (int ks = 0; ks < KS; ++ks) {
        float4 p = P[(size_t)ks * outSize4 + i];
        s.x += p.x; s.y += p.y; s.z += p.z; s.w += p.w;
    }
    y[i] = s;
    float ls  = s.x + s.y + s.z + s.w;
    float ls2 = s.x * s.x + s.y * s.y + s.z * s.z + s.w * s.w;
    __shared__ float as[16], aq[16];
    if (tid < 16) { as[tid] = 0.f; aq[tid] = 0.f; }
    __syncthreads();
    int c0 = ((blockIdx.x * 256) / HW4) % Co;
    atomicAdd(&as[c - c0], ls);
    atomicAdd(&aq[c - c0], ls2);
    __syncthreads();
    if (tid < nch) {
        atomicAdd(&bnt[(c0 + tid) * 2],     as[tid]);
        atomicAdd(&bnt[(c0 + tid) * 2 + 1], aq[tid]);
    }
}

// ================= Vector quantizer: sums 16 enc3 partial slices on load; writes
// pre-split QH/QL bf16 [n][k] row-major for dec0 MODE2; fused loss =================
__global__ void vq_main(const float* __restrict__ Pz, const float* __restrict__ b3,
                        const float* __restrict__ cbT, const float* __restrict__ cb,
                        ushort* __restrict__ qhl, float* __restrict__ dout) {
    int r0 = blockIdx.x * 4;
    int tid = threadIdx.x;
    int lane = tid & 63, w = tid >> 6;

    __shared__ __align__(16) float zT[256][4];
    __shared__ float wred[4][4];
    __shared__ float zn2s[4];
    __shared__ float wbd[4][4];
    __shared__ int   wbi[4][4];
    __shared__ int   bestsh[4];
    __shared__ float bestd[4];

    int b = r0 >> 6, s0 = r0 & 63;
    size_t zi = ((size_t)(b * 256 + tid)) * 64 + s0;
    float bv = b3[tid];
    float4 zv = make_float4(bv, bv, bv, bv);
    const float4* pp = (const float4*)Pz + (zi >> 2);
#pragma unroll
    for (int ks = 0; ks < 16; ++ks) {
        float4 p = pp[(size_t)ks * 65536];
        zv.x += p.x; zv.y += p.y; zv.z += p.z; zv.w += p.w;
    }
    *(float4*)&zT[tid][0] = zv;

    // ---- per-row |z|^2 via butterfly sum over channels ----
    float p0 = zv.x * zv.x, p1 = zv.y * zv.y, p2 = zv.z * zv.z, p3 = zv.w * zv.w;
#pragma unroll
    for (int m2 = 1; m2 < 64; m2 <<= 1) {
        p0 += __shfl_xor(p0, m2); p1 += __shfl_xor(p1, m2);
        p2 += __shfl_xor(p2, m2); p3 += __shfl_xor(p3, m2);
    }
    if (lane == 0) { wred[w][0] = p0; wred[w][1] = p1; wred[w][2] = p2; wred[w][3] = p3; }
    __syncthreads();
    if (tid < 4) zn2s[tid] = wred[0][tid] + wred[1][tid] + wred[2][tid] + wred[3][tid];
    __syncthreads();

    // ---- dot products: thread owns codebook entries k=tid and k=tid+256 ----
    float d0[4], d1[4];
#pragma unroll
    for (int rr = 0; rr < 4; ++rr) { d0[rr] = 0.f; d1[rr] = 0.f; }
    float cn0 = 0.f, cn1 = 0.f;
#pragma unroll 4
    for (int c = 0; c < 256; ++c) {
        float cv0 = cbT[c * 512 + tid];
        float cv1 = cbT[c * 512 + 256 + tid];
        cn0 += cv0 * cv0;
        cn1 += cv1 * cv1;
        float4 za = *(const float4*)&zT[c][0];
        d0[0] += za.x * cv0; d1[0] += za.x * cv1;
        d0[1] += za.y * cv0; d1[1] += za.y * cv1;
        d0[2] += za.z * cv0; d1[2] += za.z * cv1;
        d0[3] += za.w * cv0; d1[3] += za.w * cv1;
    }

    // ---- argmin via butterfly (tie-break: smaller index) ----
#pragma unroll
    for (int rr = 0; rr < 4; ++rr) {
        float dist0 = zn2s[rr] - 2.f * d0[rr] + cn0;
        float dist1 = zn2s[rr] - 2.f * d1[rr] + cn1;
        float bd = dist0; int bi = tid;
        if (dist1 < bd) { bd = dist1; bi = tid + 256; }
#pragma unroll
        for (int m2 = 1; m2 < 64; m2 <<= 1) {
            float od = __shfl_xor(bd, m2); int oi = __shfl_xor(bi, m2);
            if (od < bd || (od == bd && oi < bi)) { bd = od; bi = oi; }
        }
        if (lane == 0) { wbd[w][rr] = bd; wbi[w][rr] = bi; }
    }
    __syncthreads();
    if (tid < 4) {
        float bd = wbd[0][tid]; int bi = wbi[0][tid];
#pragma unroll
        for (int ww = 1; ww < 4; ++ww) {
            float od = wbd[ww][tid]; int oi = wbi[ww][tid];
            if (od < bd || (od == bd && oi < bi)) { bd = od; bi = oi; }
        }
        bestsh[tid] = bi; bestd[tid] = bd;
        dout[OUT_IDX + r0 + tid]  = (float)bi;
        dout[OUT_MIND + r0 + tid] = bd;
    }
    __syncthreads();

    // ---- gather quantized rows, split to bf16 hi/lo, store [n][k] (n = r0+rr) ----
#pragma unroll
    for (int rr = 0; rr < 4; ++rr) {
        float v = cb[(size_t)bestsh[rr] * 256 + tid];
        HL s = split_bf16(v);
        size_t o = (size_t)(r0 + rr) * 256 + tid;
        qhl[o]          = s.h;
        qhl[262144 + o] = s.l;
    }
    if (tid == 0) {
        float ls = (bestd[0] + bestd[1] + bestd[2] + bestd[3]) * (1.f / 262144.f);
        atomicAdd(&dout[OUT_CL], ls);
        atomicAdd(&dout[OUT_CB], ls);
    }
}

// ================= Final: BN(D2, 8-banked stats) + LeakyReLU + 1x1 conv + tanh =================
__global__ void final_conv_tanh(const float* __restrict__ hbuf, const float* __restrict__ bnt,
                                const float* __restrict__ g, const float* __restrict__ bt,
                                const float* __restrict__ w3, const float* __restrict__ b3,
                                float* __restrict__ out) {
    __shared__ float sc[32], sh[32], sw[96];
    int tid = threadIdx.x;
    if (tid < 32) {
        float sm = 0.f, sq = 0.f;
#pragma unroll
        for (int bk = 0; bk < 8; ++bk) {
            sm += bnt[bk * 64 + tid * 2];
            sq += bnt[bk * 64 + tid * 2 + 1];
        }
        float m = sm * (1.f / 262144.f);
        float var = sq * (1.f / 262144.f) - m * m;
        float scale = g[tid] * rsqrtf(var + 1e-5f);
        sc[tid] = scale;
        sh[tid] = bt[tid] - m * scale;
    }
    if (tid < 96) sw[tid] = w3[tid];
    __syncthreads();
    int idx = blockIdx.x * 256 + tid;          // 65536 = 16 * 4096 float4 pixels
    int hw4 = idx & 4095;
    int b   = idx >> 12;
    const float4* hp = (const float4*)hbuf + ((size_t)b * 32) * 4096 + hw4;
    float b0 = b3[0], b1 = b3[1], b2 = b3[2];
    float4 a0 = make_float4(b0, b0, b0, b0);
    float4 a1 = make_float4(b1, b1, b1, b1);
    float4 a2 = make_float4(b2, b2, b2, b2);
#pragma unroll 8
    for (int c = 0; c < 32; ++c) {
        float4 v = hp[(size_t)c * 4096];
        float scv = sc[c], shv = sh[c];
        float vx = v.x * scv + shv; vx = vx >= 0.f ? vx : LEAK * vx;
        float vy = v.y * scv + shv; vy = vy >= 0.f ? vy : LEAK * vy;
        float vz = v.z * scv + shv; vz = vz >= 0.f ? vz : LEAK * vz;
        float vw = v.w * scv + shv; vw = vw >= 0.f ? vw : LEAK * vw;
        float w0 = sw[c], w1 = sw[32 + c], w2 = sw[64 + c];
        a0.x += vx * w0; a0.y += vy * w0; a0.z += vz * w0; a0.w += vw * w0;
        a1.x += vx * w1; a1.y += vy * w1; a1.z += vz * w1; a1.w += vw * w1;
        a2.x += vx * w2; a2.y += vy * w2; a2.z += vz * w2; a2.w += vw * w2;
    }
    float4* op = (float4*)out;
    size_t ob = ((size_t)b * 3) * 4096 + hw4;
    op[ob]            = make_float4(tanhf(a0.x), tanhf(a0.y), tanhf(a0.z), tanhf(a0.w));
    op[ob + 4096]     = make_float4(tanhf(a1.x), tanhf(a1.y), tanhf(a1.z), tanhf(a1.w));
    op[ob + 2 * 4096] = make_float4(tanhf(a2.x), tanhf(a2.y), tanhf(a2.z), tanhf(a2.w));
}

extern "C" void kernel_launch(void* const* d_in, const int* in_sizes, int n_in,
                              void* d_out, int out_size, void* d_ws, size_t ws_size,
                              hipStream_t stream) {
    const float* x      = (const float*)d_in[0];
    const float* enc_w0 = (const float*)d_in[1];
    const float* enc_b0 = (const float*)d_in[2];
    const float* enc_w1 = (const float*)d_in[3];
    const float* enc_b1 = (const float*)d_in[4];
    const float* enc_w2 = (const float*)d_in[5];
    const float* enc_b2 = (const float*)d_in[6];
    const float* enc_w3 = (const float*)d_in[7];
    const float* enc_b3 = (const float*)d_in[8];
    const float* ebn_g0 = (const float*)d_in[9];
    const float* ebn_b0 = (const float*)d_in[10];
    const float* ebn_g1 = (const float*)d_in[11];
    const float* ebn_b1 = (const float*)d_in[12];
    const float* ebn_g2 = (const float*)d_in[13];
    const float* ebn_b2 = (const float*)d_in[14];
    const float* cb     = (const float*)d_in[15];
    const float* dec_w0 = (const float*)d_in[16];
    const float* dec_b0 = (const float*)d_in[17];
    const float* dbn_g0 = (const float*)d_in[18];
    const float* dbn_b0 = (const float*)d_in[19];
    const float* dec_w1 = (const float*)d_in[20];
    const float* dec_b1 = (const float*)d_in[21];
    const float* dbn_g1 = (const float*)d_in[22];
    const float* dbn_b1 = (const float*)d_in[23];
    const float* dec_w2 = (const float*)d_in[24];
    const float* dec_b2 = (const float*)d_in[25];
    const float* dbn_g2 = (const float*)d_in[26];
    const float* dbn_b2 = (const float*)d_in[27];
    const float* dec_w3 = (const float*)d_in[28];
    const float* dec_b3 = (const float*)d_in[29];

    float* out = (float*)d_out;
    float* ws  = (float*)d_ws;

    // ---- workspace (float units) ----
    float*  Y0   = ws;                               // 4194304
    float*  Y1   = ws + 4194304;                     // 2097152
    float*  Y2   = ws + 6291456;                     // 1048576
    float*  PST  = ws + 7340032;                     // 32768 (conv BN0 partials)
    float*  QHL  = ws + 7602176;                     // 262144 fl = 524288 us (QH | QL)
    ushort* WH   = (ushort*)(ws + 7864320);          // 2269184 us
    ushort* WL   = (ushort*)(ws + 8998912);          // 2269184 us
    float*  CBT  = ws + 10133504;                    // 131072
    float*  BNT  = ws + 10264576;                    // 6144: enc1 8x256 @0 | enc2 512 @2048
                                                     //   | dec0 8x256 @2560 | dec1 8x128 @4608
                                                     //   | dec2 8x64 @5632
    float*  PART = ws + 10270720;                    // 8388608
    float*  D0   = ws + 18659328;                    // 2097152
    float*  D1   = ws + 20756480;                    // 4194304
    float*  D2   = ws + 24950784;                    // 8388608

    dim3 blk(256);

    // ---- prologue: zero BNT/losses + cbT + weight prep + enc0 conv (fused, independent) ----
    prologue<<<11448, blk, 0, stream>>>(enc_w1, enc_w2, enc_w3, dec_w0, dec_w1, dec_w2,
                                        WH, WL, cb, CBT, BNT, out,
                                        x, enc_w0, enc_b0, Y0, PST);

    // enc1: M=128 N=16384 K=1024, MT=1, Mtiles=1 x Ntiles=512, KS=1 -> 512 blocks
    //       direct Y1 + bias + 8-banked fused stats @BNT+0; BN0 from conv partials
    gemm_mfma<0, 1><<<512, blk, 0, stream>>>(WH, WL, Y0,
        nullptr, ebn_g0, ebn_b0, 1.f / 65536.f, 4, enc_b1, Y1,
        1, 512, 1024, 1024, 1, 0, 64, 64, 128, 32, 5, 0, 0, 0, 0, BNT, PST, 256, 0);

    // enc2: M=256 N=4096 K=2048, MT=2 (256M tile, transform dedup), Mtiles=1 x
    //       Ntiles=128, KS=4 -> 512 blocks; BN1 from 8 banks @BNT+0
    gemm_mfma<0, 2><<<512, blk, 0, stream>>>(WH + 131072, WL + 131072, Y1,
        BNT, ebn_g1, ebn_b1, 1.f / 16384.f, 4, enc_b2, PART,
        1, 128, 2048, 512, 4, 1048576, 128, 32, 256, 16, 4, 0, 0, 0, 0, nullptr, nullptr, 0, 256);
    reduce_bias_stats4<<<1024, blk, 0, stream>>>((const float4*)PART, enc_b2, (float4*)Y2,
                                                 BNT + 2048, 262144, 4, 256, 64, 4);

    // enc3: M=256 N=1024 K=4096, MT=2, Mtiles=1 x Ntiles=32, KS=16 -> 512 blocks;
    //       partials -> VQ
    gemm_mfma<0, 2><<<512, blk, 0, stream>>>(WH + 655360, WL + 655360, Y2,
        BNT + 2048, ebn_g2, ebn_b2, 1.f / 4096.f, 4, enc_b3, PART,
        1, 32, 4096, 256, 16, 262144, 256, 16, 256, 8, 3, 0, 0, 0, 0, nullptr, nullptr, 0, 0);

    // ---- VQ: sums 16 partial slices + bias; emits pre-split QH/QL; fused loss ----
    vq_main<<<256, blk, 0, stream>>>(PART, enc_b3, CBT, cb, (ushort*)QHL, out);

    // ---- decoder ----
    // dec0: M=2048 N=1024 K=256, MT=1, Mtiles=16 x Ntiles=32, KS=1 -> 512 blocks; MODE2
    //       (transform-free); direct D0 + bias + 8-banked fused stats @BNT+2560
    gemm_mfma<2, 1><<<512, blk, 0, stream>>>(WH + 1703936, WL + 1703936, QHL,
        nullptr, nullptr, nullptr, 0.f, 0, dec_b0, D0,
        16, 32, 256, 256, 1, 0, 256, 8, 128, 262144, 0, 6, 3, 7, 2, BNT + 2560, nullptr, 256, 0);

    // dec1: M=256 N=16384 K=128, MT=2, Mtiles=1 x Ntiles=512, KS=1 -> 512 blocks;
    //       BN3 from banks @BNT+2560; direct D1 + 8-banked stats @BNT+4608
    gemm_mfma<1, 2><<<512, blk, 0, stream>>>(WH + 2228224, WL + 2228224, D0,
        BNT + 2560, dbn_g0, dbn_b0, 1.f / 16384.f, 0, dec_b1, D1,
        1, 512, 128, 128, 1, 0, 128, 32, 64, 0, 0, 10, 5, 6, 1, BNT + 4608, nullptr, 128, 256);

    // dec2: M=128 N=65536 K=64, MT=1, KS=1, 32N tiles -> 2048 blocks; BN4 from banks
    //       @BNT+4608; direct D2 + 8-banked stats @BNT+5632
    gemm_mfma<1, 1><<<2048, blk, 0, stream>>>(WH + 2260992, WL + 2260992, D1,
        BNT + 4608, dbn_g1, dbn_b1, 1.f / 65536.f, 0, dec_b2, D2,
        1, 2048, 64, 64, 1, 0, 64, 64, 32, 0, 0, 12, 6, 5, 1, BNT + 5632, nullptr, 64, 128);

    // final: BN5 (8 banks @BNT+5632) + leaky + 1x1 conv + tanh (float4)
    final_conv_tanh<<<256, blk, 0, stream>>>(D2, BNT + 5632, dbn_g2, dbn_b2, dec_w3, dec_b3, out);
}

// Round 14
// 350.959 us; speedup vs baseline: 1.1235x; 1.0026x over previous
//
#include <hip/hip_runtime.h>
#include <math.h>

#define LEAK 0.01f

typedef __bf16 bf16x8 __attribute__((ext_vector_type(8)));
typedef float f32x4 __attribute__((ext_vector_type(4)));
typedef unsigned short ushort;
typedef unsigned int uint32;

struct HL { ushort h, l; };

// split fp32 into bf16 hi + bf16 lo (both RNE): x ~= hi + lo, err ~2^-17 rel
__device__ inline HL split_bf16(float x) {
    unsigned u = __float_as_uint(x);
    unsigned hr = (u + 0x7FFFu + ((u >> 16) & 1u)) >> 16;
    float fh = __uint_as_float(hr << 16);
    float r = x - fh;
    unsigned v = __float_as_uint(r);
    unsigned lr = (v + 0x7FFFu + ((v >> 16) & 1u)) >> 16;
    HL out; out.h = (ushort)hr; out.l = (ushort)lr;
    return out;
}

// ============ staged-B raw load: 32n x 64k fp32 tile, 8 floats/thread (2 k-halves) ============
// r8: N-MAJOR lane mapping (nl = tid&31, kg = tid>>5) — coalesced staging (measured win).
template<int MODE>
__device__ inline void stage_load(float (&pv)[2][4], const float* __restrict__ Bf,
                                  int kbase, int n0, int tid,
                                  int Ci, int Hin, int Ho, int lgHo, int lgHW) {
    int nl = tid & 31, kg = tid >> 5;
    int n = n0 + nl;
#pragma unroll
    for (int r = 0; r < 2; ++r) {
        if (MODE == 0) {
            int k4 = kbase + (r << 5) + (kg << 2);
            int ic = k4 >> 4, kh = (k4 >> 2) & 3;
            int ow = n & (Ho - 1), oh = (n >> lgHo) & (Ho - 1), b = n >> (lgHo + lgHo);
            int ih = oh * 2 - 1 + kh;
            int ihc = ih < 0 ? 0 : (ih >= Hin ? Hin - 1 : ih);
            int iwb = ow * 2 - 1;
            size_t base = ((size_t)(b * Ci + ic) * Hin + ihc) * Hin;
#pragma unroll
            for (int e = 0; e < 4; ++e) {
                int iw = iwb + e;
                int iwc = iw < 0 ? 0 : (iw >= Hin ? Hin - 1 : iw);
                pv[r][e] = Bf[base + iwc];
            }
        } else {
            int c = kbase + (r << 5) + (kg << 2);
            int b = n >> lgHW, hw = n & ((1 << lgHW) - 1);
            size_t base = (((size_t)(b * Ci + c)) << lgHW) + hw;
            size_t str = (size_t)1 << lgHW;
#pragma unroll
            for (int e = 0; e < 4; ++e) pv[r][e] = Bf[base + e * str];
        }
    }
}

// ================= bf16-split MFMA GEMM with fused BN+LeakyReLU on B-load =================
// Block tile (128*MT)M x 32N, 4 waves of (32*MT)M x 32N. K-step 64, prefetch dist 2.
// MT=2 (enc2/enc3/dec1): both M-halves from ONE staged B tile (transform dedup).
// MODE 0: conv-im2col B; MODE 1: channel-major B; MODE 2: PRE-SPLIT B from global.
// statsBnt != nullptr (KS==1): fused per-channel sum/sumsq atomics, 8-way banked.
// bntBankStride > 0: input bnt is 8-banked; sum banks in prologue.
template<int MODE, int MT>
__global__ __launch_bounds__(256, 3) void gemm_mfma(
    const ushort* __restrict__ Ah, const ushort* __restrict__ Al,
    const float* __restrict__ Bf,
    const float* __restrict__ bnt, const float* __restrict__ gamma,
    const float* __restrict__ beta, float invN, int chanShift,
    const float* __restrict__ bias, float* __restrict__ P,
    int Mtiles, int Ntiles, int K, int Kslice, int KS, int outSize,
    int Ci, int Hin, int Co, int Ho, int lgHo,
    int lgHW, int lgHin, int lgCo, int lgk,
    float* __restrict__ statsBnt, const float* __restrict__ bnPart,
    int statsBank, int bntBankStride)
{
    __shared__ __align__(16) uint32 Bsp[32 * 68];   // [n][64k] packed, stride 68
    __shared__ float scs[256], shs[256];

    int bid = blockIdx.x;
    int ntile = bid % Ntiles; bid /= Ntiles;
    int mtile = bid % Mtiles;
    int ks = bid / Mtiles;
    int tid = threadIdx.x;
    int lane = tid & 63, w = tid >> 6;
    int quad = lane >> 4, tl = lane & 15;
    int n0 = ntile << 5, m0 = mtile * (128 * MT), k0 = ks * Kslice;
    int Kt = K >> 5;

    bool useBN = (bnt != nullptr) || (bnPart != nullptr);
    int c0 = k0 >> chanShift;
    if (bnPart != nullptr) {
        // BN0 from conv tile-partials: 64 channels x 256 (sum,sq) pairs
        int c = tid >> 2, qq = tid & 3;
        const float2* pp2 = (const float2*)(bnPart + c * 512) + qq * 64;
        float s = 0.f, s2 = 0.f;
#pragma unroll 8
        for (int p = 0; p < 64; ++p) { float2 v = pp2[p]; s += v.x; s2 += v.y; }
        scs[tid] = s; shs[tid] = s2;
        __syncthreads();
        float scale = 0.f, shift = 0.f;
        if (tid < 64) {
            float st = scs[tid * 4] + scs[tid * 4 + 1] + scs[tid * 4 + 2] + scs[tid * 4 + 3];
            float qt = shs[tid * 4] + shs[tid * 4 + 1] + shs[tid * 4 + 2] + shs[tid * 4 + 3];
            float m = st * invN;
            float var = qt * invN - m * m;
            scale = gamma[tid] * rsqrtf(var + 1e-5f);
            shift = beta[tid] - m * scale;
        }
        __syncthreads();
        // store shifted so the transform's scs[ic - c0] indexing works for any K-slice
        if (tid < 64 && tid >= c0) { scs[tid - c0] = scale; shs[tid - c0] = shift; }
    } else if (bnt != nullptr) {
        int nch = Kslice >> chanShift;
        for (int c = tid; c < nch; c += 256) {
            float sm, sq;
            if (bntBankStride > 0) {
                sm = 0.f; sq = 0.f;
#pragma unroll
                for (int bk = 0; bk < 8; ++bk) {
                    sm += bnt[bk * bntBankStride + (c0 + c) * 2];
                    sq += bnt[bk * bntBankStride + (c0 + c) * 2 + 1];
                }
            } else {
                sm = bnt[(c0 + c) * 2];
                sq = bnt[(c0 + c) * 2 + 1];
            }
            float m = sm * invN;
            float var = sq * invN - m * m;
            float scale = gamma[c0 + c] * rsqrtf(var + 1e-5f);
            scs[c] = scale;
            shs[c] = beta[c0 + c] - m * scale;
        }
    }
    __syncthreads();

    f32x4 zero4 = {0.f, 0.f, 0.f, 0.f};
    f32x4 acc[2 * MT][2];
#pragma unroll
    for (int mt = 0; mt < 2 * MT; ++mt)
#pragma unroll
        for (int nt = 0; nt < 2; ++nt) acc[mt][nt] = zero4;

    if (MODE == 2) {
        // ---- barrier-free K-loop: B pre-split in global (L2-resident) ----
        const ushort* Bu = (const ushort*)Bf;
        for (int kc = 0; kc < Kslice; kc += 32) {
            int kbase = k0 + kc;
            int kt = kbase >> 5;
            bf16x8 afh[2 * MT], afl[2 * MT];
#pragma unroll
            for (int mt = 0; mt < 2 * MT; ++mt) {
                int mtAbs = (m0 >> 4) + w * (2 * MT) + mt;
                size_t abase = (((size_t)mtAbs * Kt + kt) << 6) + lane;
                afh[mt] = *(const bf16x8*)(Ah + abase * 8);
                afl[mt] = *(const bf16x8*)(Al + abase * 8);
            }
            bf16x8 bfh[2], bfl[2];
#pragma unroll
            for (int nt = 0; nt < 2; ++nt) {
                int n = n0 + (nt << 4) + tl;
                size_t ba = (size_t)n * Ci + kbase + (quad << 3);
                bfh[nt] = *(const bf16x8*)(Bu + ba);
                bfl[nt] = *(const bf16x8*)(Bu + Ho + ba);
            }
            __builtin_amdgcn_s_setprio(1);
#pragma unroll
            for (int mt = 0; mt < 2 * MT; ++mt)
#pragma unroll
                for (int nt = 0; nt < 2; ++nt) {
                    acc[mt][nt] = __builtin_amdgcn_mfma_f32_16x16x32_bf16(afh[mt], bfh[nt], acc[mt][nt], 0, 0, 0);
                    acc[mt][nt] = __builtin_amdgcn_mfma_f32_16x16x32_bf16(afh[mt], bfl[nt], acc[mt][nt], 0, 0, 0);
                    acc[mt][nt] = __builtin_amdgcn_mfma_f32_16x16x32_bf16(afl[mt], bfh[nt], acc[mt][nt], 0, 0, 0);
                }
            __builtin_amdgcn_s_setprio(0);
        }
    } else {
        // ---- staged K-loop, BK=64, prefetch distance 2 (pvA even steps / pvB odd) ----
        int nsteps = Kslice >> 6;
        float pvA[2][4], pvB[2][4];
        stage_load<MODE>(pvA, Bf, k0, n0, tid, Ci, Hin, Ho, lgHo, lgHW);
        if (nsteps > 1) stage_load<MODE>(pvB, Bf, k0 + 64, n0, tid, Ci, Hin, Ho, lgHo, lgHW);

        auto step = [&](float (&pv)[2][4], int sidx) {
            int kbase = k0 + (sidx << 6);
            // ---- transform both k-halves + regs -> LDS (n-major lane map, r8) ----
            int nl = tid & 31, kg = tid >> 5;
#pragma unroll
            for (int r = 0; r < 2; ++r) {
                int k4 = kbase + (r << 5) + (kg << 2);
                uint32 pk[4];
                if (MODE == 0) {
                    int ic = k4 >> 4, kh = (k4 >> 2) & 3;
                    int n = n0 + nl;
                    int ow = n & (Ho - 1), oh = (n >> lgHo) & (Ho - 1);
                    int ih = oh * 2 - 1 + kh;
                    bool rowok = (unsigned)ih < (unsigned)Hin;
                    int iwb = ow * 2 - 1;
                    float sc_ = useBN ? scs[ic - c0] : 0.f;
                    float sh_ = useBN ? shs[ic - c0] : 0.f;
#pragma unroll
                    for (int e = 0; e < 4; ++e) {
                        int iw = iwb + e;
                        bool ok = rowok && ((unsigned)iw < (unsigned)Hin);
                        float f = pv[r][e];
                        if (useBN) { f = f * sc_ + sh_; f = f >= 0.f ? f : LEAK * f; }
                        if (!ok) f = 0.f;
                        HL s = split_bf16(f);
                        pk[e] = ((uint32)s.h << 16) | s.l;
                    }
                } else {
#pragma unroll
                    for (int e = 0; e < 4; ++e) {
                        float f = pv[r][e];
                        if (useBN) {
                            int lc = k4 + e - k0;
                            f = f * scs[lc] + shs[lc];
                            f = f >= 0.f ? f : LEAK * f;
                        }
                        HL s = split_bf16(f);
                        pk[e] = ((uint32)s.h << 16) | s.l;
                    }
                }
                *(uint4*)&Bsp[nl * 68 + (r << 5) + (kg << 2)] = make_uint4(pk[0], pk[1], pk[2], pk[3]);
            }
            __syncthreads();

            // ---- MT==1: hoist A fragments for BOTH subs (r11, measured win) ----
            bf16x8 afhP[2][2], aflP[2][2];
            if constexpr (MT == 1) {
#pragma unroll
                for (int sub = 0; sub < 2; ++sub) {
                    int kt = (kbase >> 5) + sub;
#pragma unroll
                    for (int mt = 0; mt < 2; ++mt) {
                        int mtAbs = (m0 >> 4) + (w << 1) + mt;
                        size_t abase = (((size_t)mtAbs * Kt + kt) << 6) + lane;
                        afhP[sub][mt] = *(const bf16x8*)(Ah + abase * 8);
                        aflP[sub][mt] = *(const bf16x8*)(Al + abase * 8);
                    }
                }
            }

            // ---- distance-2 prefetch: refill THIS register set for step sidx+2 ----
            if (sidx + 2 < nsteps)
                stage_load<MODE>(pv, Bf, kbase + 128, n0, tid, Ci, Hin, Ho, lgHo, lgHW);

            // ---- two 32-K substeps from LDS ----
#pragma unroll
            for (int sub = 0; sub < 2; ++sub) {
                bf16x8 afh[2 * MT], afl[2 * MT];
                if constexpr (MT == 1) {
#pragma unroll
                    for (int mt = 0; mt < 2; ++mt) { afh[mt] = afhP[sub][mt]; afl[mt] = aflP[sub][mt]; }
                } else {
                    int kt = (kbase >> 5) + sub;
#pragma unroll
                    for (int mt = 0; mt < 2 * MT; ++mt) {
                        int mtAbs = (m0 >> 4) + w * (2 * MT) + mt;
                        size_t abase = (((size_t)mtAbs * Kt + kt) << 6) + lane;
                        afh[mt] = *(const bf16x8*)(Ah + abase * 8);
                        afl[mt] = *(const bf16x8*)(Al + abase * 8);
                    }
                }
                bf16x8 bfh[2], bfl[2];
#pragma unroll
                for (int nt = 0; nt < 2; ++nt) {
                    int base = ((nt << 4) + tl) * 68 + (sub << 5) + (quad << 3);
                    uint4 ua = *(const uint4*)&Bsp[base];
                    uint4 ub = *(const uint4*)&Bsp[base + 4];
                    union { uint32 u[4]; bf16x8 v; } H, L;
                    H.u[0] = __builtin_amdgcn_perm(ua.y, ua.x, 0x07060302u);
                    H.u[1] = __builtin_amdgcn_perm(ua.w, ua.z, 0x07060302u);
                    H.u[2] = __builtin_amdgcn_perm(ub.y, ub.x, 0x07060302u);
                    H.u[3] = __builtin_amdgcn_perm(ub.w, ub.z, 0x07060302u);
                    L.u[0] = __builtin_amdgcn_perm(ua.y, ua.x, 0x05040100u);
                    L.u[1] = __builtin_amdgcn_perm(ua.w, ua.z, 0x05040100u);
                    L.u[2] = __builtin_amdgcn_perm(ub.y, ub.x, 0x05040100u);
                    L.u[3] = __builtin_amdgcn_perm(ub.w, ub.z, 0x05040100u);
                    bfh[nt] = H.v; bfl[nt] = L.v;
                }
                __builtin_amdgcn_s_setprio(1);
#pragma unroll
                for (int mt = 0; mt < 2 * MT; ++mt)
#pragma unroll
                    for (int nt = 0; nt < 2; ++nt) {
                        acc[mt][nt] = __builtin_amdgcn_mfma_f32_16x16x32_bf16(afh[mt], bfh[nt], acc[mt][nt], 0, 0, 0);
                        acc[mt][nt] = __builtin_amdgcn_mfma_f32_16x16x32_bf16(afh[mt], bfl[nt], acc[mt][nt], 0, 0, 0);
                        acc[mt][nt] = __builtin_amdgcn_mfma_f32_16x16x32_bf16(afl[mt], bfh[nt], acc[mt][nt], 0, 0, 0);
                    }
                __builtin_amdgcn_s_setprio(0);
            }
            __syncthreads();
        };

        for (int s = 0; s < nsteps; s += 2) {
            step(pvA, s);
            if (s + 1 < nsteps) step(pvB, s + 1);
        }
    }

    // ---- epilogue: D[m = quad*4+reg][n = tl] + optional fused stats (KS==1 paths) ----
    bool doStats = (statsBnt != nullptr);
    if (doStats) {
        if (tid < 2 * Co) scs[tid] = 0.f;
        __syncthreads();
    }
    float ssum[2 * MT][4] = {};
    float ssq [2 * MT][4] = {};
    float* dst = P + (size_t)ks * outSize;
    if (MODE == 0) {
#pragma unroll
        for (int nt = 0; nt < 2; ++nt) {
            int n = n0 + (nt << 4) + tl;
            int ow = n & (Ho - 1), oh = (n >> lgHo) & (Ho - 1), b = n >> (lgHo + lgHo);
#pragma unroll
            for (int mt = 0; mt < 2 * MT; ++mt) {
                int mb = m0 + w * (32 * MT) + (mt << 4) + (quad << 2);
#pragma unroll
                for (int r = 0; r < 4; ++r) {
                    int oc = mb + r;
                    float v = acc[mt][nt][r];
                    if (KS == 1) v += bias[oc];
                    if (doStats) { ssum[mt][r] += v; ssq[mt][r] += v * v; }
                    dst[((size_t)(b * Co + oc) * Ho + oh) * Ho + ow] = v;
                }
            }
        }
    } else {
        int kf = 1 << lgk;
        int Ho2 = Hin << lgk;
#pragma unroll
        for (int nt = 0; nt < 2; ++nt) {
            int n = n0 + (nt << 4) + tl;
            int b = n >> lgHW, hw = n & ((1 << lgHW) - 1);
            int h = hw >> lgHin, wp = hw & (Hin - 1);
#pragma unroll
            for (int mt = 0; mt < 2 * MT; ++mt) {
                int mb = m0 + w * (32 * MT) + (mt << 4) + (quad << 2);
#pragma unroll
                for (int r = 0; r < 4; ++r) {
                    int m = mb + r;
                    int o = m & (Co - 1), ij = m >> lgCo;
                    int ii = ij >> lgk, jj = ij & (kf - 1);
                    float v = acc[mt][nt][r];
                    if (KS == 1) v += bias[o];
                    if (doStats) { ssum[mt][r] += v; ssq[mt][r] += v * v; }
                    dst[((size_t)(b * Co + o) * Ho2 + (h << lgk) + ii) * Ho2 + (wp << lgk) + jj] = v;
                }
            }
        }
    }
    if (doStats) {
        // reduce over the 16 lanes (tl) sharing identical channels
#pragma unroll
        for (int mt = 0; mt < 2 * MT; ++mt)
#pragma unroll
            for (int r = 0; r < 4; ++r) {
                float s = ssum[mt][r], q2 = ssq[mt][r];
#pragma unroll
                for (int m2 = 1; m2 < 16; m2 <<= 1) {
                    s  += __shfl_xor(s,  m2);
                    q2 += __shfl_xor(q2, m2);
                }
                if (tl == 0) {
                    int m = m0 + w * (32 * MT) + (mt << 4) + (quad << 2) + r;
                    int o = (MODE == 0) ? m : (m & (Co - 1));
                    atomicAdd(&scs[o * 2],     s);
                    atomicAdd(&scs[o * 2 + 1], q2);
                }
            }
        __syncthreads();
        float* sb = statsBnt + (blockIdx.x & 7) * statsBank;
        if (tid < 2 * Co) atomicAdd(&sb[tid], scs[tid]);
    }
}

// ================= weight prep address =================
__device__ inline int fragaddr(int m, int k, int K) {
    return ((((m >> 4) * (K >> 5) + (k >> 5)) << 9) | (((k >> 3) & 3) << 7) | ((m & 15) << 3) | (k & 7));
}

#define OUT_CL   786432
#define OUT_CB   786433
#define OUT_IDX  786434
#define OUT_MIND 787458

// ================= enc0 direct conv (Ci=3) with non-atomic per-tile BN stat partials =================
__device__ void conv_body(int bid, int tid,
                          const float* __restrict__ x, const float* __restrict__ w,
                          const float* __restrict__ bias, float* __restrict__ P,
                          float* __restrict__ pst, float (&cst)[4][16])
{
    const int Ci = 3, Hin = 128, Co = 64, Ho = 64, OCT = 8;
    int ntile = (16 * Ho * Ho) >> 8;          // 256
    int tile = bid % ntile;
    int og = bid / ntile;
    int oc0 = og * OCT;

    int px = (tile << 8) + tid;
    int ow = px % Ho; int t = px / Ho;
    int oh = t % Ho;  int b = t / Ho;

    int off[16]; float fm[16];
    int ih0 = oh * 2 - 1, iw0 = ow * 2 - 1;
#pragma unroll
    for (int kh = 0; kh < 4; ++kh)
#pragma unroll
        for (int kw = 0; kw < 4; ++kw) {
            int ih = ih0 + kh, iw = iw0 + kw;
            bool ok = (ih >= 0) && (ih < Hin) && (iw >= 0) && (iw < Hin);
            int ihc = ih < 0 ? 0 : (ih >= Hin ? Hin - 1 : ih);
            int iwc = iw < 0 ? 0 : (iw >= Hin ? Hin - 1 : iw);
            off[kh * 4 + kw] = ihc * Hin + iwc;
            fm[kh * 4 + kw] = ok ? 1.f : 0.f;
        }

    float acc[OCT];
#pragma unroll
    for (int u = 0; u < OCT; ++u) acc[u] = bias[oc0 + u];

    const float* xc = x + (size_t)b * Ci * Hin * Hin;
    const float* wi = w + (size_t)oc0 * Ci * 16;
    int HinHin = Hin * Hin;
    for (int ic = 0; ic < Ci; ++ic) {
        float xv[16];
#pragma unroll
        for (int q = 0; q < 16; ++q) xv[q] = xc[off[q]] * fm[q];
#pragma unroll
        for (int u = 0; u < OCT; ++u) {
            const float* wo = wi + (size_t)u * Ci * 16;
            float a = acc[u];
#pragma unroll
            for (int q = 0; q < 16; ++q) a += xv[q] * wo[q];
            acc[u] = a;
        }
        xc += HinHin;
        wi += 16;
    }
    size_t obase = (((size_t)b * Co + oc0) * Ho + oh) * Ho + ow;
    size_t opl = (size_t)Ho * Ho;
#pragma unroll
    for (int u = 0; u < OCT; ++u) P[obase + u * opl] = acc[u];

    // ---- BN stat partials: butterfly over 64 lanes, combine 4 waves, plain store ----
    float sv[OCT], qv[OCT];
#pragma unroll
    for (int u = 0; u < OCT; ++u) { sv[u] = acc[u]; qv[u] = acc[u] * acc[u]; }
#pragma unroll
    for (int m2 = 1; m2 < 64; m2 <<= 1)
#pragma unroll
        for (int u = 0; u < OCT; ++u) {
            sv[u] += __shfl_xor(sv[u], m2);
            qv[u] += __shfl_xor(qv[u], m2);
        }
    int lane = tid & 63, wv = tid >> 6;
    if (lane == 0) {
#pragma unroll
        for (int u = 0; u < OCT; ++u) { cst[wv][u * 2] = sv[u]; cst[wv][u * 2 + 1] = qv[u]; }
    }
    __syncthreads();
    if (tid < 2 * OCT) {
        float v = cst[0][tid] + cst[1][tid] + cst[2][tid] + cst[3][tid];
        pst[(oc0 + (tid >> 1)) * 512 + tile * 2 + (tid & 1)] = v;
    }
}

// ================= fused prologue: zero BNT/losses + cbT + VECTORIZED weight prep + enc0 conv ======
// r13 (resubmit after infra flake): weight prep 4 elements/thread — fragaddr has k&7
// innermost, so 4 consecutive (4-aligned) k map to 4 consecutive dst ushorts: one
// float4 load (enc weights are k-contiguous) + two 8B ushort4 stores. ~3x fewer insts.
__global__ void prologue(const float* __restrict__ w1, const float* __restrict__ w2,
                         const float* __restrict__ w3, const float* __restrict__ d0,
                         const float* __restrict__ d1, const float* __restrict__ d2,
                         ushort* __restrict__ WH, ushort* __restrict__ WL,
                         const float* __restrict__ cb, float* __restrict__ cbT,
                         float* __restrict__ bnt, float* __restrict__ dout,
                         const float* __restrict__ x, const float* __restrict__ w0,
                         const float* __restrict__ b0, float* __restrict__ Y0,
                         float* __restrict__ pst) {
    __shared__ float cst[4][16];
    int blk = blockIdx.x;
    int tid = threadIdx.x;
    if (blk < 24) {                          // zero BN totals + loss accumulators
        bnt[blk * 256 + tid] = 0.f;
        if (blk == 0 && tid < 2) dout[OUT_CL + tid] = 0.f;
        return;
    }
    if (blk < 536) {                         // codebook transpose
        int idx = (blk - 24) * 256 + tid;
        int k = idx & 511, c = idx >> 9;
        cbT[idx] = cb[k * 256 + c];
        return;
    }
    if (blk >= 2752) {                       // enc0 direct conv (2048 blocks)
        conv_body(blk - 2752, tid, x, w0, b0, Y0, pst, cst);
        return;
    }
    // ---- vectorized weight split+reorder: 4 consecutive k per thread ----
    int idx4 = (blk - 536) * 256 + tid;      // 0 .. 567295
    if (idx4 >= 567296) return;
    int base = idx4 << 2;
    float v[4]; int dst;
    if (base < 131072) {                     // enc1: M=128 K=1024
        int m = base >> 10, k = base & 1023;
        float4 t = *(const float4*)(w1 + base);
        v[0] = t.x; v[1] = t.y; v[2] = t.z; v[3] = t.w;
        dst = fragaddr(m, k, 1024);
    } else if (base < 655360) {              // enc2: M=256 K=2048
        int i = base - 131072;
        int m = i >> 11, k = i & 2047;
        float4 t = *(const float4*)(w2 + i);
        v[0] = t.x; v[1] = t.y; v[2] = t.z; v[3] = t.w;
        dst = 131072 + fragaddr(m, k, 2048);
    } else if (base < 1703936) {             // enc3: M=256 K=4096
        int i = base - 655360;
        int m = i >> 12, k = i & 4095;
        float4 t = *(const float4*)(w3 + i);
        v[0] = t.x; v[1] = t.y; v[2] = t.z; v[3] = t.w;
        dst = 655360 + fragaddr(m, k, 4096);
    } else if (base < 2228224) {             // dec0: M=2048 K=256 (k-gather, source strided)
        int i = base - 1703936;
        int m = i >> 8, c = i & 255;
        int o = m & 127, ij = m >> 7;
#pragma unroll
        for (int e = 0; e < 4; ++e) v[e] = d0[((size_t)(c + e) * 128 + o) * 16 + ij];
        dst = 1703936 + fragaddr(m, c, 256);
    } else if (base < 2260992) {             // dec1: M=256 K=128
        int i = base - 2228224;
        int m = i >> 7, c = i & 127;
        int o = m & 63, ij = m >> 6;
#pragma unroll
        for (int e = 0; e < 4; ++e) v[e] = d1[((size_t)(c + e) * 64 + o) * 4 + ij];
        dst = 2228224 + fragaddr(m, c, 128);
    } else {                                 // dec2: M=128 K=64
        int i = base - 2260992;
        int m = i >> 6, c = i & 63;
        int o = m & 31, ij = m >> 5;
#pragma unroll
        for (int e = 0; e < 4; ++e) v[e] = d2[((size_t)(c + e) * 32 + o) * 4 + ij];
        dst = 2260992 + fragaddr(m, c, 64);
    }
    HL s0 = split_bf16(v[0]), s1 = split_bf16(v[1]);
    HL s2 = split_bf16(v[2]), s3 = split_bf16(v[3]);
    *(ushort4*)&WH[dst] = make_ushort4(s0.h, s1.h, s2.h, s3.h);
    *(ushort4*)&WL[dst] = make_ushort4(s0.l, s1.l, s2.l, s3.l);
}

// ================= reduce partials + BN stats (enc2 only) =================
__global__ void reduce_bias_stats4(const float4* __restrict__ P, const float* __restrict__ bias,
                                   float4* __restrict__ y, float* __restrict__ bnt,
                                   int outSize4, int KS, int Co, int HW4, int nch) {
    int tid = threadIdx.x;
    int i = blockIdx.x * 256 + tid;
    int c = (i / HW4) % Co;
    float bv = bias[c];
    float4 s = make_float4(bv, bv, bv, bv);
    for (int ks = 0; ks < KS; ++ks) {
        float4 p = P[(size_t)ks * outSize4 + i];
        s.x += p.x; s.y += p.y; s.z += p.z; s.w += p.w;
    }
    y[i] = s;
    float ls  = s.x + s.y + s.z + s.w;
    float ls2 = s.x * s.x + s.y * s.y + s.z * s.z + s.w * s.w;
    __shared__ float as[16], aq[16];
    if (tid < 16) { as[tid] = 0.f; aq[tid] = 0.f; }
    __syncthreads();
    int c0 = ((blockIdx.x * 256) / HW4) % Co;
    atomicAdd(&as[c - c0], ls);
    atomicAdd(&aq[c - c0], ls2);
    __syncthreads();
    if (tid < nch) {
        atomicAdd(&bnt[(c0 + tid) * 2],     as[tid]);
        atomicAdd(&bnt[(c0 + tid) * 2 + 1], aq[tid]);
    }
}

// ================= Vector quantizer: sums 16 enc3 partial slices on load; writes
// pre-split QH/QL bf16 [n][k] row-major for dec0 MODE2; fused loss =================
__global__ void vq_main(const float* __restrict__ Pz, const float* __restrict__ b3,
                        const float* __restrict__ cbT, const float* __restrict__ cb,
                        ushort* __restrict__ qhl, float* __restrict__ dout) {
    int r0 = blockIdx.x * 4;
    int tid = threadIdx.x;
    int lane = tid & 63, w = tid >> 6;

    __shared__ __align__(16) float zT[256][4];
    __shared__ float wred[4][4];
    __shared__ float zn2s[4];
    __shared__ float wbd[4][4];
    __shared__ int   wbi[4][4];
    __shared__ int   bestsh[4];
    __shared__ float bestd[4];

    int b = r0 >> 6, s0 = r0 & 63;
    size_t zi = ((size_t)(b * 256 + tid)) * 64 + s0;
    float bv = b3[tid];
    float4 zv = make_float4(bv, bv, bv, bv);
    const float4* pp = (const float4*)Pz + (zi >> 2);
#pragma unroll
    for (int ks = 0; ks < 16; ++ks) {
        float4 p = pp[(size_t)ks * 65536];
        zv.x += p.x; zv.y += p.y; zv.z += p.z; zv.w += p.w;
    }
    *(float4*)&zT[tid][0] = zv;

    // ---- per-row |z|^2 via butterfly sum over channels ----
    float p0 = zv.x * zv.x, p1 = zv.y * zv.y, p2 = zv.z * zv.z, p3 = zv.w * zv.w;
#pragma unroll
    for (int m2 = 1; m2 < 64; m2 <<= 1) {
        p0 += __shfl_xor(p0, m2); p1 += __shfl_xor(p1, m2);
        p2 += __shfl_xor(p2, m2); p3 += __shfl_xor(p3, m2);
    }
    if (lane == 0) { wred[w][0] = p0; wred[w][1] = p1; wred[w][2] = p2; wred[w][3] = p3; }
    __syncthreads();
    if (tid < 4) zn2s[tid] = wred[0][tid] + wred[1][tid] + wred[2][tid] + wred[3][tid];
    __syncthreads();

    // ---- dot products: thread owns codebook entries k=tid and k=tid+256 ----
    float d0[4], d1[4];
#pragma unroll
    for (int rr = 0; rr < 4; ++rr) { d0[rr] = 0.f; d1[rr] = 0.f; }
    float cn0 = 0.f, cn1 = 0.f;
#pragma unroll 4
    for (int c = 0; c < 256; ++c) {
        float cv0 = cbT[c * 512 + tid];
        float cv1 = cbT[c * 512 + 256 + tid];
        cn0 += cv0 * cv0;
        cn1 += cv1 * cv1;
        float4 za = *(const float4*)&zT[c][0];
        d0[0] += za.x * cv0; d1[0] += za.x * cv1;
        d0[1] += za.y * cv0; d1[1] += za.y * cv1;
        d0[2] += za.z * cv0; d1[2] += za.z * cv1;
        d0[3] += za.w * cv0; d1[3] += za.w * cv1;
    }

    // ---- argmin via butterfly (tie-break: smaller index) ----
#pragma unroll
    for (int rr = 0; rr < 4; ++rr) {
        float dist0 = zn2s[rr] - 2.f * d0[rr] + cn0;
        float dist1 = zn2s[rr] - 2.f * d1[rr] + cn1;
        float bd = dist0; int bi = tid;
        if (dist1 < bd) { bd = dist1; bi = tid + 256; }
#pragma unroll
        for (int m2 = 1; m2 < 64; m2 <<= 1) {
            float od = __shfl_xor(bd, m2); int oi = __shfl_xor(bi, m2);
            if (od < bd || (od == bd && oi < bi)) { bd = od; bi = oi; }
        }
        if (lane == 0) { wbd[w][rr] = bd; wbi[w][rr] = bi; }
    }
    __syncthreads();
    if (tid < 4) {
        float bd = wbd[0][tid]; int bi = wbi[0][tid];
#pragma unroll
        for (int ww = 1; ww < 4; ++ww) {
            float od = wbd[ww][tid]; int oi = wbi[ww][tid];
            if (od < bd || (od == bd && oi < bi)) { bd = od; bi = oi; }
        }
        bestsh[tid] = bi; bestd[tid] = bd;
        dout[OUT_IDX + r0 + tid]  = (float)bi;
        dout[OUT_MIND + r0 + tid] = bd;
    }
    __syncthreads();

    // ---- gather quantized rows, split to bf16 hi/lo, store [n][k] (n = r0+rr) ----
#pragma unroll
    for (int rr = 0; rr < 4; ++rr) {
        float v = cb[(size_t)bestsh[rr] * 256 + tid];
        HL s = split_bf16(v);
        size_t o = (size_t)(r0 + rr) * 256 + tid;
        qhl[o]          = s.h;
        qhl[262144 + o] = s.l;
    }
    if (tid == 0) {
        float ls = (bestd[0] + bestd[1] + bestd[2] + bestd[3]) * (1.f / 262144.f);
        atomicAdd(&dout[OUT_CL], ls);
        atomicAdd(&dout[OUT_CB], ls);
    }
}

// ================= Final: BN(D2, 8-banked stats) + LeakyReLU + 1x1 conv + tanh =================
__global__ void final_conv_tanh(const float* __restrict__ hbuf, const float* __restrict__ bnt,
                                const float* __restrict__ g, const float* __restrict__ bt,
                                const float* __restrict__ w3, const float* __restrict__ b3,
                                float* __restrict__ out) {
    __shared__ float sc[32], sh[32], sw[96];
    int tid = threadIdx.x;
    if (tid < 32) {
        float sm = 0.f, sq = 0.f;
#pragma unroll
        for (int bk = 0; bk < 8; ++bk) {
            sm += bnt[bk * 64 + tid * 2];
            sq += bnt[bk * 64 + tid * 2 + 1];
        }
        float m = sm * (1.f / 262144.f);
        float var = sq * (1.f / 262144.f) - m * m;
        float scale = g[tid] * rsqrtf(var + 1e-5f);
        sc[tid] = scale;
        sh[tid] = bt[tid] - m * scale;
    }
    if (tid < 96) sw[tid] = w3[tid];
    __syncthreads();
    int idx = blockIdx.x * 256 + tid;          // 65536 = 16 * 4096 float4 pixels
    int hw4 = idx & 4095;
    int b   = idx >> 12;
    const float4* hp = (const float4*)hbuf + ((size_t)b * 32) * 4096 + hw4;
    float b0 = b3[0], b1 = b3[1], b2 = b3[2];
    float4 a0 = make_float4(b0, b0, b0, b0);
    float4 a1 = make_float4(b1, b1, b1, b1);
    float4 a2 = make_float4(b2, b2, b2, b2);
#pragma unroll 8
    for (int c = 0; c < 32; ++c) {
        float4 v = hp[(size_t)c * 4096];
        float scv = sc[c], shv = sh[c];
        float vx = v.x * scv + shv; vx = vx >= 0.f ? vx : LEAK * vx;
        float vy = v.y * scv + shv; vy = vy >= 0.f ? vy : LEAK * vy;
        float vz = v.z * scv + shv; vz = vz >= 0.f ? vz : LEAK * vz;
        float vw = v.w * scv + shv; vw = vw >= 0.f ? vw : LEAK * vw;
        float w0 = sw[c], w1 = sw[32 + c], w2 = sw[64 + c];
        a0.x += vx * w0; a0.y += vy * w0; a0.z += vz * w0; a0.w += vw * w0;
        a1.x += vx * w1; a1.y += vy * w1; a1.z += vz * w1; a1.w += vw * w1;
        a2.x += vx * w2; a2.y += vy * w2; a2.z += vz * w2; a2.w += vw * w2;
    }
    float4* op = (float4*)out;
    size_t ob = ((size_t)b * 3) * 4096 + hw4;
    op[ob]            = make_float4(tanhf(a0.x), tanhf(a0.y), tanhf(a0.z), tanhf(a0.w));
    op[ob + 4096]     = make_float4(tanhf(a1.x), tanhf(a1.y), tanhf(a1.z), tanhf(a1.w));
    op[ob + 2 * 4096] = make_float4(tanhf(a2.x), tanhf(a2.y), tanhf(a2.z), tanhf(a2.w));
}

extern "C" void kernel_launch(void* const* d_in, const int* in_sizes, int n_in,
                              void* d_out, int out_size, void* d_ws, size_t ws_size,
                              hipStream_t stream) {
    const float* x      = (const float*)d_in[0];
    const float* enc_w0 = (const float*)d_in[1];
    const float* enc_b0 = (const float*)d_in[2];
    const float* enc_w1 = (const float*)d_in[3];
    const float* enc_b1 = (const float*)d_in[4];
    const float* enc_w2 = (const float*)d_in[5];
    const float* enc_b2 = (const float*)d_in[6];
    const float* enc_w3 = (const float*)d_in[7];
    const float* enc_b3 = (const float*)d_in[8];
    const float* ebn_g0 = (const float*)d_in[9];
    const float* ebn_b0 = (const float*)d_in[10];
    const float* ebn_g1 = (const float*)d_in[11];
    const float* ebn_b1 = (const float*)d_in[12];
    const float* ebn_g2 = (const float*)d_in[13];
    const float* ebn_b2 = (const float*)d_in[14];
    const float* cb     = (const float*)d_in[15];
    const float* dec_w0 = (const float*)d_in[16];
    const float* dec_b0 = (const float*)d_in[17];
    const float* dbn_g0 = (const float*)d_in[18];
    const float* dbn_b0 = (const float*)d_in[19];
    const float* dec_w1 = (const float*)d_in[20];
    const float* dec_b1 = (const float*)d_in[21];
    const float* dbn_g1 = (const float*)d_in[22];
    const float* dbn_b1 = (const float*)d_in[23];
    const float* dec_w2 = (const float*)d_in[24];
    const float* dec_b2 = (const float*)d_in[25];
    const float* dbn_g2 = (const float*)d_in[26];
    const float* dbn_b2 = (const float*)d_in[27];
    const float* dec_w3 = (const float*)d_in[28];
    const float* dec_b3 = (const float*)d_in[29];

    float* out = (float*)d_out;
    float* ws  = (float*)d_ws;

    // ---- workspace (float units) ----
    float*  Y0   = ws;                               // 4194304
    float*  Y1   = ws + 4194304;                     // 2097152
    float*  Y2   = ws + 6291456;                     // 1048576
    float*  PST  = ws + 7340032;                     // 32768 (conv BN0 partials)
    float*  QHL  = ws + 7602176;                     // 262144 fl = 524288 us (QH | QL)
    ushort* WH   = (ushort*)(ws + 7864320);          // 2269184 us
    ushort* WL   = (ushort*)(ws + 8998912);          // 2269184 us
    float*  CBT  = ws + 10133504;                    // 131072
    float*  BNT  = ws + 10264576;                    // 6144: enc1 8x256 @0 | enc2 512 @2048
                                                     //   | dec0 8x256 @2560 | dec1 8x128 @4608
                                                     //   | dec2 8x64 @5632
    float*  PART = ws + 10270720;                    // 8388608
    float*  D0   = ws + 18659328;                    // 2097152
    float*  D1   = ws + 20756480;                    // 4194304
    float*  D2   = ws + 24950784;                    // 8388608

    dim3 blk(256);

    // ---- prologue: zero BNT/losses + cbT + vectorized weight prep + enc0 conv ----
    prologue<<<4800, blk, 0, stream>>>(enc_w1, enc_w2, enc_w3, dec_w0, dec_w1, dec_w2,
                                       WH, WL, cb, CBT, BNT, out,
                                       x, enc_w0, enc_b0, Y0, PST);

    // enc1: M=128 N=16384 K=1024, MT=1, Mtiles=1 x Ntiles=512, KS=1 -> 512 blocks
    //       direct Y1 + bias + 8-banked fused stats @BNT+0; BN0 from conv partials
    gemm_mfma<0, 1><<<512, blk, 0, stream>>>(WH, WL, Y0,
        nullptr, ebn_g0, ebn_b0, 1.f / 65536.f, 4, enc_b1, Y1,
        1, 512, 1024, 1024, 1, 0, 64, 64, 128, 32, 5, 0, 0, 0, 0, BNT, PST, 256, 0);

    // enc2: M=256 N=4096 K=2048, MT=2 (256M tile, transform dedup), Mtiles=1 x
    //       Ntiles=128, KS=4 -> 512 blocks; BN1 from 8 banks @BNT+0
    gemm_mfma<0, 2><<<512, blk, 0, stream>>>(WH + 131072, WL + 131072, Y1,
        BNT, ebn_g1, ebn_b1, 1.f / 16384.f, 4, enc_b2, PART,
        1, 128, 2048, 512, 4, 1048576, 128, 32, 256, 16, 4, 0, 0, 0, 0, nullptr, nullptr, 0, 256);
    reduce_bias_stats4<<<1024, blk, 0, stream>>>((const float4*)PART, enc_b2, (float4*)Y2,
                                                 BNT + 2048, 262144, 4, 256, 64, 4);

    // enc3: M=256 N=1024 K=4096, MT=2, Mtiles=1 x Ntiles=32, KS=16 -> 512 blocks;
    //       partials -> VQ
    gemm_mfma<0, 2><<<512, blk, 0, stream>>>(WH + 655360, WL + 655360, Y2,
        BNT + 2048, ebn_g2, ebn_b2, 1.f / 4096.f, 4, enc_b3, PART,
        1, 32, 4096, 256, 16, 262144, 256, 16, 256, 8, 3, 0, 0, 0, 0, nullptr, nullptr, 0, 0);

    // ---- VQ: sums 16 partial slices + bias; emits pre-split QH/QL; fused loss ----
    vq_main<<<256, blk, 0, stream>>>(PART, enc_b3, CBT, cb, (ushort*)QHL, out);

    // ---- decoder ----
    // dec0: M=2048 N=1024 K=256, MT=1, Mtiles=16 x Ntiles=32, KS=1 -> 512 blocks; MODE2
    //       (transform-free); direct D0 + bias + 8-banked fused stats @BNT+2560
    gemm_mfma<2, 1><<<512, blk, 0, stream>>>(WH + 1703936, WL + 1703936, QHL,
        nullptr, nullptr, nullptr, 0.f, 0, dec_b0, D0,
        16, 32, 256, 256, 1, 0, 256, 8, 128, 262144, 0, 6, 3, 7, 2, BNT + 2560, nullptr, 256, 0);

    // dec1: M=256 N=16384 K=128, MT=2, Mtiles=1 x Ntiles=512, KS=1 -> 512 blocks;
    //       BN3 from banks @BNT+2560; direct D1 + 8-banked stats @BNT+4608
    gemm_mfma<1, 2><<<512, blk, 0, stream>>>(WH + 2228224, WL + 2228224, D0,
        BNT + 2560, dbn_g0, dbn_b0, 1.f / 16384.f, 0, dec_b1, D1,
        1, 512, 128, 128, 1, 0, 128, 32, 64, 0, 0, 10, 5, 6, 1, BNT + 4608, nullptr, 128, 256);

    // dec2: M=128 N=65536 K=64, MT=1, KS=1, 32N tiles -> 2048 blocks; BN4 from banks
    //       @BNT+4608; direct D2 + 8-banked stats @BNT+5632
    gemm_mfma<1, 1><<<2048, blk, 0, stream>>>(WH + 2260992, WL + 2260992, D1,
        BNT + 4608, dbn_g1, dbn_b1, 1.f / 65536.f, 0, dec_b2, D2,
        1, 2048, 64, 64, 1, 0, 64, 64, 32, 0, 0, 12, 6, 5, 1, BNT + 5632, nullptr, 64, 128);

    // final: BN5 (8 banks @BNT+5632) + leaky + 1x1 conv + tanh (float4)
    final_conv_tanh<<<256, blk, 0, stream>>>(D2, BNT + 5632, dbn_g2, dbn_b2, dec_w3, dec_b3, out);
}